// Round 1
// baseline (1389.008 us; speedup 1.0000x reference)
//
#include <hip/hip_runtime.h>
#include <math.h>
#include <stdint.h>

// Problem constants (B=8,S=1024,D=256,N=4096)
#define TTOK 8192
#define DIM 256
#define NSLOT 4096
#define TCHUNK 2048
#define CAPC 65536
#define SCALE 0.0625f     // 1/sqrt(256), exact

typedef unsigned long long u64;

// misc[0]=cand count, misc[1]=flagA (all-novel & all-mask & act0>=0),
// misc[2]=flagB (no ladder overflow), misc[3]=flagFinal (fast path valid)

// ---------------------------------------------------------------- init
__global__ void k_init(int* cnt, int* misc) {
    int t = blockIdx.x * 256 + threadIdx.x;
    if (t < NSLOT) cnt[t] = 0;
    if (t == 0) { misc[0] = 0; misc[1] = 1; misc[2] = 1; misc[3] = 0; }
}

// ------------------------------------------------- projections (3 GEMMs)
// out[t][n] = sum_k x[t][k]*W[n][k] + b[n]; grid (T/64, D/64, 3)
__global__ __launch_bounds__(256) void k_proj(
    const float* __restrict__ x,
    const float* __restrict__ Wk, const float* __restrict__ bk,
    const float* __restrict__ Wv, const float* __restrict__ bv,
    const float* __restrict__ Wq, const float* __restrict__ bq,
    float* __restrict__ ka, float* __restrict__ va, float* __restrict__ qa)
{
    const float* W; const float* bias; float* out;
    if (blockIdx.z == 0)      { W = Wk; bias = bk; out = ka; }
    else if (blockIdx.z == 1) { W = Wv; bias = bv; out = va; }
    else                      { W = Wq; bias = bq; out = qa; }

    __shared__ float As[16][68];
    __shared__ float Bs[16][68];
    const int tid = threadIdx.x;
    const int tx = tid & 15, ty = tid >> 4;
    const int row0 = blockIdx.x * 64;
    const int col0 = blockIdx.y * 64;
    const int lm = tid >> 2;
    const int lk = (tid & 3) * 4;

    float acc[4][4] = {};
    for (int kk = 0; kk < DIM; kk += 16) {
        float4 a4 = *(const float4*)&x[(size_t)(row0 + lm) * DIM + kk + lk];
        float4 b4 = *(const float4*)&W[(size_t)(col0 + lm) * DIM + kk + lk];
        __syncthreads();
        As[lk+0][lm] = a4.x; As[lk+1][lm] = a4.y; As[lk+2][lm] = a4.z; As[lk+3][lm] = a4.w;
        Bs[lk+0][lm] = b4.x; Bs[lk+1][lm] = b4.y; Bs[lk+2][lm] = b4.z; Bs[lk+3][lm] = b4.w;
        __syncthreads();
        #pragma unroll
        for (int k = 0; k < 16; k++) {
            float4 av = *(const float4*)&As[k][ty*4];
            float4 bv2 = *(const float4*)&Bs[k][tx*4];
            float aa[4] = {av.x, av.y, av.z, av.w};
            float bb[4] = {bv2.x, bv2.y, bv2.z, bv2.w};
            #pragma unroll
            for (int i = 0; i < 4; i++)
                #pragma unroll
                for (int j = 0; j < 4; j++)
                    acc[i][j] += aa[i] * bb[j];
        }
    }
    #pragma unroll
    for (int j = 0; j < 4; j++) {
        float bj = bias[col0 + tx*4 + j];
        #pragma unroll
        for (int i = 0; i < 4; i++)
            out[(size_t)(row0 + ty*4 + i) * DIM + col0 + tx*4 + j] = acc[i][j] + bj;
    }
}

// --------------------------------------- sim row-argmax (fused, no sim buffer)
// grid (T/64, 4): each block: 64 tokens x 1024 slots (16 chunks of 64)
__global__ __launch_bounds__(256) void k_simmax(
    const float* __restrict__ ka, const float* __restrict__ keys0,
    float* __restrict__ partV, int* __restrict__ partI)
{
    __shared__ float As[16][68];
    __shared__ float Bs[16][68];
    __shared__ float redV[64][17];
    __shared__ int   redI[64][17];
    const int tid = threadIdx.x;
    const int tx = tid & 15, ty = tid >> 4;
    const int row0 = blockIdx.x * 64;
    const int nbase = blockIdx.y * 1024;
    const int lm = tid >> 2;
    const int lk = (tid & 3) * 4;

    float runV = -INFINITY; int runI = 0;
    for (int nc = 0; nc < 16; nc++) {
        const int col0 = nbase + nc * 64;
        float acc[4][4] = {};
        for (int kk = 0; kk < DIM; kk += 16) {
            float4 a4 = *(const float4*)&ka[(size_t)(row0 + lm) * DIM + kk + lk];
            float4 b4 = *(const float4*)&keys0[(size_t)(col0 + lm) * DIM + kk + lk];
            __syncthreads();
            As[lk+0][lm] = a4.x; As[lk+1][lm] = a4.y; As[lk+2][lm] = a4.z; As[lk+3][lm] = a4.w;
            Bs[lk+0][lm] = b4.x; Bs[lk+1][lm] = b4.y; Bs[lk+2][lm] = b4.z; Bs[lk+3][lm] = b4.w;
            __syncthreads();
            #pragma unroll
            for (int k = 0; k < 16; k++) {
                float4 av = *(const float4*)&As[k][ty*4];
                float4 bv2 = *(const float4*)&Bs[k][tx*4];
                float aa[4] = {av.x, av.y, av.z, av.w};
                float bb[4] = {bv2.x, bv2.y, bv2.z, bv2.w};
                #pragma unroll
                for (int i = 0; i < 4; i++)
                    #pragma unroll
                    for (int j = 0; j < 4; j++)
                        acc[i][j] += aa[i] * bb[j];
            }
        }
        __syncthreads();
        #pragma unroll
        for (int i = 0; i < 4; i++) {
            float bvx = acc[i][0]; int bix = col0 + tx*4;
            #pragma unroll
            for (int j = 1; j < 4; j++)
                if (acc[i][j] > bvx) { bvx = acc[i][j]; bix = col0 + tx*4 + j; }
            redV[ty*4+i][tx] = bvx; redI[ty*4+i][tx] = bix;
        }
        __syncthreads();
        if (tid < 64) {
            #pragma unroll
            for (int c = 0; c < 16; c++) {
                float v = redV[tid][c];
                if (v > runV) { runV = v; runI = redI[tid][c]; }  // ascending n => first-max kept
            }
        }
    }
    if (tid < 64) {
        partV[(size_t)blockIdx.y * TTOK + row0 + tid] = runV;
        partI[(size_t)blockIdx.y * TTOK + row0 + tid] = runI;
    }
}

__global__ void k_bestmerge(const float* partV, const int* partI,
                            int* best, int* novel, int* misc) {
    int t = blockIdx.x * 256 + threadIdx.x;
    if (t >= TTOK) return;
    float bv = partV[t]; int bi = partI[t];
    #pragma unroll
    for (int q = 1; q < 4; q++) {
        float v = partV[(size_t)q * TTOK + t];
        if (v > bv) { bv = v; bi = partI[(size_t)q * TTOK + t]; }
    }
    best[t] = bi;
    int nv = (bv * SCALE < 0.5f) ? 1 : 0;   // max commutes exactly with positive scale
    novel[t] = nv;
    if (!nv) atomicAnd(&misc[1], 0);
}

// --------------------------------------------------------------- flags
// mask layout detect: byte1==1 -> uint8 bools; else int-like (covers int32/fp32 all-true)
__global__ void k_flags(const unsigned char* maskraw, const float* act0, int* misc) {
    int t = blockIdx.x * 256 + threadIdx.x;
    int u8 = (maskraw[1] == 1);
    if (t < TTOK) {
        int mv = u8 ? (int)maskraw[t] : ((const int*)maskraw)[t];
        if (mv == 0) atomicAnd(&misc[1], 0);
    }
    if (t < NSLOT) {
        float a = act0[t];
        if (!(a >= 0.0f)) atomicAnd(&misc[1], 0);  // u64 packing needs non-negative floats
    }
}

// ------------------------------------------------- ladder candidate generation
__global__ void k_ladder(const float* act0, u64* cand, int* candJ, int* misc) {
    if (misc[1] == 0) return;
    int i = blockIdx.x * 256 + threadIdx.x;
    if (i >= NSLOT) return;
    float w = act0[i];
    int j = 0;
    while (w < 1.0f) {
        if (j >= 48) { atomicAnd(&misc[2], 0); break; }
        int pos = atomicAdd(&misc[0], 1);
        if (pos >= CAPC) { atomicAnd(&misc[2], 0); break; }
        cand[pos] = ((u64)__float_as_uint(w) << 32) | (unsigned)i;
        candJ[pos] = j;
        j++;
        w = fminf(1.0f, w + 0.1f);   // identical fp op to reference's min(1, act+0.1)
    }
}

__global__ void k_finalize(int* misc) {
    misc[3] = (misc[1] && misc[2] && misc[0] >= TTOK) ? 1 : 0;
}

// ------------------------------------------------- rank candidates (O(K^2/P))
__global__ __launch_bounds__(256) void k_rank(
    const u64* __restrict__ cand, const int* __restrict__ candJ,
    int* slot_seq, int* rankis, int* cnt, const int* misc)
{
    if (!(misc[1] && misc[2])) return;
    int K = misc[0]; if (K > CAPC) K = CAPC;
    if ((int)blockIdx.x * 256 >= K) return;
    int tid = blockIdx.x * 256 + threadIdx.x;
    u64 my = (tid < K) ? cand[tid] : ~0ull;
    int rank = 0;
    __shared__ u64 ch[2048];
    for (int base = 0; base < K; base += 2048) {
        int len = min(2048, K - base);
        __syncthreads();
        for (int i = threadIdx.x; i < len; i += 256) ch[i] = cand[base + i];
        __syncthreads();
        if (tid < K) {
            #pragma unroll 8
            for (int i = 0; i < len; i++) rank += (ch[i] < my) ? 1 : 0;
        }
    }
    if (tid < K && rank < TTOK) {
        int slot = (int)(my & 0xffffffffu);
        slot_seq[rank] = slot;
        rankis[rank] = candJ[tid];   // ladder index == temporal rank within slot
        atomicAdd(&cnt[slot], 1);
    }
}

__global__ void k_actfinal(const float* act0, const int* cnt, float* act_f, const int* misc) {
    if (!misc[3]) return;
    int i = blockIdx.x * 256 + threadIdx.x;
    if (i >= NSLOT) return;
    float a = act0[i];
    int m = cnt[i];
    for (int r = 0; r < m; r++) a = fminf(1.0f, a + 0.1f);
    act_f[i] = a;
}

// ------------------------------------------------- serial fallback (cold path)
__global__ __launch_bounds__(64) void k_serial(
    const int* novel, const int* best, const unsigned char* maskraw,
    const float* act0, const int* misc,
    int* slot_seq, int* rankis, int* cnt, float* act_f)
{
    if (misc[3]) return;   // fast path valid -> skip
    __shared__ float act[NSLOT];
    __shared__ int cntL[NSLOT];
    const int lane = threadIdx.x;
    const int u8 = (maskraw[1] == 1);
    for (int i = lane; i < NSLOT; i += 64) { act[i] = act0[i]; cntL[i] = 0; }
    __syncthreads();
    // chunk mins: lane owns chunk=lane (64 elems)
    float cv; int ci;
    {
        cv = act[lane * 64]; ci = lane * 64;
        for (int u = 1; u < 64; u++) {
            float v = act[lane * 64 + u];
            if (v < cv) { cv = v; ci = lane * 64 + u; }
        }
    }
    for (int t = 0; t < TTOK; t++) {
        int nv = novel[t];
        int mk = (u8 ? (int)maskraw[t] : ((const int*)maskraw)[t]) != 0;
        int slot;
        if (nv) {
            float v = cv; int ix = ci;
            for (int off = 32; off >= 1; off >>= 1) {
                float ov = __shfl_xor(v, off);
                int oi = __shfl_xor(ix, off);
                if (ov < v || (ov == v && oi < ix)) { v = ov; ix = oi; }
            }
            slot = ix;
        } else {
            slot = best[t];
        }
        if (mk) {
            float a = act[slot];
            float a2 = fminf(1.0f, a + 0.1f);
            __syncthreads();
            if (lane == 0) {
                act[slot] = a2;
                slot_seq[t] = slot;
                int r = cntL[slot]; rankis[t] = r; cntL[slot] = r + 1;
            }
            __syncthreads();
            int c = slot >> 6;
            float v = act[c * 64 + lane]; int ix = c * 64 + lane;
            for (int off = 32; off >= 1; off >>= 1) {
                float ov = __shfl_xor(v, off);
                int oi = __shfl_xor(ix, off);
                if (ov < v || (ov == v && oi < ix)) { v = ov; ix = oi; }
            }
            if (lane == c) { cv = v; ci = ix; }
        } else {
            if (lane == 0) rankis[t] = -1;
        }
        __syncthreads();
    }
    for (int i = lane; i < NSLOT; i += 64) { cnt[i] = cntL[i]; act_f[i] = act[i]; }
}

// ------------------------------------------------- CSR build: scan + scatter
__global__ __launch_bounds__(256) void k_offsets(const int* cnt, int* offs) {
    __shared__ int part[256];
    int tid = threadIdx.x;
    int base = tid * 16;
    int loc[16];
    int s = 0;
    #pragma unroll
    for (int i = 0; i < 16; i++) { loc[i] = s; s += cnt[base + i]; }
    part[tid] = s;
    __syncthreads();
    for (int off = 1; off < 256; off <<= 1) {
        int v = (tid >= off) ? part[tid - off] : 0;
        __syncthreads();
        part[tid] += v;
        __syncthreads();
    }
    int pre = (tid == 0) ? 0 : part[tid - 1];
    #pragma unroll
    for (int i = 0; i < 16; i++) offs[base + i] = pre + loc[i];
}

__global__ void k_scatter(const int* slot_seq, const int* rankis, const int* offs, int* listTok) {
    int t = blockIdx.x * 256 + threadIdx.x;
    if (t >= TTOK) return;
    int r = rankis[t];
    if (r >= 0) listTok[offs[slot_seq[t]] + r] = t;
}

// ------------------------------------------------- apply buffer writes per slot
__global__ __launch_bounds__(256) void k_apply(
    const float* __restrict__ keys0, const float* __restrict__ values0,
    const float* __restrict__ ka, const float* __restrict__ va,
    const int* __restrict__ novel, const int* __restrict__ cnt,
    const int* __restrict__ offs, const int* __restrict__ listTok,
    float* __restrict__ kb, float* __restrict__ vb)
{
    int s = blockIdx.x;
    int d = threadIdx.x;
    float kv = keys0[(size_t)s * DIM + d];
    float vv = values0[(size_t)s * DIM + d];
    int m = cnt[s], off = offs[s];
    for (int r = 0; r < m; r++) {
        int t = listTok[off + r];
        float al = novel[t] ? 0.9f : 0.3f;
        kv = (1.0f - al) * kv + al * ka[(size_t)t * DIM + d];
        vv = (1.0f - al) * vv + al * va[(size_t)t * DIM + d];
    }
    kb[(size_t)s * DIM + d] = kv;
    vb[(size_t)s * DIM + d] = vv;
}

// ------------------------------------------------- attention: logits GEMM
// grid (TCHUNK/64, NSLOT/64); rows global = t0 + local
__global__ __launch_bounds__(256) void k_logits(
    const float* __restrict__ qa, const float* __restrict__ kb,
    const float* __restrict__ act_f, float* __restrict__ logits, int t0)
{
    __shared__ float As[16][68];
    __shared__ float Bs[16][68];
    const int tid = threadIdx.x;
    const int tx = tid & 15, ty = tid >> 4;
    const int row0 = blockIdx.x * 64;       // chunk-local
    const int col0 = blockIdx.y * 64;
    const int lm = tid >> 2;
    const int lk = (tid & 3) * 4;

    float acc[4][4] = {};
    for (int kk = 0; kk < DIM; kk += 16) {
        float4 a4 = *(const float4*)&qa[(size_t)(t0 + row0 + lm) * DIM + kk + lk];
        float4 b4 = *(const float4*)&kb[(size_t)(col0 + lm) * DIM + kk + lk];
        __syncthreads();
        As[lk+0][lm] = a4.x; As[lk+1][lm] = a4.y; As[lk+2][lm] = a4.z; As[lk+3][lm] = a4.w;
        Bs[lk+0][lm] = b4.x; Bs[lk+1][lm] = b4.y; Bs[lk+2][lm] = b4.z; Bs[lk+3][lm] = b4.w;
        __syncthreads();
        #pragma unroll
        for (int k = 0; k < 16; k++) {
            float4 av = *(const float4*)&As[k][ty*4];
            float4 bv2 = *(const float4*)&Bs[k][tx*4];
            float aa[4] = {av.x, av.y, av.z, av.w};
            float bb[4] = {bv2.x, bv2.y, bv2.z, bv2.w};
            #pragma unroll
            for (int i = 0; i < 4; i++)
                #pragma unroll
                for (int j = 0; j < 4; j++)
                    acc[i][j] += aa[i] * bb[j];
        }
    }
    #pragma unroll
    for (int j = 0; j < 4; j++) {
        int gn = col0 + tx*4 + j;
        float a = act_f[gn];
        float lg = logf(fmaxf(a, 1e-8f));
        bool dead = (a < 0.01f);
        #pragma unroll
        for (int i = 0; i < 4; i++) {
            float v = dead ? -INFINITY : (acc[i][j] * SCALE + lg);
            logits[(size_t)(row0 + ty*4 + i) * NSLOT + gn] = v;
        }
    }
}

// ------------------------------------------------- row softmax in place
__global__ __launch_bounds__(256) void k_softmax(float* __restrict__ logits) {
    float* row = logits + (size_t)blockIdx.x * NSLOT;
    __shared__ float sd[256];
    int tid = threadIdx.x;
    float m = -INFINITY;
    for (int i = tid; i < NSLOT; i += 256) m = fmaxf(m, row[i]);
    sd[tid] = m; __syncthreads();
    for (int off = 128; off >= 1; off >>= 1) {
        if (tid < off) sd[tid] = fmaxf(sd[tid], sd[tid + off]);
        __syncthreads();
    }
    m = sd[0]; __syncthreads();
    float s = 0.0f;
    for (int i = tid; i < NSLOT; i += 256) {
        float e = expf(row[i] - m);
        row[i] = e;
        s += e;
    }
    sd[tid] = s; __syncthreads();
    for (int off = 128; off >= 1; off >>= 1) {
        if (tid < off) sd[tid] += sd[tid + off];
        __syncthreads();
    }
    float inv = 1.0f / sd[0];
    for (int i = tid; i < NSLOT; i += 256) row[i] *= inv;
}

// ------------------------------------------------- PV GEMM with K-split
// grid (TCHUNK/64, DIM/64, 4); K-slice = 1024
__global__ __launch_bounds__(256) void k_pv(
    const float* __restrict__ p, const float* __restrict__ vb, float* __restrict__ part)
{
    __shared__ float As[16][68];
    __shared__ float Bs[16][68];
    const int tid = threadIdx.x;
    const int tx = tid & 15, ty = tid >> 4;
    const int row0 = blockIdx.x * 64;
    const int col0 = blockIdx.y * 64;
    const int k0 = blockIdx.z * 1024;
    const int lm = tid >> 2;
    const int lk = (tid & 3) * 4;
    const int br = tid >> 4;          // 0..15
    const int bc = (tid & 15) * 4;    // 0..60

    float acc[4][4] = {};
    for (int kk = 0; kk < 1024; kk += 16) {
        float4 a4 = *(const float4*)&p[(size_t)(row0 + lm) * NSLOT + k0 + kk + lk];
        float4 b4 = *(const float4*)&vb[(size_t)(k0 + kk + br) * DIM + col0 + bc];
        __syncthreads();
        As[lk+0][lm] = a4.x; As[lk+1][lm] = a4.y; As[lk+2][lm] = a4.z; As[lk+3][lm] = a4.w;
        *(float4*)&Bs[br][bc] = b4;
        __syncthreads();
        #pragma unroll
        for (int k = 0; k < 16; k++) {
            float4 av = *(const float4*)&As[k][ty*4];
            float4 bv2 = *(const float4*)&Bs[k][tx*4];
            float aa[4] = {av.x, av.y, av.z, av.w};
            float bb[4] = {bv2.x, bv2.y, bv2.z, bv2.w};
            #pragma unroll
            for (int i = 0; i < 4; i++)
                #pragma unroll
                for (int j = 0; j < 4; j++)
                    acc[i][j] += aa[i] * bb[j];
        }
    }
    #pragma unroll
    for (int i = 0; i < 4; i++)
        #pragma unroll
        for (int j = 0; j < 4; j++)
            part[(size_t)blockIdx.z * TCHUNK * DIM + (size_t)(row0 + ty*4 + i) * DIM + col0 + tx*4 + j] = acc[i][j];
}

__global__ void k_pvsum(const float* __restrict__ part, float* __restrict__ out, int t0) {
    int idx = blockIdx.x * 256 + threadIdx.x;
    if (idx >= TCHUNK * DIM) return;
    float s = part[idx] + part[TCHUNK*DIM + idx] + part[2*TCHUNK*DIM + idx] + part[3*TCHUNK*DIM + idx];
    out[(size_t)t0 * DIM + idx] = s;
}

// ================================================================ launch
extern "C" void kernel_launch(void* const* d_in, const int* in_sizes, int n_in,
                              void* d_out, int out_size, void* d_ws, size_t ws_size,
                              hipStream_t stream)
{
    (void)in_sizes; (void)n_in; (void)out_size; (void)ws_size;
    const float* x       = (const float*)d_in[0];
    const unsigned char* mask = (const unsigned char*)d_in[1];
    const float* keys0   = (const float*)d_in[2];
    const float* values0 = (const float*)d_in[3];
    const float* act0    = (const float*)d_in[4];
    const float* Wk = (const float*)d_in[5];
    const float* bk = (const float*)d_in[6];
    const float* Wv = (const float*)d_in[7];
    const float* bv = (const float*)d_in[8];
    const float* Wq = (const float*)d_in[9];
    const float* bq = (const float*)d_in[10];
    float* out = (float*)d_out;

    // workspace carve-up (~74 MB total)
    uint8_t* w = (uint8_t*)d_ws;
    size_t off = 0;
    auto alloc = [&](size_t bytes) -> void* {
        void* p = w + off;
        off = (off + bytes + 255) & ~(size_t)255;
        return p;
    };
    float* ka      = (float*)alloc((size_t)TTOK * DIM * 4);
    float* va_     = (float*)alloc((size_t)TTOK * DIM * 4);
    float* qa      = (float*)alloc((size_t)TTOK * DIM * 4);
    float* kb      = (float*)alloc((size_t)NSLOT * DIM * 4);
    float* vb      = (float*)alloc((size_t)NSLOT * DIM * 4);
    float* logits  = (float*)alloc((size_t)TCHUNK * NSLOT * 4);
    float* pvpart  = (float*)alloc((size_t)4 * TCHUNK * DIM * 4);
    float* partV   = (float*)alloc((size_t)4 * TTOK * 4);
    int*   partI   = (int*)  alloc((size_t)4 * TTOK * 4);
    float* act_f   = (float*)alloc((size_t)NSLOT * 4);
    int*   best    = (int*)  alloc((size_t)TTOK * 4);
    int*   novel   = (int*)  alloc((size_t)TTOK * 4);
    int*   slot_seq= (int*)  alloc((size_t)TTOK * 4);
    int*   rankis  = (int*)  alloc((size_t)TTOK * 4);
    int*   cnt     = (int*)  alloc((size_t)NSLOT * 4);
    int*   offs    = (int*)  alloc((size_t)NSLOT * 4);
    int*   listTok = (int*)  alloc((size_t)TTOK * 4);
    u64*   cand    = (u64*)  alloc((size_t)CAPC * 8);
    int*   candJ   = (int*)  alloc((size_t)CAPC * 4);
    int*   misc    = (int*)  alloc(64);

    k_init<<<17, 256, 0, stream>>>(cnt, misc);
    k_proj<<<dim3(TTOK/64, DIM/64, 3), 256, 0, stream>>>(x, Wk, bk, Wv, bv, Wq, bq, ka, va_, qa);
    k_simmax<<<dim3(TTOK/64, 4), 256, 0, stream>>>(ka, keys0, partV, partI);
    k_bestmerge<<<TTOK/256, 256, 0, stream>>>(partV, partI, best, novel, misc);
    k_flags<<<TTOK/256, 256, 0, stream>>>(mask, act0, misc);
    k_ladder<<<NSLOT/256, 256, 0, stream>>>(act0, cand, candJ, misc);
    k_finalize<<<1, 1, 0, stream>>>(misc);
    k_rank<<<CAPC/256, 256, 0, stream>>>(cand, candJ, slot_seq, rankis, cnt, misc);
    k_actfinal<<<NSLOT/256, 256, 0, stream>>>(act0, cnt, act_f, misc);
    k_serial<<<1, 64, 0, stream>>>(novel, best, mask, act0, misc, slot_seq, rankis, cnt, act_f);
    k_offsets<<<1, 256, 0, stream>>>(cnt, offs);
    k_scatter<<<TTOK/256, 256, 0, stream>>>(slot_seq, rankis, offs, listTok);
    k_apply<<<NSLOT, 256, 0, stream>>>(keys0, values0, ka, va_, novel, cnt, offs, listTok, kb, vb);

    for (int c = 0; c < TTOK / TCHUNK; c++) {
        int t0 = c * TCHUNK;
        k_logits<<<dim3(TCHUNK/64, NSLOT/64), 256, 0, stream>>>(qa, kb, act_f, logits, t0);
        k_softmax<<<TCHUNK, 256, 0, stream>>>(logits);
        k_pv<<<dim3(TCHUNK/64, DIM/64, 4), 256, 0, stream>>>(logits, vb, pvpart);
        k_pvsum<<<TCHUNK*DIM/256, 256, 0, stream>>>(pvpart, out, t0);
    }
}

// Round 2
// 912.797 us; speedup vs baseline: 1.5217x; 1.5217x over previous
//
#include <hip/hip_runtime.h>
#include <hip/hip_bf16.h>
#include <math.h>
#include <stdint.h>

// Problem constants (B=8,S=1024,D=256,N=4096)
#define TTOK 8192
#define DIM 256
#define NSLOT 4096
#define TCHUNK 2048
#define CAPC 65536
#define SCALE 0.0625f     // 1/sqrt(256), exact

typedef unsigned long long u64;
typedef unsigned short ushort_t;
typedef __attribute__((ext_vector_type(8))) __bf16 bf16x8;
typedef __attribute__((ext_vector_type(4))) float f32x4;

__device__ inline ushort_t f2bf(float f) {
    unsigned u = __float_as_uint(f);
    unsigned r = (u + 0x7fffu + ((u >> 16) & 1u)) >> 16;   // RNE
    return (ushort_t)r;
}

// misc[0]=cand count, misc[1]=flagA, misc[2]=flagB, misc[3]=fast-path valid

// ---------------------------------------------------------------- init
__global__ void k_init(int* cnt, int* misc) {
    int t = blockIdx.x * 256 + threadIdx.x;
    if (t < NSLOT) cnt[t] = 0;
    if (t == 0) { misc[0] = 0; misc[1] = 1; misc[2] = 1; misc[3] = 0; }
}

// ------------------------------------------------- projections (fp32, exact)
__global__ __launch_bounds__(256) void k_proj(
    const float* __restrict__ x,
    const float* __restrict__ Wk, const float* __restrict__ bk,
    const float* __restrict__ Wv, const float* __restrict__ bv,
    const float* __restrict__ Wq, const float* __restrict__ bq,
    float* __restrict__ ka, float* __restrict__ va, float* __restrict__ qa)
{
    const float* W; const float* bias; float* out;
    if (blockIdx.z == 0)      { W = Wk; bias = bk; out = ka; }
    else if (blockIdx.z == 1) { W = Wv; bias = bv; out = va; }
    else                      { W = Wq; bias = bq; out = qa; }

    __shared__ float As[16][68];
    __shared__ float Bs[16][68];
    const int tid = threadIdx.x;
    const int tx = tid & 15, ty = tid >> 4;
    const int row0 = blockIdx.x * 64;
    const int col0 = blockIdx.y * 64;
    const int lm = tid >> 2;
    const int lk = (tid & 3) * 4;

    float acc[4][4] = {};
    for (int kk = 0; kk < DIM; kk += 16) {
        float4 a4 = *(const float4*)&x[(size_t)(row0 + lm) * DIM + kk + lk];
        float4 b4 = *(const float4*)&W[(size_t)(col0 + lm) * DIM + kk + lk];
        __syncthreads();
        As[lk+0][lm] = a4.x; As[lk+1][lm] = a4.y; As[lk+2][lm] = a4.z; As[lk+3][lm] = a4.w;
        Bs[lk+0][lm] = b4.x; Bs[lk+1][lm] = b4.y; Bs[lk+2][lm] = b4.z; Bs[lk+3][lm] = b4.w;
        __syncthreads();
        #pragma unroll
        for (int k = 0; k < 16; k++) {
            float4 av = *(const float4*)&As[k][ty*4];
            float4 bv2 = *(const float4*)&Bs[k][tx*4];
            float aa[4] = {av.x, av.y, av.z, av.w};
            float bb[4] = {bv2.x, bv2.y, bv2.z, bv2.w};
            #pragma unroll
            for (int i = 0; i < 4; i++)
                #pragma unroll
                for (int j = 0; j < 4; j++)
                    acc[i][j] += aa[i] * bb[j];
        }
    }
    #pragma unroll
    for (int j = 0; j < 4; j++) {
        float bj = bias[col0 + tx*4 + j];
        #pragma unroll
        for (int i = 0; i < 4; i++)
            out[(size_t)(row0 + ty*4 + i) * DIM + col0 + tx*4 + j] = acc[i][j] + bj;
    }
}

// ---------------------------------------------------------------- fp32->bf16 cast
__global__ void k_cast(const float* __restrict__ in, ushort_t* __restrict__ out, int n) {
    int i = (blockIdx.x * 256 + threadIdx.x) * 4;
    if (i >= n) return;
    float4 v = *(const float4*)&in[i];
    ushort4 o;
    o.x = f2bf(v.x); o.y = f2bf(v.y); o.z = f2bf(v.z); o.w = f2bf(v.w);
    *(ushort4*)&out[i] = o;
}

// ---------------------------------------------------------------- vb -> vbT (bf16)
__global__ __launch_bounds__(256) void k_transV(const float* __restrict__ vb, ushort_t* __restrict__ vbT) {
    __shared__ float ts[32][33];
    int tx = threadIdx.x & 31, ty = threadIdx.x >> 5;   // ty 0..7
    int s0 = blockIdx.x * 32, d0 = blockIdx.y * 32;
    #pragma unroll
    for (int j = 0; j < 4; j++)
        ts[ty + j*8][tx] = vb[(size_t)(s0 + ty + j*8) * DIM + d0 + tx];
    __syncthreads();
    #pragma unroll
    for (int j = 0; j < 4; j++)
        vbT[(size_t)(d0 + ty + j*8) * NSLOT + s0 + tx] = f2bf(ts[tx][ty + j*8]);
}

// =============================================================== MFMA GEMM
// C[row][col] = sum_k A[row][k]*B[col][k]; A,B bf16 row-major.
// 128x128 tile, BK=64, 4 waves (2x2 of 64x64), XOR-swizzled LDS.
// MODE 0: simmax  -> per-row max/argmax over this col-block -> partV/partI[by][grow]
// MODE 1: logits  -> outF[grow*4096+gcol] = dead?-inf : acc*SCALE+log(act)
// MODE 2: pv      -> outF[(bz*2048+grow)*256+gcol] = acc (fp32 partial)
template<int MODE>
__global__ __launch_bounds__(256) void k_mm(
    const ushort_t* __restrict__ A, const ushort_t* __restrict__ B,
    int lda, int ldb, int rowA_off, int ksteps,
    float* __restrict__ outF, int* __restrict__ outI,
    const float* __restrict__ actf)
{
    __shared__ ushort_t sA[128 * 64];
    __shared__ ushort_t sB[128 * 64];
    const int tid = threadIdx.x;
    const int lane = tid & 63;
    const int w = tid >> 6;
    const int wr = w >> 1, wc = w & 1;
    const int lr = lane & 15, lg = lane >> 4;
    const int bx = blockIdx.x, by = blockIdx.y;
    const int kbase = blockIdx.z * ksteps * 64;
    const int rA0 = rowA_off + bx * 128;
    const int rB0 = by * 128;
    const int ex = (tid & 7) * 8;   // element offset of this thread's 16B within a 64-elem row
    const int rsub = tid >> 3;      // 0..31

    f32x4 acc[4][4] = {};
    uint4 ra[4], rb[4];

    {   // prologue: load K-step 0
        #pragma unroll
        for (int j = 0; j < 4; j++) {
            int row = j * 32 + rsub;
            ra[j] = *(const uint4*)&A[(size_t)(rA0 + row) * lda + kbase + ex];
            rb[j] = *(const uint4*)&B[(size_t)(rB0 + row) * ldb + kbase + ex];
        }
    }
    for (int step = 0; step < ksteps; step++) {
        __syncthreads();
        #pragma unroll
        for (int j = 0; j < 4; j++) {
            int row = j * 32 + rsub;
            int xi = ex ^ ((row & 7) << 3);
            *(uint4*)&sA[row * 64 + xi] = ra[j];
            *(uint4*)&sB[row * 64 + xi] = rb[j];
        }
        __syncthreads();
        if (step + 1 < ksteps) {
            int k0 = kbase + (step + 1) * 64;
            #pragma unroll
            for (int j = 0; j < 4; j++) {
                int row = j * 32 + rsub;
                ra[j] = *(const uint4*)&A[(size_t)(rA0 + row) * lda + k0 + ex];
                rb[j] = *(const uint4*)&B[(size_t)(rB0 + row) * ldb + k0 + ex];
            }
        }
        #pragma unroll
        for (int h = 0; h < 2; h++) {
            int xs = (h * 32 + lg * 8) ^ ((lr & 7) << 3);
            bf16x8 aF[4], bF[4];
            #pragma unroll
            for (int m = 0; m < 4; m++)
                aF[m] = *(const bf16x8*)&sA[(wr * 64 + m * 16 + lr) * 64 + xs];
            #pragma unroll
            for (int n = 0; n < 4; n++)
                bF[n] = *(const bf16x8*)&sB[(wc * 64 + n * 16 + lr) * 64 + xs];
            #pragma unroll
            for (int m = 0; m < 4; m++)
                #pragma unroll
                for (int n = 0; n < 4; n++)
                    acc[m][n] = __builtin_amdgcn_mfma_f32_16x16x32_bf16(aF[m], bF[n], acc[m][n], 0, 0, 0);
        }
    }

    // ---------------- epilogue ----------------
    if (MODE == 0) {
        #pragma unroll
        for (int m = 0; m < 4; m++) {
            #pragma unroll
            for (int r = 0; r < 4; r++) {
                float bv = acc[m][0][r];
                int bi = by * 128 + wc * 64 + lr;
                #pragma unroll
                for (int n = 1; n < 4; n++) {
                    float v = acc[m][n][r];
                    int c = by * 128 + wc * 64 + n * 16 + lr;
                    if (v > bv) { bv = v; bi = c; }
                }
                #pragma unroll
                for (int off = 1; off < 16; off <<= 1) {
                    float ov = __shfl_xor(bv, off);
                    int oi = __shfl_xor(bi, off);
                    if (ov > bv || (ov == bv && oi < bi)) { bv = ov; bi = oi; }
                }
                if (lr == 0) {
                    int grow = bx * 128 + wr * 64 + m * 16 + lg * 4 + r;
                    outF[(size_t)by * TTOK + grow] = bv;
                    outI[(size_t)by * TTOK + grow] = bi;
                }
            }
        }
    } else if (MODE == 1) {
        #pragma unroll
        for (int n = 0; n < 4; n++) {
            int gcol = by * 128 + wc * 64 + n * 16 + lr;
            float a = actf[gcol];
            float lgv = logf(fmaxf(a, 1e-8f));
            bool dead = (a < 0.01f);
            #pragma unroll
            for (int m = 0; m < 4; m++)
                #pragma unroll
                for (int r = 0; r < 4; r++) {
                    int grow = bx * 128 + wr * 64 + m * 16 + lg * 4 + r;
                    outF[(size_t)grow * NSLOT + gcol] =
                        dead ? -INFINITY : acc[m][n][r] * SCALE + lgv;
                }
        }
    } else {
        #pragma unroll
        for (int m = 0; m < 4; m++)
            #pragma unroll
            for (int r = 0; r < 4; r++) {
                int grow = bx * 128 + wr * 64 + m * 16 + lg * 4 + r;
                #pragma unroll
                for (int n = 0; n < 4; n++) {
                    int gcol = by * 128 + wc * 64 + n * 16 + lr;
                    outF[((size_t)blockIdx.z * TCHUNK + grow) * DIM + gcol] = acc[m][n][r];
                }
            }
    }
}

// ---------------------------------------------------------------- merge 32 partials
__global__ void k_bestmerge(const float* partV, const int* partI,
                            int* best, int* novel, int* misc) {
    int t = blockIdx.x * 256 + threadIdx.x;
    if (t >= TTOK) return;
    float bv = partV[t]; int bi = partI[t];
    #pragma unroll
    for (int q = 1; q < 32; q++) {
        float v = partV[(size_t)q * TTOK + t];
        int i = partI[(size_t)q * TTOK + t];
        if (v > bv || (v == bv && i < bi)) { bv = v; bi = i; }
    }
    best[t] = bi;
    int nv = (bv * SCALE < 0.5f) ? 1 : 0;
    novel[t] = nv;
    if (!nv) atomicAnd(&misc[1], 0);
}

// --------------------------------------------------------------- flags
__global__ void k_flags(const unsigned char* maskraw, const float* act0, int* misc) {
    int t = blockIdx.x * 256 + threadIdx.x;
    int u8 = (maskraw[1] == 1);
    if (t < TTOK) {
        int mv = u8 ? (int)maskraw[t] : ((const int*)maskraw)[t];
        if (mv == 0) atomicAnd(&misc[1], 0);
    }
    if (t < NSLOT) {
        float a = act0[t];
        if (!(a >= 0.0f)) atomicAnd(&misc[1], 0);
    }
}

// ------------------------------------------------- ladder candidate generation
__global__ void k_ladder(const float* act0, u64* cand, int* candJ, int* misc) {
    if (misc[1] == 0) return;
    int i = blockIdx.x * 256 + threadIdx.x;
    if (i >= NSLOT) return;
    float w = act0[i];
    int j = 0;
    while (w < 1.0f) {
        if (j >= 48) { atomicAnd(&misc[2], 0); break; }
        int pos = atomicAdd(&misc[0], 1);
        if (pos >= CAPC) { atomicAnd(&misc[2], 0); break; }
        cand[pos] = ((u64)__float_as_uint(w) << 32) | (unsigned)i;
        candJ[pos] = j;
        j++;
        w = fminf(1.0f, w + 0.1f);
    }
}

__global__ void k_finalize(int* misc) {
    misc[3] = (misc[1] && misc[2] && misc[0] >= TTOK) ? 1 : 0;
}

// ------------------------------------------------- rank candidates
__global__ __launch_bounds__(256) void k_rank(
    const u64* __restrict__ cand, const int* __restrict__ candJ,
    int* slot_seq, int* rankis, int* cnt, const int* misc)
{
    if (!(misc[1] && misc[2])) return;
    int K = misc[0]; if (K > CAPC) K = CAPC;
    if ((int)blockIdx.x * 256 >= K) return;
    int tid = blockIdx.x * 256 + threadIdx.x;
    u64 my = (tid < K) ? cand[tid] : ~0ull;
    int rank = 0;
    __shared__ u64 ch[2048];
    for (int base = 0; base < K; base += 2048) {
        int len = min(2048, K - base);
        __syncthreads();
        for (int i = threadIdx.x; i < len; i += 256) ch[i] = cand[base + i];
        __syncthreads();
        if (tid < K) {
            #pragma unroll 8
            for (int i = 0; i < len; i++) rank += (ch[i] < my) ? 1 : 0;
        }
    }
    if (tid < K && rank < TTOK) {
        int slot = (int)(my & 0xffffffffu);
        slot_seq[rank] = slot;
        rankis[rank] = candJ[tid];
        atomicAdd(&cnt[slot], 1);
    }
}

__global__ void k_actfinal(const float* act0, const int* cnt, float* act_f, const int* misc) {
    if (!misc[3]) return;
    int i = blockIdx.x * 256 + threadIdx.x;
    if (i >= NSLOT) return;
    float a = act0[i];
    int m = cnt[i];
    for (int r = 0; r < m; r++) a = fminf(1.0f, a + 0.1f);
    act_f[i] = a;
}

// ------------------------------------------------- serial fallback (cold path)
__global__ __launch_bounds__(64) void k_serial(
    const int* novel, const int* best, const unsigned char* maskraw,
    const float* act0, const int* misc,
    int* slot_seq, int* rankis, int* cnt, float* act_f)
{
    if (misc[3]) return;
    __shared__ float act[NSLOT];
    __shared__ int cntL[NSLOT];
    const int lane = threadIdx.x;
    const int u8 = (maskraw[1] == 1);
    for (int i = lane; i < NSLOT; i += 64) { act[i] = act0[i]; cntL[i] = 0; }
    __syncthreads();
    float cv; int ci;
    {
        cv = act[lane * 64]; ci = lane * 64;
        for (int u = 1; u < 64; u++) {
            float v = act[lane * 64 + u];
            if (v < cv) { cv = v; ci = lane * 64 + u; }
        }
    }
    for (int t = 0; t < TTOK; t++) {
        int nv = novel[t];
        int mk = (u8 ? (int)maskraw[t] : ((const int*)maskraw)[t]) != 0;
        int slot;
        if (nv) {
            float v = cv; int ix = ci;
            for (int off = 32; off >= 1; off >>= 1) {
                float ov = __shfl_xor(v, off);
                int oi = __shfl_xor(ix, off);
                if (ov < v || (ov == v && oi < ix)) { v = ov; ix = oi; }
            }
            slot = ix;
        } else {
            slot = best[t];
        }
        if (mk) {
            float a = act[slot];
            float a2 = fminf(1.0f, a + 0.1f);
            __syncthreads();
            if (lane == 0) {
                act[slot] = a2;
                slot_seq[t] = slot;
                int r = cntL[slot]; rankis[t] = r; cntL[slot] = r + 1;
            }
            __syncthreads();
            int c = slot >> 6;
            float v = act[c * 64 + lane]; int ix = c * 64 + lane;
            for (int off = 32; off >= 1; off >>= 1) {
                float ov = __shfl_xor(v, off);
                int oi = __shfl_xor(ix, off);
                if (ov < v || (ov == v && oi < ix)) { v = ov; ix = oi; }
            }
            if (lane == c) { cv = v; ci = ix; }
        } else {
            if (lane == 0) rankis[t] = -1;
        }
        __syncthreads();
    }
    for (int i = lane; i < NSLOT; i += 64) { cnt[i] = cntL[i]; act_f[i] = act[i]; }
}

// ------------------------------------------------- CSR build
__global__ __launch_bounds__(256) void k_offsets(const int* cnt, int* offs) {
    __shared__ int part[256];
    int tid = threadIdx.x;
    int base = tid * 16;
    int loc[16];
    int s = 0;
    #pragma unroll
    for (int i = 0; i < 16; i++) { loc[i] = s; s += cnt[base + i]; }
    part[tid] = s;
    __syncthreads();
    for (int off = 1; off < 256; off <<= 1) {
        int v = (tid >= off) ? part[tid - off] : 0;
        __syncthreads();
        part[tid] += v;
        __syncthreads();
    }
    int pre = (tid == 0) ? 0 : part[tid - 1];
    #pragma unroll
    for (int i = 0; i < 16; i++) offs[base + i] = pre + loc[i];
}

__global__ void k_scatter(const int* slot_seq, const int* rankis, const int* offs, int* listTok) {
    int t = blockIdx.x * 256 + threadIdx.x;
    if (t >= TTOK) return;
    int r = rankis[t];
    if (r >= 0) listTok[offs[slot_seq[t]] + r] = t;
}

// ------------------------------------------------- apply buffer writes per slot
__global__ __launch_bounds__(256) void k_apply(
    const float* __restrict__ keys0, const float* __restrict__ values0,
    const float* __restrict__ ka, const float* __restrict__ va,
    const int* __restrict__ novel, const int* __restrict__ cnt,
    const int* __restrict__ offs, const int* __restrict__ listTok,
    float* __restrict__ kb, float* __restrict__ vb)
{
    int s = blockIdx.x;
    int d = threadIdx.x;
    float kv = keys0[(size_t)s * DIM + d];
    float vv = values0[(size_t)s * DIM + d];
    int m = cnt[s], off = offs[s];
    for (int r = 0; r < m; r++) {
        int t = listTok[off + r];
        float al = novel[t] ? 0.9f : 0.3f;
        kv = (1.0f - al) * kv + al * ka[(size_t)t * DIM + d];
        vv = (1.0f - al) * vv + al * va[(size_t)t * DIM + d];
    }
    kb[(size_t)s * DIM + d] = kv;
    vb[(size_t)s * DIM + d] = vv;
}

// ------------------------------------------------- row softmax: fp32 in, bf16 out
__global__ __launch_bounds__(256) void k_softmax(float* __restrict__ logits, ushort_t* __restrict__ pbf) {
    float* row = logits + (size_t)blockIdx.x * NSLOT;
    ushort_t* orow = pbf + (size_t)blockIdx.x * NSLOT;
    __shared__ float sd[256];
    int tid = threadIdx.x;
    float m = -INFINITY;
    for (int i = tid; i < NSLOT; i += 256) m = fmaxf(m, row[i]);
    sd[tid] = m; __syncthreads();
    for (int off = 128; off >= 1; off >>= 1) {
        if (tid < off) sd[tid] = fmaxf(sd[tid], sd[tid + off]);
        __syncthreads();
    }
    m = sd[0]; __syncthreads();
    float s = 0.0f;
    for (int i = tid; i < NSLOT; i += 256) {
        float e = expf(row[i] - m);
        row[i] = e;
        s += e;
    }
    sd[tid] = s; __syncthreads();
    for (int off = 128; off >= 1; off >>= 1) {
        if (tid < off) sd[tid] += sd[tid + off];
        __syncthreads();
    }
    float inv = 1.0f / sd[0];
    for (int i = tid; i < NSLOT; i += 256) orow[i] = f2bf(row[i] * inv);
}

// ------------------------------------------------- sum 8 PV partials
__global__ void k_pvsum(const float* __restrict__ part, float* __restrict__ out, int t0) {
    int idx = blockIdx.x * 256 + threadIdx.x;
    float s = 0.0f;
    #pragma unroll
    for (int z = 0; z < 8; z++) s += part[(size_t)z * TCHUNK * DIM + idx];
    out[(size_t)t0 * DIM + idx] = s;
}

// ================================================================ launch
extern "C" void kernel_launch(void* const* d_in, const int* in_sizes, int n_in,
                              void* d_out, int out_size, void* d_ws, size_t ws_size,
                              hipStream_t stream)
{
    (void)in_sizes; (void)n_in; (void)out_size; (void)ws_size;
    const float* x       = (const float*)d_in[0];
    const unsigned char* mask = (const unsigned char*)d_in[1];
    const float* keys0   = (const float*)d_in[2];
    const float* values0 = (const float*)d_in[3];
    const float* act0    = (const float*)d_in[4];
    const float* Wk = (const float*)d_in[5];
    const float* bk = (const float*)d_in[6];
    const float* Wv = (const float*)d_in[7];
    const float* bv = (const float*)d_in[8];
    const float* Wq = (const float*)d_in[9];
    const float* bq = (const float*)d_in[10];
    float* out = (float*)d_out;

    uint8_t* w = (uint8_t*)d_ws;
    size_t off = 0;
    auto alloc = [&](size_t bytes) -> void* {
        void* p = w + off;
        off = (off + bytes + 255) & ~(size_t)255;
        return p;
    };
    float*    ka     = (float*)   alloc((size_t)TTOK * DIM * 4);
    float*    va_    = (float*)   alloc((size_t)TTOK * DIM * 4);
    float*    qa     = (float*)   alloc((size_t)TTOK * DIM * 4);
    float*    kb     = (float*)   alloc((size_t)NSLOT * DIM * 4);
    float*    vb     = (float*)   alloc((size_t)NSLOT * DIM * 4);
    ushort_t* ka_bf  = (ushort_t*)alloc((size_t)TTOK * DIM * 2);
    ushort_t* qa_bf  = (ushort_t*)alloc((size_t)TTOK * DIM * 2);
    ushort_t* k0_bf  = (ushort_t*)alloc((size_t)NSLOT * DIM * 2);
    ushort_t* kb_bf  = (ushort_t*)alloc((size_t)NSLOT * DIM * 2);
    ushort_t* vbT    = (ushort_t*)alloc((size_t)DIM * NSLOT * 2);
    float*    logits = (float*)   alloc((size_t)TCHUNK * NSLOT * 4);   // pvpart aliases this
    ushort_t* p_bf   = (ushort_t*)alloc((size_t)TCHUNK * NSLOT * 2);
    float*    partV  = (float*)   alloc((size_t)32 * TTOK * 4);
    int*      partI  = (int*)     alloc((size_t)32 * TTOK * 4);
    float*    act_f  = (float*)   alloc((size_t)NSLOT * 4);
    int*      best   = (int*)     alloc((size_t)TTOK * 4);
    int*      novel  = (int*)     alloc((size_t)TTOK * 4);
    int*      slot_seq = (int*)   alloc((size_t)TTOK * 4);
    int*      rankis = (int*)     alloc((size_t)TTOK * 4);
    int*      cnt    = (int*)     alloc((size_t)NSLOT * 4);
    int*      offs   = (int*)     alloc((size_t)NSLOT * 4);
    int*      listTok= (int*)     alloc((size_t)TTOK * 4);
    u64*      cand   = (u64*)     alloc((size_t)CAPC * 8);
    int*      candJ  = (int*)     alloc((size_t)CAPC * 4);
    int*      misc   = (int*)     alloc(64);
    float*    pvpart = logits;    // alias: logits dead once softmax has read it

    k_init<<<17, 256, 0, stream>>>(cnt, misc);
    k_proj<<<dim3(TTOK/64, DIM/64, 3), 256, 0, stream>>>(x, Wk, bk, Wv, bv, Wq, bq, ka, va_, qa);
    k_cast<<<TTOK*DIM/1024, 256, 0, stream>>>(ka, ka_bf, TTOK*DIM);
    k_cast<<<TTOK*DIM/1024, 256, 0, stream>>>(qa, qa_bf, TTOK*DIM);
    k_cast<<<NSLOT*DIM/1024, 256, 0, stream>>>(keys0, k0_bf, NSLOT*DIM);

    k_mm<0><<<dim3(TTOK/128, NSLOT/128, 1), 256, 0, stream>>>(
        ka_bf, k0_bf, DIM, DIM, 0, DIM/64, partV, partI, nullptr);
    k_bestmerge<<<TTOK/256, 256, 0, stream>>>(partV, partI, best, novel, misc);

    k_flags<<<TTOK/256, 256, 0, stream>>>(mask, act0, misc);
    k_ladder<<<NSLOT/256, 256, 0, stream>>>(act0, cand, candJ, misc);
    k_finalize<<<1, 1, 0, stream>>>(misc);
    k_rank<<<CAPC/256, 256, 0, stream>>>(cand, candJ, slot_seq, rankis, cnt, misc);
    k_actfinal<<<NSLOT/256, 256, 0, stream>>>(act0, cnt, act_f, misc);
    k_serial<<<1, 64, 0, stream>>>(novel, best, mask, act0, misc, slot_seq, rankis, cnt, act_f);
    k_offsets<<<1, 256, 0, stream>>>(cnt, offs);
    k_scatter<<<TTOK/256, 256, 0, stream>>>(slot_seq, rankis, offs, listTok);
    k_apply<<<NSLOT, 256, 0, stream>>>(keys0, values0, ka, va_, novel, cnt, offs, listTok, kb, vb);

    k_cast<<<NSLOT*DIM/1024, 256, 0, stream>>>(kb, kb_bf, NSLOT*DIM);
    k_transV<<<dim3(NSLOT/32, DIM/32), 256, 0, stream>>>(vb, vbT);

    for (int c = 0; c < TTOK / TCHUNK; c++) {
        int t0 = c * TCHUNK;
        k_mm<1><<<dim3(TCHUNK/128, NSLOT/128, 1), 256, 0, stream>>>(
            qa_bf, kb_bf, DIM, DIM, t0, DIM/64, logits, nullptr, act_f);
        k_softmax<<<TCHUNK, 256, 0, stream>>>(logits, p_bf);
        k_mm<2><<<dim3(TCHUNK/128, DIM/128, 8), 256, 0, stream>>>(
            p_bf, vbT, NSLOT, NSLOT, 0, 8, pvpart, nullptr, nullptr);
        k_pvsum<<<TCHUNK*DIM/256, 256, 0, stream>>>(pvpart, out, t0);
    }
}

// Round 3
// 669.327 us; speedup vs baseline: 2.0752x; 1.3638x over previous
//
#include <hip/hip_runtime.h>
#include <hip/hip_bf16.h>
#include <math.h>
#include <stdint.h>

// Problem constants (B=8,S=1024,D=256,N=4096)
#define TTOK 8192
#define DIM 256
#define NSLOT 4096
#define TCHUNK 2048
#define CAPC 65536
#define NBUCK 65536
#define SCALE 0.0625f     // 1/sqrt(256), exact

typedef unsigned long long u64;
typedef unsigned short ushort_t;
typedef __attribute__((ext_vector_type(8))) __bf16 bf16x8;
typedef __attribute__((ext_vector_type(4))) float f32x4;

__device__ inline ushort_t f2bf(float f) {
    unsigned u = __float_as_uint(f);
    unsigned r = (u + 0x7fffu + ((u >> 16) & 1u)) >> 16;   // RNE
    return (ushort_t)r;
}
__device__ inline int bucketof(float w) {
    int b = (int)(w * 65536.0f);
    return b > 65535 ? 65535 : b;
}

// misc[0]=cand count, misc[1]=flagA, misc[2]=flagB, misc[3]=fast-path valid

// ---------------------------------------------------------------- init
__global__ void k_init(int* cnt, int* misc) {
    int t = blockIdx.x * 256 + threadIdx.x;
    if (t < NSLOT) cnt[t] = 0;
    if (t == 0) { misc[0] = 0; misc[1] = 1; misc[2] = 1; misc[3] = 0; }
}
__global__ void k_zero2(int* hist, int* cnt2) {
    int i = blockIdx.x * 256 + threadIdx.x;   // grid 256 -> 65536 threads
    hist[i] = 0; cnt2[i] = 0;
}

// ------------------------------------------- split fp32 -> [hi|lo] bf16 (K doubled)
// out2 row-major [rows][512]: cols 0..255 = hi, 256..511 = lo
__global__ void k_split(const float* __restrict__ in, ushort_t* __restrict__ out2, int rows) {
    int i = blockIdx.x * 256 + threadIdx.x;
    if (i >= rows * 256) return;
    int t = i >> 8, k = i & 255;
    float v = in[i];
    ushort_t h = f2bf(v);
    float hf = __uint_as_float(((unsigned)h) << 16);
    ushort_t l = f2bf(v - hf);
    out2[(size_t)t * 512 + k] = h;
    out2[(size_t)t * 512 + 256 + k] = l;
}

// ---------------------------------------------------------------- fp32->bf16 cast
__global__ void k_cast(const float* __restrict__ in, ushort_t* __restrict__ out, int n) {
    int i = (blockIdx.x * 256 + threadIdx.x) * 4;
    if (i >= n) return;
    float4 v = *(const float4*)&in[i];
    ushort4 o;
    o.x = f2bf(v.x); o.y = f2bf(v.y); o.z = f2bf(v.z); o.w = f2bf(v.w);
    *(ushort4*)&out[i] = o;
}

// ---------------------------------------------------------------- vb -> vbT (bf16)
__global__ __launch_bounds__(256) void k_transV(const float* __restrict__ vb, ushort_t* __restrict__ vbT) {
    __shared__ float ts[32][33];
    int tx = threadIdx.x & 31, ty = threadIdx.x >> 5;   // ty 0..7
    int s0 = blockIdx.x * 32, d0 = blockIdx.y * 32;
    #pragma unroll
    for (int j = 0; j < 4; j++)
        ts[ty + j*8][tx] = vb[(size_t)(s0 + ty + j*8) * DIM + d0 + tx];
    __syncthreads();
    #pragma unroll
    for (int j = 0; j < 4; j++)
        vbT[(size_t)(d0 + ty + j*8) * NSLOT + s0 + tx] = f2bf(ts[tx][ty + j*8]);
}

// =============================================================== MFMA GEMM
// C[row][col] = sum_k A[row][k]*B[col][k]; A,B bf16 row-major.
// 128x128 tile, BK=64, 4 waves (2x2 of 64x64), XOR-swizzled LDS.
// MODE 0: simmax -> per-row max/argmax over col-block -> partV/partI[by][grow]
// MODE 1: logits -> outF[grow*4096+gcol] = dead?-inf : acc*SCALE+log(act)
// MODE 2: pv     -> outF[(bz*2048+grow)*256+gcol] = acc (fp32 partial)
// MODE 3: proj   -> outF[grow*256+gcol] = acc + bias(actf); optional bf16 copy via outI
template<int MODE>
__global__ __launch_bounds__(256) void k_mm(
    const ushort_t* __restrict__ A, const ushort_t* __restrict__ B,
    int lda, int ldb, int rowA_off, int ksteps,
    float* __restrict__ outF, int* __restrict__ outI,
    const float* __restrict__ actf)
{
    __shared__ ushort_t sA[128 * 64];
    __shared__ ushort_t sB[128 * 64];
    const int tid = threadIdx.x;
    const int lane = tid & 63;
    const int w = tid >> 6;
    const int wr = w >> 1, wc = w & 1;
    const int lr = lane & 15, lg = lane >> 4;
    const int bx = blockIdx.x, by = blockIdx.y;
    const int kbase = blockIdx.z * ksteps * 64;
    const int rA0 = rowA_off + bx * 128;
    const int rB0 = by * 128;
    const int ex = (tid & 7) * 8;
    const int rsub = tid >> 3;      // 0..31

    f32x4 acc[4][4] = {};
    uint4 ra[4], rb[4];

    #pragma unroll
    for (int j = 0; j < 4; j++) {
        int row = j * 32 + rsub;
        ra[j] = *(const uint4*)&A[(size_t)(rA0 + row) * lda + kbase + ex];
        rb[j] = *(const uint4*)&B[(size_t)(rB0 + row) * ldb + kbase + ex];
    }
    for (int step = 0; step < ksteps; step++) {
        __syncthreads();
        #pragma unroll
        for (int j = 0; j < 4; j++) {
            int row = j * 32 + rsub;
            int xi = ex ^ ((row & 7) << 3);
            *(uint4*)&sA[row * 64 + xi] = ra[j];
            *(uint4*)&sB[row * 64 + xi] = rb[j];
        }
        __syncthreads();
        if (step + 1 < ksteps) {
            int k0 = kbase + (step + 1) * 64;
            #pragma unroll
            for (int j = 0; j < 4; j++) {
                int row = j * 32 + rsub;
                ra[j] = *(const uint4*)&A[(size_t)(rA0 + row) * lda + k0 + ex];
                rb[j] = *(const uint4*)&B[(size_t)(rB0 + row) * ldb + k0 + ex];
            }
        }
        #pragma unroll
        for (int h = 0; h < 2; h++) {
            int xs = (h * 32 + lg * 8) ^ ((lr & 7) << 3);
            bf16x8 aF[4], bF[4];
            #pragma unroll
            for (int m = 0; m < 4; m++)
                aF[m] = *(const bf16x8*)&sA[(wr * 64 + m * 16 + lr) * 64 + xs];
            #pragma unroll
            for (int n = 0; n < 4; n++)
                bF[n] = *(const bf16x8*)&sB[(wc * 64 + n * 16 + lr) * 64 + xs];
            #pragma unroll
            for (int m = 0; m < 4; m++)
                #pragma unroll
                for (int n = 0; n < 4; n++)
                    acc[m][n] = __builtin_amdgcn_mfma_f32_16x16x32_bf16(aF[m], bF[n], acc[m][n], 0, 0, 0);
        }
    }

    // ---------------- epilogue ----------------
    if (MODE == 0) {
        #pragma unroll
        for (int m = 0; m < 4; m++) {
            #pragma unroll
            for (int r = 0; r < 4; r++) {
                float bv = acc[m][0][r];
                int bi = by * 128 + wc * 64 + lr;
                #pragma unroll
                for (int n = 1; n < 4; n++) {
                    float v = acc[m][n][r];
                    int c = by * 128 + wc * 64 + n * 16 + lr;
                    if (v > bv) { bv = v; bi = c; }
                }
                #pragma unroll
                for (int off = 1; off < 16; off <<= 1) {
                    float ov = __shfl_xor(bv, off);
                    int oi = __shfl_xor(bi, off);
                    if (ov > bv || (ov == bv && oi < bi)) { bv = ov; bi = oi; }
                }
                if (lr == 0) {
                    int grow = bx * 128 + wr * 64 + m * 16 + lg * 4 + r;
                    outF[(size_t)by * TTOK + grow] = bv;
                    outI[(size_t)by * TTOK + grow] = bi;
                }
            }
        }
    } else if (MODE == 1) {
        #pragma unroll
        for (int n = 0; n < 4; n++) {
            int gcol = by * 128 + wc * 64 + n * 16 + lr;
            float a = actf[gcol];
            float lgv = logf(fmaxf(a, 1e-8f));
            bool dead = (a < 0.01f);
            #pragma unroll
            for (int m = 0; m < 4; m++)
                #pragma unroll
                for (int r = 0; r < 4; r++) {
                    int grow = bx * 128 + wr * 64 + m * 16 + lg * 4 + r;
                    outF[(size_t)grow * NSLOT + gcol] =
                        dead ? -INFINITY : acc[m][n][r] * SCALE + lgv;
                }
        }
    } else if (MODE == 2) {
        #pragma unroll
        for (int m = 0; m < 4; m++)
            #pragma unroll
            for (int r = 0; r < 4; r++) {
                int grow = bx * 128 + wr * 64 + m * 16 + lg * 4 + r;
                #pragma unroll
                for (int n = 0; n < 4; n++) {
                    int gcol = by * 128 + wc * 64 + n * 16 + lr;
                    outF[((size_t)blockIdx.z * TCHUNK + grow) * DIM + gcol] = acc[m][n][r];
                }
            }
    } else {   // MODE 3: projection epilogue (bias add, fp32 + optional bf16 out)
        ushort_t* obf = (ushort_t*)outI;
        #pragma unroll
        for (int n = 0; n < 4; n++) {
            int gcol = by * 128 + wc * 64 + n * 16 + lr;
            float bj = actf[gcol];
            #pragma unroll
            for (int m = 0; m < 4; m++)
                #pragma unroll
                for (int r = 0; r < 4; r++) {
                    int grow = bx * 128 + wr * 64 + m * 16 + lg * 4 + r;
                    float v = acc[m][n][r] + bj;
                    outF[(size_t)grow * DIM + gcol] = v;
                    if (obf) obf[(size_t)grow * DIM + gcol] = f2bf(v);
                }
        }
    }
}

// ---------------------------------------------------------------- merge 32 partials
__global__ void k_bestmerge(const float* partV, const int* partI,
                            int* best, int* novel, int* misc) {
    int t = blockIdx.x * 256 + threadIdx.x;
    if (t >= TTOK) return;
    float bv = partV[t]; int bi = partI[t];
    #pragma unroll
    for (int q = 1; q < 32; q++) {
        float v = partV[(size_t)q * TTOK + t];
        int i = partI[(size_t)q * TTOK + t];
        if (v > bv || (v == bv && i < bi)) { bv = v; bi = i; }
    }
    best[t] = bi;
    int nv = (bv * SCALE < 0.5f) ? 1 : 0;
    novel[t] = nv;
    if (!nv) atomicAnd(&misc[1], 0);
}

// --------------------------------------------------------------- flags
__global__ void k_flags(const unsigned char* maskraw, const float* act0, int* misc) {
    int t = blockIdx.x * 256 + threadIdx.x;
    int u8 = (maskraw[1] == 1);
    if (t < TTOK) {
        int mv = u8 ? (int)maskraw[t] : ((const int*)maskraw)[t];
        if (mv == 0) atomicAnd(&misc[1], 0);
    }
    if (t < NSLOT) {
        float a = act0[t];
        if (!(a >= 0.0f)) atomicAnd(&misc[1], 0);
    }
}

// ------------------------------------------------- ladder candidate generation
__global__ void k_ladder(const float* act0, u64* cand, int* candJ, int* misc) {
    if (misc[1] == 0) return;
    int i = blockIdx.x * 256 + threadIdx.x;
    if (i >= NSLOT) return;
    float w = act0[i];
    int j = 0;
    while (w < 1.0f) {
        if (j >= 48) { atomicAnd(&misc[2], 0); break; }
        int pos = atomicAdd(&misc[0], 1);
        if (pos >= CAPC) { atomicAnd(&misc[2], 0); break; }
        cand[pos] = ((u64)__float_as_uint(w) << 32) | (unsigned)i;
        candJ[pos] = j;
        j++;
        w = fminf(1.0f, w + 0.1f);
    }
}

__global__ void k_finalize(int* misc) {
    misc[3] = (misc[1] && misc[2] && misc[0] >= TTOK) ? 1 : 0;
}

// ------------------------------------------------- histogram ranking (exact)
__global__ void k_hist(const u64* cand, const int* misc, int* hist) {
    if (!(misc[1] && misc[2])) return;
    int K = misc[0]; if (K > CAPC) K = CAPC;
    int i = blockIdx.x * 256 + threadIdx.x;
    if (i >= K) return;
    float w = __uint_as_float((unsigned)(cand[i] >> 32));
    atomicAdd(&hist[bucketof(w)], 1);
}

__global__ __launch_bounds__(1024) void k_scanhist(const int* __restrict__ hist, int* __restrict__ offsB) {
    __shared__ int part[1024];
    int tid = threadIdx.x;
    int base = tid * 64;
    int s = 0;
    for (int i = 0; i < 64; i++) s += hist[base + i];
    part[tid] = s;
    __syncthreads();
    for (int off = 1; off < 1024; off <<= 1) {
        int v = (tid >= off) ? part[tid - off] : 0;
        __syncthreads();
        part[tid] += v;
        __syncthreads();
    }
    int pre = (tid == 0) ? 0 : part[tid - 1];
    for (int i = 0; i < 64; i++) { offsB[base + i] = pre; pre += hist[base + i]; }
}

__global__ void k_place(const u64* cand, const int* candJ, const int* misc,
                        const int* offsB, int* cnt2, u64* skey, int* sj) {
    if (!(misc[1] && misc[2])) return;
    int K = misc[0]; if (K > CAPC) K = CAPC;
    int i = blockIdx.x * 256 + threadIdx.x;
    if (i >= K) return;
    u64 key = cand[i];
    float w = __uint_as_float((unsigned)(key >> 32));
    int b = bucketof(w);
    int pos = offsB[b] + atomicAdd(&cnt2[b], 1);
    skey[pos] = key; sj[pos] = candJ[i];
}

__global__ void k_rank2(const u64* __restrict__ skey, const int* __restrict__ sj, const int* misc,
                        const int* __restrict__ offsB, const int* __restrict__ hist,
                        int* slot_seq, int* rankis, int* cnt) {
    if (!(misc[1] && misc[2])) return;
    int K = misc[0]; if (K > CAPC) K = CAPC;
    int i = blockIdx.x * 256 + threadIdx.x;
    if (i >= K) return;
    u64 my = skey[i];
    float w = __uint_as_float((unsigned)(my >> 32));
    int b = bucketof(w);
    int base = offsB[b], n = hist[b];
    int r = base;
    for (int q = 0; q < n; q++) r += (skey[base + q] < my) ? 1 : 0;
    if (r < TTOK) {
        int slot = (int)(my & 0xffffffffu);
        slot_seq[r] = slot;
        rankis[r] = sj[i];
        atomicAdd(&cnt[slot], 1);
    }
}

__global__ void k_actfinal(const float* act0, const int* cnt, float* act_f, const int* misc) {
    if (!misc[3]) return;
    int i = blockIdx.x * 256 + threadIdx.x;
    if (i >= NSLOT) return;
    float a = act0[i];
    int m = cnt[i];
    for (int r = 0; r < m; r++) a = fminf(1.0f, a + 0.1f);
    act_f[i] = a;
}

// ------------------------------------------------- serial fallback (cold path)
__global__ __launch_bounds__(64) void k_serial(
    const int* novel, const int* best, const unsigned char* maskraw,
    const float* act0, const int* misc,
    int* slot_seq, int* rankis, int* cnt, float* act_f)
{
    if (misc[3]) return;
    __shared__ float act[NSLOT];
    __shared__ int cntL[NSLOT];
    const int lane = threadIdx.x;
    const int u8 = (maskraw[1] == 1);
    for (int i = lane; i < NSLOT; i += 64) { act[i] = act0[i]; cntL[i] = 0; }
    __syncthreads();
    float cv; int ci;
    {
        cv = act[lane * 64]; ci = lane * 64;
        for (int u = 1; u < 64; u++) {
            float v = act[lane * 64 + u];
            if (v < cv) { cv = v; ci = lane * 64 + u; }
        }
    }
    for (int t = 0; t < TTOK; t++) {
        int nv = novel[t];
        int mk = (u8 ? (int)maskraw[t] : ((const int*)maskraw)[t]) != 0;
        int slot;
        if (nv) {
            float v = cv; int ix = ci;
            for (int off = 32; off >= 1; off >>= 1) {
                float ov = __shfl_xor(v, off);
                int oi = __shfl_xor(ix, off);
                if (ov < v || (ov == v && oi < ix)) { v = ov; ix = oi; }
            }
            slot = ix;
        } else {
            slot = best[t];
        }
        if (mk) {
            float a = act[slot];
            float a2 = fminf(1.0f, a + 0.1f);
            __syncthreads();
            if (lane == 0) {
                act[slot] = a2;
                slot_seq[t] = slot;
                int r = cntL[slot]; rankis[t] = r; cntL[slot] = r + 1;
            }
            __syncthreads();
            int c = slot >> 6;
            float v = act[c * 64 + lane]; int ix = c * 64 + lane;
            for (int off = 32; off >= 1; off >>= 1) {
                float ov = __shfl_xor(v, off);
                int oi = __shfl_xor(ix, off);
                if (ov < v || (ov == v && oi < ix)) { v = ov; ix = oi; }
            }
            if (lane == c) { cv = v; ci = ix; }
        } else {
            if (lane == 0) rankis[t] = -1;
        }
        __syncthreads();
    }
    for (int i = lane; i < NSLOT; i += 64) { cnt[i] = cntL[i]; act_f[i] = act[i]; }
}

// ------------------------------------------------- CSR build
__global__ __launch_bounds__(256) void k_offsets(const int* cnt, int* offs) {
    __shared__ int part[256];
    int tid = threadIdx.x;
    int base = tid * 16;
    int loc[16];
    int s = 0;
    #pragma unroll
    for (int i = 0; i < 16; i++) { loc[i] = s; s += cnt[base + i]; }
    part[tid] = s;
    __syncthreads();
    for (int off = 1; off < 256; off <<= 1) {
        int v = (tid >= off) ? part[tid - off] : 0;
        __syncthreads();
        part[tid] += v;
        __syncthreads();
    }
    int pre = (tid == 0) ? 0 : part[tid - 1];
    #pragma unroll
    for (int i = 0; i < 16; i++) offs[base + i] = pre + loc[i];
}

__global__ void k_scatter(const int* slot_seq, const int* rankis, const int* offs, int* listTok) {
    int t = blockIdx.x * 256 + threadIdx.x;
    if (t >= TTOK) return;
    int r = rankis[t];
    if (r >= 0) listTok[offs[slot_seq[t]] + r] = t;
}

// ------------------------------------------------- apply buffer writes per slot
__global__ __launch_bounds__(256) void k_apply(
    const float* __restrict__ keys0, const float* __restrict__ values0,
    const float* __restrict__ ka, const float* __restrict__ va,
    const int* __restrict__ novel, const int* __restrict__ cnt,
    const int* __restrict__ offs, const int* __restrict__ listTok,
    float* __restrict__ kb, float* __restrict__ vb)
{
    int s = blockIdx.x;
    int d = threadIdx.x;
    float kv = keys0[(size_t)s * DIM + d];
    float vv = values0[(size_t)s * DIM + d];
    int m = cnt[s], off = offs[s];
    for (int r = 0; r < m; r++) {
        int t = listTok[off + r];
        float al = novel[t] ? 0.9f : 0.3f;
        kv = (1.0f - al) * kv + al * ka[(size_t)t * DIM + d];
        vv = (1.0f - al) * vv + al * va[(size_t)t * DIM + d];
    }
    kb[(size_t)s * DIM + d] = kv;
    vb[(size_t)s * DIM + d] = vv;
}

// ------------------------------------------------- row softmax: fp32 in, bf16 out
__global__ __launch_bounds__(256) void k_softmax(float* __restrict__ logits, ushort_t* __restrict__ pbf) {
    float* row = logits + (size_t)blockIdx.x * NSLOT;
    ushort_t* orow = pbf + (size_t)blockIdx.x * NSLOT;
    __shared__ float sd[256];
    int tid = threadIdx.x;
    float m = -INFINITY;
    for (int i = tid; i < NSLOT; i += 256) m = fmaxf(m, row[i]);
    sd[tid] = m; __syncthreads();
    for (int off = 128; off >= 1; off >>= 1) {
        if (tid < off) sd[tid] = fmaxf(sd[tid], sd[tid + off]);
        __syncthreads();
    }
    m = sd[0]; __syncthreads();
    float s = 0.0f;
    for (int i = tid; i < NSLOT; i += 256) {
        float e = expf(row[i] - m);
        row[i] = e;
        s += e;
    }
    sd[tid] = s; __syncthreads();
    for (int off = 128; off >= 1; off >>= 1) {
        if (tid < off) sd[tid] += sd[tid + off];
        __syncthreads();
    }
    float inv = 1.0f / sd[0];
    for (int i = tid; i < NSLOT; i += 256) orow[i] = f2bf(row[i] * inv);
}

// ------------------------------------------------- sum 8 PV partials
__global__ void k_pvsum(const float* __restrict__ part, float* __restrict__ out, int t0) {
    int idx = blockIdx.x * 256 + threadIdx.x;
    float s = 0.0f;
    #pragma unroll
    for (int z = 0; z < 8; z++) s += part[(size_t)z * TCHUNK * DIM + idx];
    out[(size_t)t0 * DIM + idx] = s;
}

// ================================================================ launch
extern "C" void kernel_launch(void* const* d_in, const int* in_sizes, int n_in,
                              void* d_out, int out_size, void* d_ws, size_t ws_size,
                              hipStream_t stream)
{
    (void)in_sizes; (void)n_in; (void)out_size; (void)ws_size;
    const float* x       = (const float*)d_in[0];
    const unsigned char* mask = (const unsigned char*)d_in[1];
    const float* keys0   = (const float*)d_in[2];
    const float* values0 = (const float*)d_in[3];
    const float* act0    = (const float*)d_in[4];
    const float* Wk = (const float*)d_in[5];
    const float* bk = (const float*)d_in[6];
    const float* Wv = (const float*)d_in[7];
    const float* bv = (const float*)d_in[8];
    const float* Wq = (const float*)d_in[9];
    const float* bq = (const float*)d_in[10];
    float* out = (float*)d_out;

    uint8_t* w = (uint8_t*)d_ws;
    size_t off = 0;
    auto alloc = [&](size_t bytes) -> void* {
        void* p = w + off;
        off = (off + bytes + 255) & ~(size_t)255;
        return p;
    };
    float*    ka     = (float*)   alloc((size_t)TTOK * DIM * 4);
    float*    va_    = (float*)   alloc((size_t)TTOK * DIM * 4);
    float*    qa     = (float*)   alloc((size_t)TTOK * DIM * 4);
    float*    kb     = (float*)   alloc((size_t)NSLOT * DIM * 4);
    float*    vb     = (float*)   alloc((size_t)NSLOT * DIM * 4);
    ushort_t* x2     = (ushort_t*)alloc((size_t)TTOK * 512 * 2);
    ushort_t* w2k    = (ushort_t*)alloc((size_t)DIM * 512 * 2);
    ushort_t* w2v    = (ushort_t*)alloc((size_t)DIM * 512 * 2);
    ushort_t* w2q    = (ushort_t*)alloc((size_t)DIM * 512 * 2);
    ushort_t* ka_bf  = (ushort_t*)alloc((size_t)TTOK * DIM * 2);
    ushort_t* qa_bf  = (ushort_t*)alloc((size_t)TTOK * DIM * 2);
    ushort_t* k0_bf  = (ushort_t*)alloc((size_t)NSLOT * DIM * 2);
    ushort_t* kb_bf  = (ushort_t*)alloc((size_t)NSLOT * DIM * 2);
    ushort_t* vbT    = (ushort_t*)alloc((size_t)DIM * NSLOT * 2);
    float*    logits = (float*)   alloc((size_t)TCHUNK * NSLOT * 4);   // pvpart aliases this
    ushort_t* p_bf   = (ushort_t*)alloc((size_t)TCHUNK * NSLOT * 2);
    float*    partV  = (float*)   alloc((size_t)32 * TTOK * 4);
    int*      partI  = (int*)     alloc((size_t)32 * TTOK * 4);
    float*    act_f  = (float*)   alloc((size_t)NSLOT * 4);
    int*      best   = (int*)     alloc((size_t)TTOK * 4);
    int*      novel  = (int*)     alloc((size_t)TTOK * 4);
    int*      slot_seq = (int*)   alloc((size_t)TTOK * 4);
    int*      rankis = (int*)     alloc((size_t)TTOK * 4);
    int*      cnt    = (int*)     alloc((size_t)NSLOT * 4);
    int*      offs   = (int*)     alloc((size_t)NSLOT * 4);
    int*      listTok= (int*)     alloc((size_t)TTOK * 4);
    u64*      cand   = (u64*)     alloc((size_t)CAPC * 8);
    int*      candJ  = (int*)     alloc((size_t)CAPC * 4);
    u64*      skey   = (u64*)     alloc((size_t)CAPC * 8);
    int*      sj     = (int*)     alloc((size_t)CAPC * 4);
    int*      hist   = (int*)     alloc((size_t)NBUCK * 4);
    int*      cnt2   = (int*)     alloc((size_t)NBUCK * 4);
    int*      offsB  = (int*)     alloc((size_t)NBUCK * 4);
    int*      misc   = (int*)     alloc(64);
    float*    pvpart = logits;    // alias: logits dead once softmax has read it

    k_init<<<17, 256, 0, stream>>>(cnt, misc);
    k_zero2<<<NBUCK/256, 256, 0, stream>>>(hist, cnt2);

    // split-bf16 projections (fp32-accurate via [hi|lo] concat, K=512)
    k_split<<<TTOK*DIM/256, 256, 0, stream>>>(x, x2, TTOK);
    k_split<<<DIM*DIM/256, 256, 0, stream>>>(Wk, w2k, DIM);
    k_split<<<DIM*DIM/256, 256, 0, stream>>>(Wv, w2v, DIM);
    k_split<<<DIM*DIM/256, 256, 0, stream>>>(Wq, w2q, DIM);
    k_mm<3><<<dim3(TTOK/128, DIM/128, 1), 256, 0, stream>>>(
        x2, w2k, 512, 512, 0, 8, ka, (int*)ka_bf, bk);
    k_mm<3><<<dim3(TTOK/128, DIM/128, 1), 256, 0, stream>>>(
        x2, w2v, 512, 512, 0, 8, va_, nullptr, bv);
    k_mm<3><<<dim3(TTOK/128, DIM/128, 1), 256, 0, stream>>>(
        x2, w2q, 512, 512, 0, 8, qa, (int*)qa_bf, bq);

    k_cast<<<NSLOT*DIM/1024, 256, 0, stream>>>(keys0, k0_bf, NSLOT*DIM);
    k_mm<0><<<dim3(TTOK/128, NSLOT/128, 1), 256, 0, stream>>>(
        ka_bf, k0_bf, DIM, DIM, 0, DIM/64, partV, partI, nullptr);
    k_bestmerge<<<TTOK/256, 256, 0, stream>>>(partV, partI, best, novel, misc);

    k_flags<<<TTOK/256, 256, 0, stream>>>(mask, act0, misc);
    k_ladder<<<NSLOT/256, 256, 0, stream>>>(act0, cand, candJ, misc);
    k_finalize<<<1, 1, 0, stream>>>(misc);
    k_hist<<<CAPC/256, 256, 0, stream>>>(cand, misc, hist);
    k_scanhist<<<1, 1024, 0, stream>>>(hist, offsB);
    k_place<<<CAPC/256, 256, 0, stream>>>(cand, candJ, misc, offsB, cnt2, skey, sj);
    k_rank2<<<CAPC/256, 256, 0, stream>>>(skey, sj, misc, offsB, hist, slot_seq, rankis, cnt);
    k_actfinal<<<NSLOT/256, 256, 0, stream>>>(act0, cnt, act_f, misc);
    k_serial<<<1, 64, 0, stream>>>(novel, best, mask, act0, misc, slot_seq, rankis, cnt, act_f);
    k_offsets<<<1, 256, 0, stream>>>(cnt, offs);
    k_scatter<<<TTOK/256, 256, 0, stream>>>(slot_seq, rankis, offs, listTok);
    k_apply<<<NSLOT, 256, 0, stream>>>(keys0, values0, ka, va_, novel, cnt, offs, listTok, kb, vb);

    k_cast<<<NSLOT*DIM/1024, 256, 0, stream>>>(kb, kb_bf, NSLOT*DIM);
    k_transV<<<dim3(NSLOT/32, DIM/32), 256, 0, stream>>>(vb, vbT);

    for (int c = 0; c < TTOK / TCHUNK; c++) {
        int t0 = c * TCHUNK;
        k_mm<1><<<dim3(TCHUNK/128, NSLOT/128, 1), 256, 0, stream>>>(
            qa_bf, kb_bf, DIM, DIM, t0, DIM/64, logits, nullptr, act_f);
        k_softmax<<<TCHUNK, 256, 0, stream>>>(logits, p_bf);
        k_mm<2><<<dim3(TCHUNK/128, DIM/128, 8), 256, 0, stream>>>(
            p_bf, vbT, NSLOT, NSLOT, 0, 8, pvpart, nullptr, nullptr);
        k_pvsum<<<TCHUNK*DIM/256, 256, 0, stream>>>(pvpart, out, t0);
    }
}

// Round 4
// 560.539 us; speedup vs baseline: 2.4780x; 1.1941x over previous
//
#include <hip/hip_runtime.h>
#include <hip/hip_bf16.h>
#include <math.h>
#include <stdint.h>

// Problem constants (B=8,S=1024,D=256,N=4096)
#define TTOK 8192
#define DIM 256
#define NSLOT 4096
#define CAPC 65536
#define NBUCK 65536
#define SCALE 0.0625f     // 1/sqrt(256), exact
#define QBLK 16
#define SBLK 64

typedef unsigned long long u64;
typedef unsigned short ushort_t;
typedef __attribute__((ext_vector_type(8))) __bf16 bf16x8;
typedef __attribute__((ext_vector_type(4))) float f32x4;

__device__ inline ushort_t f2bf(float f) {
    unsigned u = __float_as_uint(f);
    unsigned r = (u + 0x7fffu + ((u >> 16) & 1u)) >> 16;   // RNE
    return (ushort_t)r;
}
__device__ inline int bucketof(float w) {
    int b = (int)(w * 65536.0f);
    return b > 65535 ? 65535 : b;
}

// misc[0]=cand count, misc[1]=flagA, misc[2]=flagB, misc[3]=fast-path valid

// ---------------------------------------------------------------- init
__global__ void k_init(int* cnt, int* misc) {
    int t = blockIdx.x * 256 + threadIdx.x;
    if (t < NSLOT) cnt[t] = 0;
    if (t == 0) { misc[0] = 0; misc[1] = 1; misc[2] = 1; misc[3] = 0; }
}
__global__ void k_zero2(int* hist, int* cnt2) {
    int i = blockIdx.x * 256 + threadIdx.x;
    hist[i] = 0; cnt2[i] = 0;
}

// ------------------------------------------- split fp32 -> [hi|lo] bf16 (K doubled)
__global__ void k_split(const float* __restrict__ in, ushort_t* __restrict__ out2, int rows) {
    int i = blockIdx.x * 256 + threadIdx.x;
    if (i >= rows * 256) return;
    int t = i >> 8, k = i & 255;
    float v = in[i];
    ushort_t h = f2bf(v);
    float hf = __uint_as_float(((unsigned)h) << 16);
    ushort_t l = f2bf(v - hf);
    out2[(size_t)t * 512 + k] = h;
    out2[(size_t)t * 512 + 256 + k] = l;
}

// ---------------------------------------------------------------- fp32->bf16 cast
__global__ void k_cast(const float* __restrict__ in, ushort_t* __restrict__ out, int n) {
    int i = (blockIdx.x * 256 + threadIdx.x) * 4;
    if (i >= n) return;
    float4 v = *(const float4*)&in[i];
    ushort4 o;
    o.x = f2bf(v.x); o.y = f2bf(v.y); o.z = f2bf(v.z); o.w = f2bf(v.w);
    *(ushort4*)&out[i] = o;
}

// ---------------------------------------------------------------- vb -> vbT (bf16)
__global__ __launch_bounds__(256) void k_transV(const float* __restrict__ vb, ushort_t* __restrict__ vbT) {
    __shared__ float ts[32][33];
    int tx = threadIdx.x & 31, ty = threadIdx.x >> 5;
    int s0 = blockIdx.x * 32, d0 = blockIdx.y * 32;
    #pragma unroll
    for (int j = 0; j < 4; j++)
        ts[ty + j*8][tx] = vb[(size_t)(s0 + ty + j*8) * DIM + d0 + tx];
    __syncthreads();
    #pragma unroll
    for (int j = 0; j < 4; j++)
        vbT[(size_t)(d0 + ty + j*8) * NSLOT + s0 + tx] = f2bf(ts[tx][ty + j*8]);
}

// =============================================================== MFMA GEMM
// MODE 0: simmax -> per-row max/argmax, XCD-swizzled 1-D grid (2048)
// MODE 3: proj   -> outF = acc + bias; optional bf16 copy via outI
template<int MODE>
__global__ __launch_bounds__(256) void k_mm(
    const ushort_t* __restrict__ A, const ushort_t* __restrict__ B,
    int lda, int ldb, int rowA_off, int ksteps,
    float* __restrict__ outF, int* __restrict__ outI,
    const float* __restrict__ actf)
{
    __shared__ ushort_t sA[128 * 64];
    __shared__ ushort_t sB[128 * 64];
    const int tid = threadIdx.x;
    const int lane = tid & 63;
    const int w = tid >> 6;
    const int wr = w >> 1, wc = w & 1;
    const int lr = lane & 15, lg = lane >> 4;
    int bx = blockIdx.x, by = blockIdx.y;
    if (MODE == 0) {   // XCD-aware decode: xcd owns by-range [xcd*4, xcd*4+4)
        int lin = blockIdx.x;
        int xcd = lin & 7, pos = lin >> 3;
        bx = pos >> 2;
        by = (xcd << 2) | (pos & 3);
    }
    const int kbase = 0;
    const int rA0 = rowA_off + bx * 128;
    const int rB0 = by * 128;
    const int ex = (tid & 7) * 8;
    const int rsub = tid >> 3;

    f32x4 acc[4][4] = {};
    uint4 ra[4], rb[4];

    #pragma unroll
    for (int j = 0; j < 4; j++) {
        int row = j * 32 + rsub;
        ra[j] = *(const uint4*)&A[(size_t)(rA0 + row) * lda + kbase + ex];
        rb[j] = *(const uint4*)&B[(size_t)(rB0 + row) * ldb + kbase + ex];
    }
    for (int step = 0; step < ksteps; step++) {
        __syncthreads();
        #pragma unroll
        for (int j = 0; j < 4; j++) {
            int row = j * 32 + rsub;
            int xi = ex ^ ((row & 7) << 3);
            *(uint4*)&sA[row * 64 + xi] = ra[j];
            *(uint4*)&sB[row * 64 + xi] = rb[j];
        }
        __syncthreads();
        if (step + 1 < ksteps) {
            int k0 = kbase + (step + 1) * 64;
            #pragma unroll
            for (int j = 0; j < 4; j++) {
                int row = j * 32 + rsub;
                ra[j] = *(const uint4*)&A[(size_t)(rA0 + row) * lda + k0 + ex];
                rb[j] = *(const uint4*)&B[(size_t)(rB0 + row) * ldb + k0 + ex];
            }
        }
        #pragma unroll
        for (int h = 0; h < 2; h++) {
            int xs = (h * 32 + lg * 8) ^ ((lr & 7) << 3);
            bf16x8 aF[4], bF[4];
            #pragma unroll
            for (int m = 0; m < 4; m++)
                aF[m] = *(const bf16x8*)&sA[(wr * 64 + m * 16 + lr) * 64 + xs];
            #pragma unroll
            for (int n = 0; n < 4; n++)
                bF[n] = *(const bf16x8*)&sB[(wc * 64 + n * 16 + lr) * 64 + xs];
            #pragma unroll
            for (int m = 0; m < 4; m++)
                #pragma unroll
                for (int n = 0; n < 4; n++)
                    acc[m][n] = __builtin_amdgcn_mfma_f32_16x16x32_bf16(aF[m], bF[n], acc[m][n], 0, 0, 0);
        }
    }

    // ---------------- epilogue ----------------
    if (MODE == 0) {
        __syncthreads();   // all waves done reading sA/sB
        float* sRedV = (float*)sA;            // 2*128 floats (1KB)
        int*   sRedI = (int*)(sA + 2048);     // byte offset 4096 (1KB)
        #pragma unroll
        for (int m = 0; m < 4; m++) {
            #pragma unroll
            for (int r = 0; r < 4; r++) {
                float bv = acc[m][0][r];
                int bi = wc * 64 + lr;          // local col within 128
                #pragma unroll
                for (int n = 1; n < 4; n++) {
                    float v = acc[m][n][r];
                    int c = wc * 64 + n * 16 + lr;
                    if (v > bv) { bv = v; bi = c; }
                }
                #pragma unroll
                for (int off = 1; off < 16; off <<= 1) {
                    float ov = __shfl_xor(bv, off);
                    int oi = __shfl_xor(bi, off);
                    if (ov > bv || (ov == bv && oi < bi)) { bv = ov; bi = oi; }
                }
                if (lr == 0) {
                    int row = wr * 64 + m * 16 + lg * 4 + r;
                    sRedV[wc * 128 + row] = bv;
                    sRedI[wc * 128 + row] = bi;
                }
            }
        }
        __syncthreads();
        if (tid < 128) {
            float v0 = sRedV[tid]; int i0 = sRedI[tid];
            float v1 = sRedV[128 + tid]; int i1 = sRedI[128 + tid];
            bool take = (v1 > v0);                       // tie -> lower col (wc0)
            float bv = take ? v1 : v0;
            int bi = by * 128 + (take ? i1 : i0);
            outF[(size_t)by * TTOK + bx * 128 + tid] = bv;
            outI[(size_t)by * TTOK + bx * 128 + tid] = bi;
        }
    } else {   // MODE 3: projection epilogue
        ushort_t* obf = (ushort_t*)outI;
        #pragma unroll
        for (int n = 0; n < 4; n++) {
            int gcol = by * 128 + wc * 64 + n * 16 + lr;
            float bj = actf[gcol];
            #pragma unroll
            for (int m = 0; m < 4; m++)
                #pragma unroll
                for (int r = 0; r < 4; r++) {
                    int grow = bx * 128 + wr * 64 + m * 16 + lg * 4 + r;
                    float v = acc[m][n][r] + bj;
                    outF[(size_t)grow * DIM + gcol] = v;
                    if (obf) obf[(size_t)grow * DIM + gcol] = f2bf(v);
                }
        }
    }
}

// ---------------------------------------------------------------- merge 32 partials
__global__ void k_bestmerge(const float* partV, const int* partI,
                            int* best, int* novel, int* misc) {
    int t = blockIdx.x * 256 + threadIdx.x;
    if (t >= TTOK) return;
    float bv = partV[t]; int bi = partI[t];
    #pragma unroll
    for (int q = 1; q < 32; q++) {
        float v = partV[(size_t)q * TTOK + t];
        int i = partI[(size_t)q * TTOK + t];
        if (v > bv || (v == bv && i < bi)) { bv = v; bi = i; }
    }
    best[t] = bi;
    int nv = (bv * SCALE < 0.5f) ? 1 : 0;
    novel[t] = nv;
    if (!nv) atomicAnd(&misc[1], 0);
}

// --------------------------------------------------------------- flags
__global__ void k_flags(const unsigned char* maskraw, const float* act0, int* misc) {
    int t = blockIdx.x * 256 + threadIdx.x;
    int u8 = (maskraw[1] == 1);
    if (t < TTOK) {
        int mv = u8 ? (int)maskraw[t] : ((const int*)maskraw)[t];
        if (mv == 0) atomicAnd(&misc[1], 0);
    }
    if (t < NSLOT) {
        float a = act0[t];
        if (!(a >= 0.0f)) atomicAnd(&misc[1], 0);
    }
}

// ------------------------------------------------- ladder candidate generation
__global__ void k_ladder(const float* act0, u64* cand, int* candJ, int* misc) {
    if (misc[1] == 0) return;
    int i = blockIdx.x * 256 + threadIdx.x;
    if (i >= NSLOT) return;
    float w = act0[i];
    int j = 0;
    while (w < 1.0f) {
        if (j >= 48) { atomicAnd(&misc[2], 0); break; }
        int pos = atomicAdd(&misc[0], 1);
        if (pos >= CAPC) { atomicAnd(&misc[2], 0); break; }
        cand[pos] = ((u64)__float_as_uint(w) << 32) | (unsigned)i;
        candJ[pos] = j;
        j++;
        w = fminf(1.0f, w + 0.1f);
    }
}

__global__ void k_finalize(int* misc) {
    misc[3] = (misc[1] && misc[2] && misc[0] >= TTOK) ? 1 : 0;
}

// ------------------------------------------------- histogram ranking (exact)
__global__ void k_hist(const u64* cand, const int* misc, int* hist) {
    if (!(misc[1] && misc[2])) return;
    int K = misc[0]; if (K > CAPC) K = CAPC;
    int i = blockIdx.x * 256 + threadIdx.x;
    if (i >= K) return;
    float w = __uint_as_float((unsigned)(cand[i] >> 32));
    atomicAdd(&hist[bucketof(w)], 1);
}

__global__ __launch_bounds__(1024) void k_scanhist(const int* __restrict__ hist, int* __restrict__ offsB) {
    __shared__ int part[1024];
    int tid = threadIdx.x;
    int base = tid * 64;
    int s = 0;
    for (int i = 0; i < 64; i++) s += hist[base + i];
    part[tid] = s;
    __syncthreads();
    for (int off = 1; off < 1024; off <<= 1) {
        int v = (tid >= off) ? part[tid - off] : 0;
        __syncthreads();
        part[tid] += v;
        __syncthreads();
    }
    int pre = (tid == 0) ? 0 : part[tid - 1];
    for (int i = 0; i < 64; i++) { offsB[base + i] = pre; pre += hist[base + i]; }
}

__global__ void k_place(const u64* cand, const int* candJ, const int* misc,
                        const int* offsB, int* cnt2, u64* skey, int* sj) {
    if (!(misc[1] && misc[2])) return;
    int K = misc[0]; if (K > CAPC) K = CAPC;
    int i = blockIdx.x * 256 + threadIdx.x;
    if (i >= K) return;
    u64 key = cand[i];
    float w = __uint_as_float((unsigned)(key >> 32));
    int b = bucketof(w);
    int pos = offsB[b] + atomicAdd(&cnt2[b], 1);
    skey[pos] = key; sj[pos] = candJ[i];
}

__global__ void k_rank2(const u64* __restrict__ skey, const int* __restrict__ sj, const int* misc,
                        const int* __restrict__ offsB, const int* __restrict__ hist,
                        int* slot_seq, int* rankis, int* cnt) {
    if (!(misc[1] && misc[2])) return;
    int K = misc[0]; if (K > CAPC) K = CAPC;
    int i = blockIdx.x * 256 + threadIdx.x;
    if (i >= K) return;
    u64 my = skey[i];
    float w = __uint_as_float((unsigned)(my >> 32));
    int b = bucketof(w);
    int base = offsB[b], n = hist[b];
    int r = base;
    for (int q = 0; q < n; q++) r += (skey[base + q] < my) ? 1 : 0;
    if (r < TTOK) {
        int slot = (int)(my & 0xffffffffu);
        slot_seq[r] = slot;
        rankis[r] = sj[i];
        atomicAdd(&cnt[slot], 1);
    }
}

__global__ void k_actfinal(const float* act0, const int* cnt, float* act_f, const int* misc) {
    if (!misc[3]) return;
    int i = blockIdx.x * 256 + threadIdx.x;
    if (i >= NSLOT) return;
    float a = act0[i];
    int m = cnt[i];
    for (int r = 0; r < m; r++) a = fminf(1.0f, a + 0.1f);
    act_f[i] = a;
}

// ------------------------------------------------- serial fallback (cold path)
__global__ __launch_bounds__(64) void k_serial(
    const int* novel, const int* best, const unsigned char* maskraw,
    const float* act0, const int* misc,
    int* slot_seq, int* rankis, int* cnt, float* act_f)
{
    if (misc[3]) return;
    __shared__ float act[NSLOT];
    __shared__ int cntL[NSLOT];
    const int lane = threadIdx.x;
    const int u8 = (maskraw[1] == 1);
    for (int i = lane; i < NSLOT; i += 64) { act[i] = act0[i]; cntL[i] = 0; }
    __syncthreads();
    float cv; int ci;
    {
        cv = act[lane * 64]; ci = lane * 64;
        for (int u = 1; u < 64; u++) {
            float v = act[lane * 64 + u];
            if (v < cv) { cv = v; ci = lane * 64 + u; }
        }
    }
    for (int t = 0; t < TTOK; t++) {
        int nv = novel[t];
        int mk = (u8 ? (int)maskraw[t] : ((const int*)maskraw)[t]) != 0;
        int slot;
        if (nv) {
            float v = cv; int ix = ci;
            for (int off = 32; off >= 1; off >>= 1) {
                float ov = __shfl_xor(v, off);
                int oi = __shfl_xor(ix, off);
                if (ov < v || (ov == v && oi < ix)) { v = ov; ix = oi; }
            }
            slot = ix;
        } else {
            slot = best[t];
        }
        if (mk) {
            float a = act[slot];
            float a2 = fminf(1.0f, a + 0.1f);
            __syncthreads();
            if (lane == 0) {
                act[slot] = a2;
                slot_seq[t] = slot;
                int r = cntL[slot]; rankis[t] = r; cntL[slot] = r + 1;
            }
            __syncthreads();
            int c = slot >> 6;
            float v = act[c * 64 + lane]; int ix = c * 64 + lane;
            for (int off = 32; off >= 1; off >>= 1) {
                float ov = __shfl_xor(v, off);
                int oi = __shfl_xor(ix, off);
                if (ov < v || (ov == v && oi < ix)) { v = ov; ix = oi; }
            }
            if (lane == c) { cv = v; ci = ix; }
        } else {
            if (lane == 0) rankis[t] = -1;
        }
        __syncthreads();
    }
    for (int i = lane; i < NSLOT; i += 64) { cnt[i] = cntL[i]; act_f[i] = act[i]; }
}

// ------------------------------------------------- CSR build
__global__ __launch_bounds__(256) void k_offsets(const int* cnt, int* offs) {
    __shared__ int part[256];
    int tid = threadIdx.x;
    int base = tid * 16;
    int loc[16];
    int s = 0;
    #pragma unroll
    for (int i = 0; i < 16; i++) { loc[i] = s; s += cnt[base + i]; }
    part[tid] = s;
    __syncthreads();
    for (int off = 1; off < 256; off <<= 1) {
        int v = (tid >= off) ? part[tid - off] : 0;
        __syncthreads();
        part[tid] += v;
        __syncthreads();
    }
    int pre = (tid == 0) ? 0 : part[tid - 1];
    #pragma unroll
    for (int i = 0; i < 16; i++) offs[base + i] = pre + loc[i];
}

__global__ void k_scatter(const int* slot_seq, const int* rankis, const int* offs, int* listTok) {
    int t = blockIdx.x * 256 + threadIdx.x;
    if (t >= TTOK) return;
    int r = rankis[t];
    if (r >= 0) listTok[offs[slot_seq[t]] + r] = t;
}

// ------------------------------------------------- apply buffer writes per slot
__global__ __launch_bounds__(256) void k_apply(
    const float* __restrict__ keys0, const float* __restrict__ values0,
    const float* __restrict__ ka, const float* __restrict__ va,
    const int* __restrict__ novel, const int* __restrict__ cnt,
    const int* __restrict__ offs, const int* __restrict__ listTok,
    float* __restrict__ kb, float* __restrict__ vb)
{
    int s = blockIdx.x;
    int d = threadIdx.x;
    float kv = keys0[(size_t)s * DIM + d];
    float vv = values0[(size_t)s * DIM + d];
    int m = cnt[s], off = offs[s];
    for (int r = 0; r < m; r++) {
        int t = listTok[off + r];
        float al = novel[t] ? 0.9f : 0.3f;
        kv = (1.0f - al) * kv + al * ka[(size_t)t * DIM + d];
        vv = (1.0f - al) * vv + al * va[(size_t)t * DIM + d];
    }
    kb[(size_t)s * DIM + d] = kv;
    vb[(size_t)s * DIM + d] = vv;
}

// ------------------------------------------------- logit bias precompute
__global__ void k_prepla(const float* __restrict__ act_f, float* __restrict__ la) {
    int i = blockIdx.x * 256 + threadIdx.x;
    if (i >= NSLOT) return;
    float a = act_f[i];
    la[i] = (a < 0.01f) ? -INFINITY : logf(fmaxf(a, 1e-8f));
}

// ================================================= fused flash attention
// QBLK=16 queries/block, SBLK=64 slots/tile, 4 waves, 512 blocks.
__global__ __launch_bounds__(256, 2) void k_flash(
    const ushort_t* __restrict__ qa_bf,   // [8192][256]
    const ushort_t* __restrict__ kb_bf,   // [4096][256]
    const ushort_t* __restrict__ vbT,     // [256][4096]
    const float* __restrict__ la,         // [4096]
    float* __restrict__ out)              // [8192][256]
{
    __shared__ ushort_t sK[4 * 64 * 64];   // 32KB [kc][slot][64] swizzled
    __shared__ ushort_t sV[256 * 64];      // 32KB [d][slot] swizzled
    __shared__ ushort_t sP[QBLK * 64];     // 2KB  [row][slot] swizzled
    __shared__ float wstat[4 * QBLK];
    __shared__ float wsum[4 * QBLK];
    __shared__ float rowm[QBLK], rowl[QBLK], rfac[QBLK];

    const int tid = threadIdx.x;
    const int w = tid >> 6;
    const int lane = tid & 63;
    const int lr = lane & 15, lg = lane >> 4;
    const int q0 = blockIdx.x * QBLK;

    // Q into registers (per-wave replicated): rows q0+lr, k = kc*64+h*32+lg*8
    bf16x8 qreg[4][2];
    #pragma unroll
    for (int kc = 0; kc < 4; kc++)
        #pragma unroll
        for (int h = 0; h < 2; h++)
            qreg[kc][h] = *(const bf16x8*)&qa_bf[(size_t)(q0 + lr) * DIM + kc*64 + h*32 + lg*8];

    if (tid < QBLK) { rowm[tid] = -INFINITY; rowl[tid] = 0.0f; }

    f32x4 o_acc[4] = {};   // O[row=lg*4+r][d = w*64 + n*16 + lr]

    const int krow = tid >> 2, kseg = tid & 3;   // K staging: 4 thr/row, 64 rows
    const int vrow = tid >> 3, vseg = tid & 7;   // V staging: 8 thr/row, 32 rows/pass

    for (int s0 = 0; s0 < NSLOT; s0 += SBLK) {
        __syncthreads();   // protect sK/sV/sP from previous iteration readers
        #pragma unroll
        for (int p = 0; p < 8; p++) {            // K-tile: 64 rows x 256
            int g = p * 4 + kseg;                // 16B granule 0..31
            uint4 v = *(const uint4*)&kb_bf[(size_t)(s0 + krow) * DIM + g * 8];
            int kc = g >> 3, c64 = (g & 7) * 8;
            *(uint4*)&sK[kc * 4096 + krow * 64 + (c64 ^ ((krow & 7) << 3))] = v;
        }
        #pragma unroll
        for (int p = 0; p < 8; p++) {            // V^T-tile: 256 d-rows x 64
            int d = vrow + p * 32;
            uint4 v = *(const uint4*)&vbT[(size_t)d * NSLOT + s0 + vseg * 8];
            *(uint4*)&sV[d * 64 + ((vseg * 8) ^ ((d & 7) << 3))] = v;
        }
        __syncthreads();

        // S = Q K^T : wave w covers slots s0 + w*16 + lr
        f32x4 sacc = {0.f, 0.f, 0.f, 0.f};
        {
            int srow = w * 16 + lr;
            int sw = (srow & 7) << 3;
            #pragma unroll
            for (int kc = 0; kc < 4; kc++)
                #pragma unroll
                for (int h = 0; h < 2; h++) {
                    bf16x8 bF = *(const bf16x8*)&sK[kc * 4096 + srow * 64 + ((h * 32 + lg * 8) ^ sw)];
                    sacc = __builtin_amdgcn_mfma_f32_16x16x32_bf16(qreg[kc][h], bF, sacc, 0, 0, 0);
                }
        }
        float la_c = la[s0 + w * 16 + lr];
        float sl[4];
        #pragma unroll
        for (int r = 0; r < 4; r++) sl[r] = sacc[r] * SCALE + la_c;

        // per-row tile max (over 16 lanes lr)
        #pragma unroll
        for (int r = 0; r < 4; r++) {
            float v = sl[r];
            #pragma unroll
            for (int off = 1; off < 16; off <<= 1) v = fmaxf(v, __shfl_xor(v, off));
            if (lr == 0) wstat[w * QBLK + lg * 4 + r] = v;
        }
        __syncthreads();
        if (tid < QBLK) {
            float mo = rowm[tid];
            float mt = fmaxf(fmaxf(wstat[tid], wstat[QBLK + tid]),
                             fmaxf(wstat[2 * QBLK + tid], wstat[3 * QBLK + tid]));
            float mn = fmaxf(mo, mt);
            rfac[tid] = (mo == -INFINITY) ? 0.0f : __expf(mo - mn);
            rowm[tid] = mn;
        }
        __syncthreads();

        // P = exp(sl - m); write bf16 to sP; per-row partial sums
        #pragma unroll
        for (int r = 0; r < 4; r++) {
            int row = lg * 4 + r;
            float mn = rowm[row];
            float p = (sl[r] == -INFINITY) ? 0.0f : __expf(sl[r] - mn);
            int col = w * 16 + lr;
            sP[row * 64 + (col ^ ((row & 7) << 3))] = f2bf(p);
            float v = p;
            #pragma unroll
            for (int off = 1; off < 16; off <<= 1) v += __shfl_xor(v, off);
            if (lr == 0) wsum[w * QBLK + row] = v;
        }
        // rescale O by factor (regs only)
        #pragma unroll
        for (int r = 0; r < 4; r++) {
            float f = rfac[lg * 4 + r];
            #pragma unroll
            for (int n = 0; n < 4; n++) o_acc[n][r] *= f;
        }
        __syncthreads();
        if (tid < QBLK)
            rowl[tid] = rowl[tid] * rfac[tid]
                      + wsum[tid] + wsum[QBLK + tid] + wsum[2 * QBLK + tid] + wsum[3 * QBLK + tid];

        // PV: O += P · V ; A = P rows (q), B = sV rows (d), k = slots
        #pragma unroll
        for (int h = 0; h < 2; h++) {
            int prow = lr;
            bf16x8 aP = *(const bf16x8*)&sP[prow * 64 + ((h * 32 + lg * 8) ^ ((prow & 7) << 3))];
            #pragma unroll
            for (int n = 0; n < 4; n++) {
                int d = w * 64 + n * 16 + lr;
                bf16x8 bV = *(const bf16x8*)&sV[d * 64 + ((h * 32 + lg * 8) ^ ((d & 7) << 3))];
                o_acc[n] = __builtin_amdgcn_mfma_f32_16x16x32_bf16(aP, bV, o_acc[n], 0, 0, 0);
            }
        }
    }
    __syncthreads();
    #pragma unroll
    for (int n = 0; n < 4; n++) {
        int d = w * 64 + n * 16 + lr;
        #pragma unroll
        for (int r = 0; r < 4; r++) {
            int row = lg * 4 + r;
            out[(size_t)(q0 + row) * DIM + d] = o_acc[n][r] / rowl[row];
        }
    }
}

// ================================================================ launch
extern "C" void kernel_launch(void* const* d_in, const int* in_sizes, int n_in,
                              void* d_out, int out_size, void* d_ws, size_t ws_size,
                              hipStream_t stream)
{
    (void)in_sizes; (void)n_in; (void)out_size; (void)ws_size;
    const float* x       = (const float*)d_in[0];
    const unsigned char* mask = (const unsigned char*)d_in[1];
    const float* keys0   = (const float*)d_in[2];
    const float* values0 = (const float*)d_in[3];
    const float* act0    = (const float*)d_in[4];
    const float* Wk = (const float*)d_in[5];
    const float* bk = (const float*)d_in[6];
    const float* Wv = (const float*)d_in[7];
    const float* bv = (const float*)d_in[8];
    const float* Wq = (const float*)d_in[9];
    const float* bq = (const float*)d_in[10];
    float* out = (float*)d_out;

    uint8_t* w = (uint8_t*)d_ws;
    size_t off = 0;
    auto alloc = [&](size_t bytes) -> void* {
        void* p = w + off;
        off = (off + bytes + 255) & ~(size_t)255;
        return p;
    };
    float*    ka     = (float*)   alloc((size_t)TTOK * DIM * 4);
    float*    va_    = (float*)   alloc((size_t)TTOK * DIM * 4);
    float*    qa     = (float*)   alloc((size_t)TTOK * DIM * 4);
    float*    kb     = (float*)   alloc((size_t)NSLOT * DIM * 4);
    float*    vb     = (float*)   alloc((size_t)NSLOT * DIM * 4);
    ushort_t* x2     = (ushort_t*)alloc((size_t)TTOK * 512 * 2);
    ushort_t* w2k    = (ushort_t*)alloc((size_t)DIM * 512 * 2);
    ushort_t* w2v    = (ushort_t*)alloc((size_t)DIM * 512 * 2);
    ushort_t* w2q    = (ushort_t*)alloc((size_t)DIM * 512 * 2);
    ushort_t* ka_bf  = (ushort_t*)alloc((size_t)TTOK * DIM * 2);
    ushort_t* qa_bf  = (ushort_t*)alloc((size_t)TTOK * DIM * 2);
    ushort_t* k0_bf  = (ushort_t*)alloc((size_t)NSLOT * DIM * 2);
    ushort_t* kb_bf  = (ushort_t*)alloc((size_t)NSLOT * DIM * 2);
    ushort_t* vbT    = (ushort_t*)alloc((size_t)DIM * NSLOT * 2);
    float*    partV  = (float*)   alloc((size_t)32 * TTOK * 4);
    int*      partI  = (int*)     alloc((size_t)32 * TTOK * 4);
    float*    act_f  = (float*)   alloc((size_t)NSLOT * 4);
    float*    la     = (float*)   alloc((size_t)NSLOT * 4);
    int*      best   = (int*)     alloc((size_t)TTOK * 4);
    int*      novel  = (int*)     alloc((size_t)TTOK * 4);
    int*      slot_seq = (int*)   alloc((size_t)TTOK * 4);
    int*      rankis = (int*)     alloc((size_t)TTOK * 4);
    int*      cnt    = (int*)     alloc((size_t)NSLOT * 4);
    int*      offs   = (int*)     alloc((size_t)NSLOT * 4);
    int*      listTok= (int*)     alloc((size_t)TTOK * 4);
    u64*      cand   = (u64*)     alloc((size_t)CAPC * 8);
    int*      candJ  = (int*)     alloc((size_t)CAPC * 4);
    u64*      skey   = (u64*)     alloc((size_t)CAPC * 8);
    int*      sj     = (int*)     alloc((size_t)CAPC * 4);
    int*      hist   = (int*)     alloc((size_t)NBUCK * 4);
    int*      cnt2   = (int*)     alloc((size_t)NBUCK * 4);
    int*      offsB  = (int*)     alloc((size_t)NBUCK * 4);
    int*      misc   = (int*)     alloc(64);

    k_init<<<17, 256, 0, stream>>>(cnt, misc);
    k_zero2<<<NBUCK/256, 256, 0, stream>>>(hist, cnt2);

    // split-bf16 projections (fp32-accurate via [hi|lo] concat, K=512)
    k_split<<<TTOK*DIM/256, 256, 0, stream>>>(x, x2, TTOK);
    k_split<<<DIM*DIM/256, 256, 0, stream>>>(Wk, w2k, DIM);
    k_split<<<DIM*DIM/256, 256, 0, stream>>>(Wv, w2v, DIM);
    k_split<<<DIM*DIM/256, 256, 0, stream>>>(Wq, w2q, DIM);
    k_mm<3><<<dim3(TTOK/128, DIM/128, 1), 256, 0, stream>>>(
        x2, w2k, 512, 512, 0, 8, ka, (int*)ka_bf, bk);
    k_mm<3><<<dim3(TTOK/128, DIM/128, 1), 256, 0, stream>>>(
        x2, w2v, 512, 512, 0, 8, va_, nullptr, bv);
    k_mm<3><<<dim3(TTOK/128, DIM/128, 1), 256, 0, stream>>>(
        x2, w2q, 512, 512, 0, 8, qa, (int*)qa_bf, bq);

    k_cast<<<NSLOT*DIM/1024, 256, 0, stream>>>(keys0, k0_bf, NSLOT*DIM);
    k_mm<0><<<dim3(2048, 1, 1), 256, 0, stream>>>(
        ka_bf, k0_bf, DIM, DIM, 0, DIM/64, partV, partI, nullptr);
    k_bestmerge<<<TTOK/256, 256, 0, stream>>>(partV, partI, best, novel, misc);

    k_flags<<<TTOK/256, 256, 0, stream>>>(mask, act0, misc);
    k_ladder<<<NSLOT/256, 256, 0, stream>>>(act0, cand, candJ, misc);
    k_finalize<<<1, 1, 0, stream>>>(misc);
    k_hist<<<CAPC/256, 256, 0, stream>>>(cand, misc, hist);
    k_scanhist<<<1, 1024, 0, stream>>>(hist, offsB);
    k_place<<<CAPC/256, 256, 0, stream>>>(cand, candJ, misc, offsB, cnt2, skey, sj);
    k_rank2<<<CAPC/256, 256, 0, stream>>>(skey, sj, misc, offsB, hist, slot_seq, rankis, cnt);
    k_actfinal<<<NSLOT/256, 256, 0, stream>>>(act0, cnt, act_f, misc);
    k_serial<<<1, 64, 0, stream>>>(novel, best, mask, act0, misc, slot_seq, rankis, cnt, act_f);
    k_offsets<<<1, 256, 0, stream>>>(cnt, offs);
    k_scatter<<<TTOK/256, 256, 0, stream>>>(slot_seq, rankis, offs, listTok);
    k_apply<<<NSLOT, 256, 0, stream>>>(keys0, values0, ka, va_, novel, cnt, offs, listTok, kb, vb);

    k_cast<<<NSLOT*DIM/1024, 256, 0, stream>>>(kb, kb_bf, NSLOT*DIM);
    k_transV<<<dim3(NSLOT/32, DIM/32), 256, 0, stream>>>(vb, vbT);
    k_prepla<<<NSLOT/256, 256, 0, stream>>>(act_f, la);

    k_flash<<<TTOK/QBLK, 256, 0, stream>>>(qa_bf, kb_bf, vbT, la, out);
}

// Round 6
// 416.190 us; speedup vs baseline: 3.3374x; 1.3468x over previous
//
#include <hip/hip_runtime.h>
#include <hip/hip_bf16.h>
#include <math.h>
#include <stdint.h>

// Problem constants (B=8,S=1024,D=256,N=4096)
#define TTOK 8192
#define DIM 256
#define NSLOT 4096
#define CAPC 65536
#define NBUCK 65536
#define SCALE 0.0625f     // 1/sqrt(256), exact
#define QBLK 64
#define SPLIT 4

typedef unsigned long long u64;
typedef unsigned short ushort_t;
typedef __attribute__((ext_vector_type(8))) __bf16 bf16x8;
typedef __attribute__((ext_vector_type(4))) float f32x4;

__device__ inline ushort_t f2bf(float f) {
    unsigned u = __float_as_uint(f);
    unsigned r = (u + 0x7fffu + ((u >> 16) & 1u)) >> 16;   // RNE
    return (ushort_t)r;
}
__device__ inline int bucketof(float w) {
    int b = (int)(w * 65536.0f);
    return b > 65535 ? 65535 : b;
}

// misc[0]=cand count, misc[1]=flagA, misc[2]=flagB, misc[3]=fast-path valid

// ---------------------------------------------------------------- init
__global__ void k_init(int* cnt, int* misc) {
    int t = blockIdx.x * 256 + threadIdx.x;
    if (t < NSLOT) cnt[t] = 0;
    if (t == 0) { misc[0] = 0; misc[1] = 1; misc[2] = 1; misc[3] = 0; }
}
__global__ void k_zero2(int* hist, int* cnt2) {
    int i = blockIdx.x * 256 + threadIdx.x;
    hist[i] = 0; cnt2[i] = 0;
}

// ------------------------------------------- split fp32 -> [hi|lo] bf16 (K doubled)
__global__ void k_split(const float* __restrict__ in, ushort_t* __restrict__ out2, int rows) {
    int i = blockIdx.x * 256 + threadIdx.x;
    if (i >= rows * 256) return;
    int t = i >> 8, k = i & 255;
    float v = in[i];
    ushort_t h = f2bf(v);
    float hf = __uint_as_float(((unsigned)h) << 16);
    ushort_t l = f2bf(v - hf);
    out2[(size_t)t * 512 + k] = h;
    out2[(size_t)t * 512 + 256 + k] = l;
}

// ---------------------------------------------------------------- fp32->bf16 cast
__global__ void k_cast(const float* __restrict__ in, ushort_t* __restrict__ out, int n) {
    int i = (blockIdx.x * 256 + threadIdx.x) * 4;
    if (i >= n) return;
    float4 v = *(const float4*)&in[i];
    ushort4 o;
    o.x = f2bf(v.x); o.y = f2bf(v.y); o.z = f2bf(v.z); o.w = f2bf(v.w);
    *(ushort4*)&out[i] = o;
}

// ---------------------------------------------------------------- vb -> vbT (bf16)
__global__ __launch_bounds__(256) void k_transV(const float* __restrict__ vb, ushort_t* __restrict__ vbT) {
    __shared__ float ts[32][33];
    int tx = threadIdx.x & 31, ty = threadIdx.x >> 5;
    int s0 = blockIdx.x * 32, d0 = blockIdx.y * 32;
    #pragma unroll
    for (int j = 0; j < 4; j++)
        ts[ty + j*8][tx] = vb[(size_t)(s0 + ty + j*8) * DIM + d0 + tx];
    __syncthreads();
    #pragma unroll
    for (int j = 0; j < 4; j++)
        vbT[(size_t)(d0 + ty + j*8) * NSLOT + s0 + tx] = f2bf(ts[tx][ty + j*8]);
}

// =============================================================== MFMA GEMM
// MODE 0: simmax -> per-row max/argmax, XCD-swizzled 1-D grid (2048)
// MODE 3: proj   -> outF = acc + bias; optional bf16 copy via outI
template<int MODE>
__global__ __launch_bounds__(256) void k_mm(
    const ushort_t* __restrict__ A, const ushort_t* __restrict__ B,
    int lda, int ldb, int rowA_off, int ksteps,
    float* __restrict__ outF, int* __restrict__ outI,
    const float* __restrict__ actf)
{
    __shared__ ushort_t sA[128 * 64];
    __shared__ ushort_t sB[128 * 64];
    const int tid = threadIdx.x;
    const int lane = tid & 63;
    const int w = tid >> 6;
    const int wr = w >> 1, wc = w & 1;
    const int lr = lane & 15, lg = lane >> 4;
    int bx = blockIdx.x, by = blockIdx.y;
    if (MODE == 0) {   // XCD-aware decode: xcd owns by-range [xcd*4, xcd*4+4)
        int lin = blockIdx.x;
        int xcd = lin & 7, pos = lin >> 3;
        bx = pos >> 2;
        by = (xcd << 2) | (pos & 3);
    }
    const int kbase = 0;
    const int rA0 = rowA_off + bx * 128;
    const int rB0 = by * 128;
    const int ex = (tid & 7) * 8;
    const int rsub = tid >> 3;

    f32x4 acc[4][4] = {};
    uint4 ra[4], rb[4];

    #pragma unroll
    for (int j = 0; j < 4; j++) {
        int row = j * 32 + rsub;
        ra[j] = *(const uint4*)&A[(size_t)(rA0 + row) * lda + kbase + ex];
        rb[j] = *(const uint4*)&B[(size_t)(rB0 + row) * ldb + kbase + ex];
    }
    for (int step = 0; step < ksteps; step++) {
        __syncthreads();
        #pragma unroll
        for (int j = 0; j < 4; j++) {
            int row = j * 32 + rsub;
            int xi = ex ^ ((row & 7) << 3);
            *(uint4*)&sA[row * 64 + xi] = ra[j];
            *(uint4*)&sB[row * 64 + xi] = rb[j];
        }
        __syncthreads();
        if (step + 1 < ksteps) {
            int k0 = kbase + (step + 1) * 64;
            #pragma unroll
            for (int j = 0; j < 4; j++) {
                int row = j * 32 + rsub;
                ra[j] = *(const uint4*)&A[(size_t)(rA0 + row) * lda + k0 + ex];
                rb[j] = *(const uint4*)&B[(size_t)(rB0 + row) * ldb + k0 + ex];
            }
        }
        #pragma unroll
        for (int h = 0; h < 2; h++) {
            int xs = (h * 32 + lg * 8) ^ ((lr & 7) << 3);
            bf16x8 aF[4], bF[4];
            #pragma unroll
            for (int m = 0; m < 4; m++)
                aF[m] = *(const bf16x8*)&sA[(wr * 64 + m * 16 + lr) * 64 + xs];
            #pragma unroll
            for (int n = 0; n < 4; n++)
                bF[n] = *(const bf16x8*)&sB[(wc * 64 + n * 16 + lr) * 64 + xs];
            #pragma unroll
            for (int m = 0; m < 4; m++)
                #pragma unroll
                for (int n = 0; n < 4; n++)
                    acc[m][n] = __builtin_amdgcn_mfma_f32_16x16x32_bf16(aF[m], bF[n], acc[m][n], 0, 0, 0);
        }
    }

    // ---------------- epilogue ----------------
    if (MODE == 0) {
        __syncthreads();   // all waves done reading sA/sB
        float* sRedV = (float*)sA;
        int*   sRedI = (int*)(sA + 2048);
        #pragma unroll
        for (int m = 0; m < 4; m++) {
            #pragma unroll
            for (int r = 0; r < 4; r++) {
                float bv = acc[m][0][r];
                int bi = wc * 64 + lr;
                #pragma unroll
                for (int n = 1; n < 4; n++) {
                    float v = acc[m][n][r];
                    int c = wc * 64 + n * 16 + lr;
                    if (v > bv) { bv = v; bi = c; }
                }
                #pragma unroll
                for (int off = 1; off < 16; off <<= 1) {
                    float ov = __shfl_xor(bv, off);
                    int oi = __shfl_xor(bi, off);
                    if (ov > bv || (ov == bv && oi < bi)) { bv = ov; bi = oi; }
                }
                if (lr == 0) {
                    int row = wr * 64 + m * 16 + lg * 4 + r;
                    sRedV[wc * 128 + row] = bv;
                    sRedI[wc * 128 + row] = bi;
                }
            }
        }
        __syncthreads();
        if (tid < 128) {
            float v0 = sRedV[tid]; int i0 = sRedI[tid];
            float v1 = sRedV[128 + tid]; int i1 = sRedI[128 + tid];
            bool take = (v1 > v0);
            float bv = take ? v1 : v0;
            int bi = by * 128 + (take ? i1 : i0);
            outF[(size_t)by * TTOK + bx * 128 + tid] = bv;
            outI[(size_t)by * TTOK + bx * 128 + tid] = bi;
        }
    } else {   // MODE 3: projection epilogue
        ushort_t* obf = (ushort_t*)outI;
        #pragma unroll
        for (int n = 0; n < 4; n++) {
            int gcol = by * 128 + wc * 64 + n * 16 + lr;
            float bj = actf[gcol];
            #pragma unroll
            for (int m = 0; m < 4; m++)
                #pragma unroll
                for (int r = 0; r < 4; r++) {
                    int grow = bx * 128 + wr * 64 + m * 16 + lg * 4 + r;
                    float v = acc[m][n][r] + bj;
                    outF[(size_t)grow * DIM + gcol] = v;
                    if (obf) obf[(size_t)grow * DIM + gcol] = f2bf(v);
                }
        }
    }
}

// ---------------------------------------------------------------- merge 32 partials
__global__ void k_bestmerge(const float* partV, const int* partI,
                            int* best, int* novel, int* misc) {
    int t = blockIdx.x * 256 + threadIdx.x;
    if (t >= TTOK) return;
    float bv = partV[t]; int bi = partI[t];
    #pragma unroll
    for (int q = 1; q < 32; q++) {
        float v = partV[(size_t)q * TTOK + t];
        int i = partI[(size_t)q * TTOK + t];
        if (v > bv || (v == bv && i < bi)) { bv = v; bi = i; }
    }
    best[t] = bi;
    int nv = (bv * SCALE < 0.5f) ? 1 : 0;
    novel[t] = nv;
    if (!nv) atomicAnd(&misc[1], 0);
}

// --------------------------------------------------------------- flags
__global__ void k_flags(const unsigned char* maskraw, const float* act0, int* misc) {
    int t = blockIdx.x * 256 + threadIdx.x;
    int u8 = (maskraw[1] == 1);
    if (t < TTOK) {
        int mv = u8 ? (int)maskraw[t] : ((const int*)maskraw)[t];
        if (mv == 0) atomicAnd(&misc[1], 0);
    }
    if (t < NSLOT) {
        float a = act0[t];
        if (!(a >= 0.0f)) atomicAnd(&misc[1], 0);
    }
}

// ------------------------------------------------- ladder candidate generation
__global__ void k_ladder(const float* act0, u64* cand, int* candJ, int* misc) {
    if (misc[1] == 0) return;
    int i = blockIdx.x * 256 + threadIdx.x;
    if (i >= NSLOT) return;
    float w = act0[i];
    int j = 0;
    while (w < 1.0f) {
        if (j >= 48) { atomicAnd(&misc[2], 0); break; }
        int pos = atomicAdd(&misc[0], 1);
        if (pos >= CAPC) { atomicAnd(&misc[2], 0); break; }
        cand[pos] = ((u64)__float_as_uint(w) << 32) | (unsigned)i;
        candJ[pos] = j;
        j++;
        w = fminf(1.0f, w + 0.1f);
    }
}

__global__ void k_finalize(int* misc) {
    misc[3] = (misc[1] && misc[2] && misc[0] >= TTOK) ? 1 : 0;
}

// ------------------------------------------------- histogram ranking (exact)
__global__ void k_hist(const u64* cand, const int* misc, int* hist) {
    if (!(misc[1] && misc[2])) return;
    int K = misc[0]; if (K > CAPC) K = CAPC;
    int i = blockIdx.x * 256 + threadIdx.x;
    if (i >= K) return;
    float w = __uint_as_float((unsigned)(cand[i] >> 32));
    atomicAdd(&hist[bucketof(w)], 1);
}

__global__ __launch_bounds__(1024) void k_scanhist(const int* __restrict__ hist, int* __restrict__ offsB) {
    __shared__ int part[1024];
    int tid = threadIdx.x;
    int base = tid * 64;
    int s = 0;
    for (int i = 0; i < 64; i++) s += hist[base + i];
    part[tid] = s;
    __syncthreads();
    for (int off = 1; off < 1024; off <<= 1) {
        int v = (tid >= off) ? part[tid - off] : 0;
        __syncthreads();
        part[tid] += v;
        __syncthreads();
    }
    int pre = (tid == 0) ? 0 : part[tid - 1];
    for (int i = 0; i < 64; i++) { offsB[base + i] = pre; pre += hist[base + i]; }
}

__global__ void k_place(const u64* cand, const int* candJ, const int* misc,
                        const int* offsB, int* cnt2, u64* skey, int* sj) {
    if (!(misc[1] && misc[2])) return;
    int K = misc[0]; if (K > CAPC) K = CAPC;
    int i = blockIdx.x * 256 + threadIdx.x;
    if (i >= K) return;
    u64 key = cand[i];
    float w = __uint_as_float((unsigned)(key >> 32));
    int b = bucketof(w);
    int pos = offsB[b] + atomicAdd(&cnt2[b], 1);
    skey[pos] = key; sj[pos] = candJ[i];
}

__global__ void k_rank2(const u64* __restrict__ skey, const int* __restrict__ sj, const int* misc,
                        const int* __restrict__ offsB, const int* __restrict__ hist,
                        int* slot_seq, int* rankis, int* cnt) {
    if (!(misc[1] && misc[2])) return;
    int K = misc[0]; if (K > CAPC) K = CAPC;
    int i = blockIdx.x * 256 + threadIdx.x;
    if (i >= K) return;
    u64 my = skey[i];
    float w = __uint_as_float((unsigned)(my >> 32));
    int b = bucketof(w);
    int base = offsB[b], n = hist[b];
    int r = base;
    for (int q = 0; q < n; q++) r += (skey[base + q] < my) ? 1 : 0;
    if (r < TTOK) {
        int slot = (int)(my & 0xffffffffu);
        slot_seq[r] = slot;
        rankis[r] = sj[i];
        atomicAdd(&cnt[slot], 1);
    }
}

__global__ void k_actfinal(const float* act0, const int* cnt, float* act_f, const int* misc) {
    if (!misc[3]) return;
    int i = blockIdx.x * 256 + threadIdx.x;
    if (i >= NSLOT) return;
    float a = act0[i];
    int m = cnt[i];
    for (int r = 0; r < m; r++) a = fminf(1.0f, a + 0.1f);
    act_f[i] = a;
}

// ------------------------------------------------- serial fallback (cold path)
__global__ __launch_bounds__(64) void k_serial(
    const int* novel, const int* best, const unsigned char* maskraw,
    const float* act0, const int* misc,
    int* slot_seq, int* rankis, int* cnt, float* act_f)
{
    if (misc[3]) return;
    __shared__ float act[NSLOT];
    __shared__ int cntL[NSLOT];
    const int lane = threadIdx.x;
    const int u8 = (maskraw[1] == 1);
    for (int i = lane; i < NSLOT; i += 64) { act[i] = act0[i]; cntL[i] = 0; }
    __syncthreads();
    float cv; int ci;
    {
        cv = act[lane * 64]; ci = lane * 64;
        for (int u = 1; u < 64; u++) {
            float v = act[lane * 64 + u];
            if (v < cv) { cv = v; ci = lane * 64 + u; }
        }
    }
    for (int t = 0; t < TTOK; t++) {
        int nv = novel[t];
        int mk = (u8 ? (int)maskraw[t] : ((const int*)maskraw)[t]) != 0;
        int slot;
        if (nv) {
            float v = cv; int ix = ci;
            for (int off = 32; off >= 1; off >>= 1) {
                float ov = __shfl_xor(v, off);
                int oi = __shfl_xor(ix, off);
                if (ov < v || (ov == v && oi < ix)) { v = ov; ix = oi; }
            }
            slot = ix;
        } else {
            slot = best[t];
        }
        if (mk) {
            float a = act[slot];
            float a2 = fminf(1.0f, a + 0.1f);
            __syncthreads();
            if (lane == 0) {
                act[slot] = a2;
                slot_seq[t] = slot;
                int r = cntL[slot]; rankis[t] = r; cntL[slot] = r + 1;
            }
            __syncthreads();
            int c = slot >> 6;
            float v = act[c * 64 + lane]; int ix = c * 64 + lane;
            for (int off = 32; off >= 1; off >>= 1) {
                float ov = __shfl_xor(v, off);
                int oi = __shfl_xor(ix, off);
                if (ov < v || (ov == v && oi < ix)) { v = ov; ix = oi; }
            }
            if (lane == c) { cv = v; ci = ix; }
        } else {
            if (lane == 0) rankis[t] = -1;
        }
        __syncthreads();
    }
    for (int i = lane; i < NSLOT; i += 64) { cnt[i] = cntL[i]; act_f[i] = act[i]; }
}

// ------------------------------------------------- CSR build
__global__ __launch_bounds__(256) void k_offsets(const int* cnt, int* offs) {
    __shared__ int part[256];
    int tid = threadIdx.x;
    int base = tid * 16;
    int loc[16];
    int s = 0;
    #pragma unroll
    for (int i = 0; i < 16; i++) { loc[i] = s; s += cnt[base + i]; }
    part[tid] = s;
    __syncthreads();
    for (int off = 1; off < 256; off <<= 1) {
        int v = (tid >= off) ? part[tid - off] : 0;
        __syncthreads();
        part[tid] += v;
        __syncthreads();
    }
    int pre = (tid == 0) ? 0 : part[tid - 1];
    #pragma unroll
    for (int i = 0; i < 16; i++) offs[base + i] = pre + loc[i];
}

__global__ void k_scatter(const int* slot_seq, const int* rankis, const int* offs, int* listTok) {
    int t = blockIdx.x * 256 + threadIdx.x;
    if (t >= TTOK) return;
    int r = rankis[t];
    if (r >= 0) listTok[offs[slot_seq[t]] + r] = t;
}

// ------------------------------------------------- apply buffer writes per slot
__global__ __launch_bounds__(256) void k_apply(
    const float* __restrict__ keys0, const float* __restrict__ values0,
    const float* __restrict__ ka, const float* __restrict__ va,
    const int* __restrict__ novel, const int* __restrict__ cnt,
    const int* __restrict__ offs, const int* __restrict__ listTok,
    float* __restrict__ kb, float* __restrict__ vb)
{
    int s = blockIdx.x;
    int d = threadIdx.x;
    float kv = keys0[(size_t)s * DIM + d];
    float vv = values0[(size_t)s * DIM + d];
    int m = cnt[s], off = offs[s];
    for (int r = 0; r < m; r++) {
        int t = listTok[off + r];
        float al = novel[t] ? 0.9f : 0.3f;
        kv = (1.0f - al) * kv + al * ka[(size_t)t * DIM + d];
        vv = (1.0f - al) * vv + al * va[(size_t)t * DIM + d];
    }
    kb[(size_t)s * DIM + d] = kv;
    vb[(size_t)s * DIM + d] = vv;
}

// ------------------------------------------------- logit bias precompute
__global__ void k_prepla(const float* __restrict__ act_f, float* __restrict__ la) {
    int i = blockIdx.x * 256 + threadIdx.x;
    if (i >= NSLOT) return;
    float a = act_f[i];
    la[i] = (a < 0.01f) ? -INFINITY : logf(fmaxf(a, 1e-8f));
}

// ================================================= fused flash attention (no-max)
// QBLK=64 (wave owns 16 private q-rows), SBLK=64, 4-way slot split.
// Logits are bounded (|sim*scale|<~6, log(act)<=0) so exp() needs no max shift;
// softmax shift-invariance => identical result up to rounding.
__global__ __launch_bounds__(256, 2) void k_flash(
    const ushort_t* __restrict__ qa_bf,   // [8192][256]
    const ushort_t* __restrict__ kb_bf,   // [4096][256]
    const ushort_t* __restrict__ vbT,     // [256][4096]
    const float* __restrict__ la,         // [4096]
    float* __restrict__ opart,            // [SPLIT][8192][256] unnormalized
    float* __restrict__ lpart)            // [SPLIT][8192]
{
    __shared__ ushort_t sK[4 * 64 * 64];   // 32KB [kc][slot][64] swizzled
    __shared__ ushort_t sV[256 * 64];      // 32KB [d][slot] swizzled
    __shared__ ushort_t sP[4][16 * 64];    // 8KB per-wave private P tiles

    const int tid = threadIdx.x;
    const int w = tid >> 6;
    const int lane = tid & 63;
    const int lr = lane & 15, lg = lane >> 4;
    const int qw = blockIdx.x * QBLK + w * 16;   // wave's first q-row
    const int z = blockIdx.y;
    const int sbase = z * (NSLOT / SPLIT);

    // Q for this wave's 16 rows: row qw+lr, k = kc*64 + h*32 + lg*8
    bf16x8 qreg[4][2];
    #pragma unroll
    for (int kc = 0; kc < 4; kc++)
        #pragma unroll
        for (int h = 0; h < 2; h++)
            qreg[kc][h] = *(const bf16x8*)&qa_bf[(size_t)(qw + lr) * DIM + kc*64 + h*32 + lg*8];

    f32x4 o_acc[16] = {};      // O[row=lg*4+r][d = nd*16 + lr]
    float lsum[4] = {0.f, 0.f, 0.f, 0.f};

    const int krow = tid >> 2, kseg = tid & 3;   // K staging: 4 thr/row
    const int vrow = tid >> 3, vseg = tid & 7;   // V staging: 8 thr/row

    for (int it = 0; it < NSLOT / SPLIT / 64; ++it) {
        int s0 = sbase + it * 64;
        __syncthreads();   // prior tile fully consumed
        #pragma unroll
        for (int p = 0; p < 8; p++) {            // K-tile 64 x 256
            int g = p * 4 + kseg;
            uint4 v = *(const uint4*)&kb_bf[(size_t)(s0 + krow) * DIM + g * 8];
            int kc = g >> 3, c64 = (g & 7) * 8;
            *(uint4*)&sK[kc * 4096 + krow * 64 + (c64 ^ ((krow & 7) << 3))] = v;
        }
        #pragma unroll
        for (int p = 0; p < 8; p++) {            // V^T-tile 256 x 64
            int d = vrow + p * 32;
            uint4 v = *(const uint4*)&vbT[(size_t)d * NSLOT + s0 + vseg * 8];
            *(uint4*)&sV[d * 64 + ((vseg * 8) ^ ((d & 7) << 3))] = v;
        }
        __syncthreads();

        float la_r[4];
        #pragma unroll
        for (int n = 0; n < 4; n++) la_r[n] = la[s0 + n * 16 + lr];

        // S = Q K^T for this wave's 16 rows x 64 slots
        f32x4 accs[4] = {};
        #pragma unroll
        for (int n = 0; n < 4; n++) {
            int srow = n * 16 + lr;
            int sw = (srow & 7) << 3;
            #pragma unroll
            for (int kc = 0; kc < 4; kc++)
                #pragma unroll
                for (int h = 0; h < 2; h++) {
                    bf16x8 bF = *(const bf16x8*)&sK[kc * 4096 + srow * 64 + ((h * 32 + lg * 8) ^ sw)];
                    accs[n] = __builtin_amdgcn_mfma_f32_16x16x32_bf16(qreg[kc][h], bF, accs[n], 0, 0, 0);
                }
        }

        // P = exp(S*scale + la) directly (no max shift); private sP, register lsum
        #pragma unroll
        for (int n = 0; n < 4; n++)
            #pragma unroll
            for (int r = 0; r < 4; r++) {
                int row = lg * 4 + r;
                float p = __expf(accs[n][r] * SCALE + la_r[n]);
                sP[w][row * 64 + ((n * 16 + lr) ^ ((row & 7) << 3))] = f2bf(p);
                lsum[r] += p;
            }

        // PV: O += P * V (same-wave sP write->read; compiler inserts lgkmcnt)
        #pragma unroll
        for (int h = 0; h < 2; h++) {
            bf16x8 aP = *(const bf16x8*)&sP[w][lr * 64 + ((h * 32 + lg * 8) ^ ((lr & 7) << 3))];
            #pragma unroll
            for (int nd = 0; nd < 16; nd++) {
                int d = nd * 16 + lr;
                bf16x8 bV = *(const bf16x8*)&sV[d * 64 + ((h * 32 + lg * 8) ^ ((d & 7) << 3))];
                o_acc[nd] = __builtin_amdgcn_mfma_f32_16x16x32_bf16(aP, bV, o_acc[nd], 0, 0, 0);
            }
        }
    }

    // row sums: reduce per-lane partials over the 16 lr lanes
    #pragma unroll
    for (int r = 0; r < 4; r++) {
        #pragma unroll
        for (int off = 1; off < 16; off <<= 1) lsum[r] += __shfl_xor(lsum[r], off);
        if (lr == 0) lpart[(size_t)z * TTOK + qw + lg * 4 + r] = lsum[r];
    }
    #pragma unroll
    for (int nd = 0; nd < 16; nd++)
        #pragma unroll
        for (int r = 0; r < 4; r++)
            opart[((size_t)z * TTOK + qw + lg * 4 + r) * DIM + nd * 16 + lr] = o_acc[nd][r];
}

// ------------------------------------------------- combine split partials
__global__ void k_comb(const float* __restrict__ opart, const float* __restrict__ lpart,
                       float* __restrict__ out) {
    int idx = blockIdx.x * 256 + threadIdx.x;   // over 8192*256
    int t = idx >> 8;
    float den = lpart[t] + lpart[TTOK + t] + lpart[2 * TTOK + t] + lpart[3 * TTOK + t];
    float num = opart[idx] + opart[(size_t)TTOK * DIM + idx]
              + opart[2 * (size_t)TTOK * DIM + idx] + opart[3 * (size_t)TTOK * DIM + idx];
    out[idx] = num / den;
}

// ================================================================ launch
extern "C" void kernel_launch(void* const* d_in, const int* in_sizes, int n_in,
                              void* d_out, int out_size, void* d_ws, size_t ws_size,
                              hipStream_t stream)
{
    (void)in_sizes; (void)n_in; (void)out_size; (void)ws_size;
    const float* x       = (const float*)d_in[0];
    const unsigned char* mask = (const unsigned char*)d_in[1];
    const float* keys0   = (const float*)d_in[2];
    const float* values0 = (const float*)d_in[3];
    const float* act0    = (const float*)d_in[4];
    const float* Wk = (const float*)d_in[5];
    const float* bk = (const float*)d_in[6];
    const float* Wv = (const float*)d_in[7];
    const float* bv = (const float*)d_in[8];
    const float* Wq = (const float*)d_in[9];
    const float* bq = (const float*)d_in[10];
    float* out = (float*)d_out;

    uint8_t* w = (uint8_t*)d_ws;
    size_t off = 0;
    auto alloc = [&](size_t bytes) -> void* {
        void* p = w + off;
        off = (off + bytes + 255) & ~(size_t)255;
        return p;
    };
    float*    ka     = (float*)   alloc((size_t)TTOK * DIM * 4);
    float*    va_    = (float*)   alloc((size_t)TTOK * DIM * 4);
    float*    qa     = (float*)   alloc((size_t)TTOK * DIM * 4);
    float*    kb     = (float*)   alloc((size_t)NSLOT * DIM * 4);
    float*    vb     = (float*)   alloc((size_t)NSLOT * DIM * 4);
    ushort_t* x2     = (ushort_t*)alloc((size_t)TTOK * 512 * 2);
    ushort_t* w2k    = (ushort_t*)alloc((size_t)DIM * 512 * 2);
    ushort_t* w2v    = (ushort_t*)alloc((size_t)DIM * 512 * 2);
    ushort_t* w2q    = (ushort_t*)alloc((size_t)DIM * 512 * 2);
    ushort_t* ka_bf  = (ushort_t*)alloc((size_t)TTOK * DIM * 2);
    ushort_t* qa_bf  = (ushort_t*)alloc((size_t)TTOK * DIM * 2);
    ushort_t* k0_bf  = (ushort_t*)alloc((size_t)NSLOT * DIM * 2);
    ushort_t* kb_bf  = (ushort_t*)alloc((size_t)NSLOT * DIM * 2);
    ushort_t* vbT    = (ushort_t*)alloc((size_t)DIM * NSLOT * 2);
    float*    opart  = (float*)   alloc((size_t)SPLIT * TTOK * DIM * 4);
    float*    lpart  = (float*)   alloc((size_t)SPLIT * TTOK * 4);
    float*    partV  = (float*)   alloc((size_t)32 * TTOK * 4);
    int*      partI  = (int*)     alloc((size_t)32 * TTOK * 4);
    float*    act_f  = (float*)   alloc((size_t)NSLOT * 4);
    float*    la     = (float*)   alloc((size_t)NSLOT * 4);
    int*      best   = (int*)     alloc((size_t)TTOK * 4);
    int*      novel  = (int*)     alloc((size_t)TTOK * 4);
    int*      slot_seq = (int*)   alloc((size_t)TTOK * 4);
    int*      rankis = (int*)     alloc((size_t)TTOK * 4);
    int*      cnt    = (int*)     alloc((size_t)NSLOT * 4);
    int*      offs   = (int*)     alloc((size_t)NSLOT * 4);
    int*      listTok= (int*)     alloc((size_t)TTOK * 4);
    u64*      cand   = (u64*)     alloc((size_t)CAPC * 8);
    int*      candJ  = (int*)     alloc((size_t)CAPC * 4);
    u64*      skey   = (u64*)     alloc((size_t)CAPC * 8);
    int*      sj     = (int*)     alloc((size_t)CAPC * 4);
    int*      hist   = (int*)     alloc((size_t)NBUCK * 4);
    int*      cnt2   = (int*)     alloc((size_t)NBUCK * 4);
    int*      offsB  = (int*)     alloc((size_t)NBUCK * 4);
    int*      misc   = (int*)     alloc(64);

    k_init<<<17, 256, 0, stream>>>(cnt, misc);
    k_zero2<<<NBUCK/256, 256, 0, stream>>>(hist, cnt2);

    // split-bf16 projections (fp32-accurate via [hi|lo] concat, K=512)
    k_split<<<TTOK*DIM/256, 256, 0, stream>>>(x, x2, TTOK);
    k_split<<<DIM*DIM/256, 256, 0, stream>>>(Wk, w2k, DIM);
    k_split<<<DIM*DIM/256, 256, 0, stream>>>(Wv, w2v, DIM);
    k_split<<<DIM*DIM/256, 256, 0, stream>>>(Wq, w2q, DIM);
    k_mm<3><<<dim3(TTOK/128, DIM/128, 1), 256, 0, stream>>>(
        x2, w2k, 512, 512, 0, 8, ka, (int*)ka_bf, bk);
    k_mm<3><<<dim3(TTOK/128, DIM/128, 1), 256, 0, stream>>>(
        x2, w2v, 512, 512, 0, 8, va_, nullptr, bv);
    k_mm<3><<<dim3(TTOK/128, DIM/128, 1), 256, 0, stream>>>(
        x2, w2q, 512, 512, 0, 8, qa, (int*)qa_bf, bq);

    k_cast<<<NSLOT*DIM/1024, 256, 0, stream>>>(keys0, k0_bf, NSLOT*DIM);
    k_mm<0><<<dim3(2048, 1, 1), 256, 0, stream>>>(
        ka_bf, k0_bf, DIM, DIM, 0, DIM/64, partV, partI, nullptr);
    k_bestmerge<<<TTOK/256, 256, 0, stream>>>(partV, partI, best, novel, misc);

    k_flags<<<TTOK/256, 256, 0, stream>>>(mask, act0, misc);
    k_ladder<<<NSLOT/256, 256, 0, stream>>>(act0, cand, candJ, misc);
    k_finalize<<<1, 1, 0, stream>>>(misc);
    k_hist<<<CAPC/256, 256, 0, stream>>>(cand, misc, hist);
    k_scanhist<<<1, 1024, 0, stream>>>(hist, offsB);
    k_place<<<CAPC/256, 256, 0, stream>>>(cand, candJ, misc, offsB, cnt2, skey, sj);
    k_rank2<<<CAPC/256, 256, 0, stream>>>(skey, sj, misc, offsB, hist, slot_seq, rankis, cnt);
    k_actfinal<<<NSLOT/256, 256, 0, stream>>>(act0, cnt, act_f, misc);
    k_serial<<<1, 64, 0, stream>>>(novel, best, mask, act0, misc, slot_seq, rankis, cnt, act_f);
    k_offsets<<<1, 256, 0, stream>>>(cnt, offs);
    k_scatter<<<TTOK/256, 256, 0, stream>>>(slot_seq, rankis, offs, listTok);
    k_apply<<<NSLOT, 256, 0, stream>>>(keys0, values0, ka, va_, novel, cnt, offs, listTok, kb, vb);

    k_cast<<<NSLOT*DIM/1024, 256, 0, stream>>>(kb, kb_bf, NSLOT*DIM);
    k_transV<<<dim3(NSLOT/32, DIM/32), 256, 0, stream>>>(vb, vbT);
    k_prepla<<<NSLOT/256, 256, 0, stream>>>(act_f, la);

    k_flash<<<dim3(TTOK/QBLK, SPLIT), 256, 0, stream>>>(qa_bf, kb_bf, vbT, la, opart, lpart);
    k_comb<<<TTOK*DIM/256, 256, 0, stream>>>(opart, lpart, out);
}

// Round 7
// 367.532 us; speedup vs baseline: 3.7793x; 1.1324x over previous
//
#include <hip/hip_runtime.h>
#include <hip/hip_bf16.h>
#include <math.h>
#include <stdint.h>

// Problem constants (B=8,S=1024,D=256,N=4096)
#define TTOK 8192
#define DIM 256
#define NSLOT 4096
#define CAPC 65536
#define NBUCK 65536
#define SCALE 0.0625f     // 1/sqrt(256), exact
#define QBLK 64
#define SPLIT 4

typedef unsigned long long u64;
typedef unsigned short ushort_t;
typedef __attribute__((ext_vector_type(8))) __bf16 bf16x8;
typedef __attribute__((ext_vector_type(4))) float f32x4;

__device__ inline ushort_t f2bf(float f) {
    unsigned u = __float_as_uint(f);
    unsigned r = (u + 0x7fffu + ((u >> 16) & 1u)) >> 16;   // RNE
    return (ushort_t)r;
}
__device__ inline int bucketof(float w) {
    int b = (int)(w * 65536.0f);
    return b > 65535 ? 65535 : b;
}

// misc[0]=cand count, misc[1]=flagA, misc[2]=flagB, misc[3]=fast-path valid

// ---------------------------------------------------------------- zero/init
__global__ void k_zero(int* hist, int* cnt2, int* cnt, int* misc) {
    int i = blockIdx.x * 256 + threadIdx.x;   // grid 256 -> 65536
    hist[i] = 0; cnt2[i] = 0;
    if (i < NSLOT) cnt[i] = 0;
    if (i == 0) { misc[0] = 0; misc[1] = 1; misc[2] = 1; misc[3] = 0; }
}

// ---------------------------------------------------------------- all casts fused
// regions: x(2048 blk) Wk(64) Wv(64) Wq(64) keys0(1024); 4 elems/thread
__global__ void k_prep(const float* __restrict__ x, const float* __restrict__ Wk,
                       const float* __restrict__ Wv, const float* __restrict__ Wq,
                       const float* __restrict__ keys0,
                       ushort_t* __restrict__ x_bf, ushort_t* __restrict__ wk_bf,
                       ushort_t* __restrict__ wv_bf, ushort_t* __restrict__ wq_bf,
                       ushort_t* __restrict__ k0_bf)
{
    int b = blockIdx.x;
    const float* src; ushort_t* dst; int i;
    if (b < 2048)      { src = x;     dst = x_bf;  i = (b * 256 + threadIdx.x) * 4; }
    else if (b < 2112) { src = Wk;    dst = wk_bf; i = ((b - 2048) * 256 + threadIdx.x) * 4; }
    else if (b < 2176) { src = Wv;    dst = wv_bf; i = ((b - 2112) * 256 + threadIdx.x) * 4; }
    else if (b < 2240) { src = Wq;    dst = wq_bf; i = ((b - 2176) * 256 + threadIdx.x) * 4; }
    else               { src = keys0; dst = k0_bf; i = ((b - 2240) * 256 + threadIdx.x) * 4; }
    float4 v = *(const float4*)&src[i];
    ushort4 o;
    o.x = f2bf(v.x); o.y = f2bf(v.y); o.z = f2bf(v.z); o.w = f2bf(v.w);
    *(ushort4*)&dst[i] = o;
}

// ---------------------------------------------------------------- vb -> vbT (bf16)
__global__ __launch_bounds__(256) void k_transV(const float* __restrict__ vb, ushort_t* __restrict__ vbT) {
    __shared__ float ts[32][33];
    int tx = threadIdx.x & 31, ty = threadIdx.x >> 5;
    int s0 = blockIdx.x * 32, d0 = blockIdx.y * 32;
    #pragma unroll
    for (int j = 0; j < 4; j++)
        ts[ty + j*8][tx] = vb[(size_t)(s0 + ty + j*8) * DIM + d0 + tx];
    __syncthreads();
    #pragma unroll
    for (int j = 0; j < 4; j++)
        vbT[(size_t)(d0 + ty + j*8) * NSLOT + s0 + tx] = f2bf(ts[tx][ty + j*8]);
}

// =============================================================== GEMM core
// 128x128 tile, K = KSTEPS*64. 4 waves, wave w owns rows w*32..w*32+31 x ALL 128 cols.
// 2-step register prefetch + LDS double-buffer; ONE barrier per K-step.
// acc[m in 0..1][n in 0..7]: row = w*32 + m*16 + lg*4 + r, col = n*16 + lr.
template<int KSTEPS>
__device__ __forceinline__ void gemm_core(
    const ushort_t* __restrict__ A, const ushort_t* __restrict__ B,
    int lda, int ldb, int rA0, int rB0,
    ushort_t* sA, ushort_t* sB, f32x4 (&acc)[2][8])
{
    const int tid = threadIdx.x;
    const int lane = tid & 63;
    const int w = tid >> 6;
    const int lr = lane & 15, lg = lane >> 4;
    const int ex = (tid & 7) * 8;
    const int rsub = tid >> 3;   // 0..31

    uint4 rA[2][4], rB[2][4];    // parity-indexed only with unrolled (compile-time) s

    auto LOAD = [&](uint4 (&ra)[4], uint4 (&rb)[4], int s) {
        #pragma unroll
        for (int j = 0; j < 4; j++) {
            int row = j * 32 + rsub;
            ra[j] = *(const uint4*)&A[(size_t)(rA0 + row) * lda + s * 64 + ex];
            rb[j] = *(const uint4*)&B[(size_t)(rB0 + row) * ldb + s * 64 + ex];
        }
    };
    auto STAGE = [&](int buf, uint4 (&ra)[4], uint4 (&rb)[4]) {
        #pragma unroll
        for (int j = 0; j < 4; j++) {
            int row = j * 32 + rsub;
            int xi = ex ^ ((row & 7) << 3);
            *(uint4*)&sA[buf * 8192 + row * 64 + xi] = ra[j];
            *(uint4*)&sB[buf * 8192 + row * 64 + xi] = rb[j];
        }
    };

    LOAD(rA[0], rB[0], 0);
    LOAD(rA[1], rB[1], 1);
    STAGE(0, rA[0], rB[0]);
    __syncthreads();
    #pragma unroll
    for (int s = 0; s < KSTEPS; ++s) {
        if (s + 1 < KSTEPS) STAGE((s + 1) & 1, rA[(s + 1) & 1], rB[(s + 1) & 1]);
        if (s + 2 < KSTEPS) LOAD(rA[s & 1], rB[s & 1], s + 2);
        const ushort_t* cA = sA + (s & 1) * 8192;
        const ushort_t* cB = sB + (s & 1) * 8192;
        #pragma unroll
        for (int h = 0; h < 2; h++) {
            int xs = h * 32 + lg * 8;
            bf16x8 aF[2], bF[8];
            #pragma unroll
            for (int m = 0; m < 2; m++)
                aF[m] = *(const bf16x8*)&cA[(w * 32 + m * 16 + lr) * 64 + (xs ^ ((lr & 7) << 3))];
            #pragma unroll
            for (int n = 0; n < 8; n++)
                bF[n] = *(const bf16x8*)&cB[(n * 16 + lr) * 64 + (xs ^ ((lr & 7) << 3))];
            #pragma unroll
            for (int m = 0; m < 2; m++)
                #pragma unroll
                for (int n = 0; n < 8; n++)
                    acc[m][n] = __builtin_amdgcn_mfma_f32_16x16x32_bf16(aF[m], bF[n], acc[m][n], 0, 0, 0);
        }
        __syncthreads();
    }
}

// ---------------- 3 projections in one dispatch: grid (64, 2, 3)
__global__ __launch_bounds__(256) void k_proj3(
    const ushort_t* __restrict__ x_bf,
    const ushort_t* __restrict__ wk_bf, const ushort_t* __restrict__ wv_bf,
    const ushort_t* __restrict__ wq_bf,
    const float* __restrict__ bk, const float* __restrict__ bv, const float* __restrict__ bq,
    float* __restrict__ ka, ushort_t* __restrict__ ka_bf,
    float* __restrict__ va, ushort_t* __restrict__ qa_bf)
{
    __shared__ ushort_t sA[2 * 8192];
    __shared__ ushort_t sB[2 * 8192];
    const ushort_t* B; const float* bias; float* oF; ushort_t* oB;
    int z = blockIdx.z;
    if (z == 0)      { B = wk_bf; bias = bk; oF = ka;      oB = ka_bf;   }
    else if (z == 1) { B = wv_bf; bias = bv; oF = va;      oB = nullptr; }
    else             { B = wq_bf; bias = bq; oF = nullptr; oB = qa_bf;  }
    int rA0 = blockIdx.x * 128, rB0 = blockIdx.y * 128;
    f32x4 acc[2][8] = {};
    gemm_core<4>(x_bf, B, DIM, DIM, rA0, rB0, sA, sB, acc);

    const int tid = threadIdx.x, lane = tid & 63, w = tid >> 6;
    const int lr = lane & 15, lg = lane >> 4;
    #pragma unroll
    for (int n = 0; n < 8; n++) {
        int gcol = rB0 + n * 16 + lr;
        float bj = bias[gcol];
        #pragma unroll
        for (int m = 0; m < 2; m++)
            #pragma unroll
            for (int r = 0; r < 4; r++) {
                int grow = rA0 + w * 32 + m * 16 + lg * 4 + r;
                float v = acc[m][n][r] + bj;
                if (oF) oF[(size_t)grow * DIM + gcol] = v;
                if (oB) oB[(size_t)grow * DIM + gcol] = f2bf(v);
            }
    }
}

// ---------------- simmax: grid 2048 1-D, XCD-swizzled; per-wave argmax epilogue
__global__ __launch_bounds__(256) void k_sim(
    const ushort_t* __restrict__ ka_bf, const ushort_t* __restrict__ k0_bf,
    float* __restrict__ partV, int* __restrict__ partI)
{
    __shared__ ushort_t sA[2 * 8192];
    __shared__ ushort_t sB[2 * 8192];
    int lin = blockIdx.x;
    int xcd = lin & 7, pos = lin >> 3;
    int bx = pos >> 2, by = (xcd << 2) | (pos & 3);
    int rA0 = bx * 128, rB0 = by * 128;
    f32x4 acc[2][8] = {};
    gemm_core<4>(ka_bf, k0_bf, DIM, DIM, rA0, rB0, sA, sB, acc);

    const int tid = threadIdx.x, lane = tid & 63, w = tid >> 6;
    const int lr = lane & 15, lg = lane >> 4;
    #pragma unroll
    for (int m = 0; m < 2; m++)
        #pragma unroll
        for (int r = 0; r < 4; r++) {
            float bvv = acc[m][0][r]; int bi = rB0 + lr;
            #pragma unroll
            for (int n = 1; n < 8; n++) {
                float v = acc[m][n][r]; int c = rB0 + n * 16 + lr;
                if (v > bvv) { bvv = v; bi = c; }
            }
            #pragma unroll
            for (int off = 1; off < 16; off <<= 1) {   // reduce within lr group
                float ov = __shfl_xor(bvv, off);
                int oi = __shfl_xor(bi, off);
                if (ov > bvv || (ov == bvv && oi < bi)) { bvv = ov; bi = oi; }
            }
            if (lr == 0) {
                int row = rA0 + w * 32 + m * 16 + lg * 4 + r;
                partV[(size_t)by * TTOK + row] = bvv;
                partI[(size_t)by * TTOK + row] = bi;
            }
        }
}

// ---------------------------------------------------------------- bestmerge + flags
__global__ void k_bmflags(const float* __restrict__ partV, const int* __restrict__ partI,
                          const unsigned char* __restrict__ maskraw, const float* __restrict__ act0,
                          int* best, int* novel, int* misc) {
    int t = blockIdx.x * 256 + threadIdx.x;   // grid 32
    int u8 = (maskraw[1] == 1);
    if (t < TTOK) {
        float bv = partV[t]; int bi = partI[t];
        #pragma unroll
        for (int q = 1; q < 32; q++) {
            float v = partV[(size_t)q * TTOK + t];
            int i = partI[(size_t)q * TTOK + t];
            if (v > bv || (v == bv && i < bi)) { bv = v; bi = i; }
        }
        best[t] = bi;
        int nv = (bv * SCALE < 0.5f) ? 1 : 0;
        novel[t] = nv;
        int mv = u8 ? (int)maskraw[t] : ((const int*)maskraw)[t];
        if (!nv || mv == 0) atomicAnd(&misc[1], 0);
    }
    if (t < NSLOT) {
        float a = act0[t];
        if (!(a >= 0.0f)) atomicAnd(&misc[1], 0);
    }
}

// ------------------------------------------------- ladder candidate generation
__global__ void k_ladder(const float* act0, u64* cand, int* candJ, int* misc) {
    if (misc[1] == 0) return;
    int i = blockIdx.x * 256 + threadIdx.x;
    if (i >= NSLOT) return;
    float w = act0[i];
    int j = 0;
    while (w < 1.0f) {
        if (j >= 48) { atomicAnd(&misc[2], 0); break; }
        int pos = atomicAdd(&misc[0], 1);
        if (pos >= CAPC) { atomicAnd(&misc[2], 0); break; }
        cand[pos] = ((u64)__float_as_uint(w) << 32) | (unsigned)i;
        candJ[pos] = j;
        j++;
        w = fminf(1.0f, w + 0.1f);
    }
}

// ------------------------------------------------- histogram (+ finalize fold)
__global__ void k_hist(const u64* cand, int* misc, int* hist) {
    if (blockIdx.x == 0 && threadIdx.x == 0)
        misc[3] = (misc[1] && misc[2] && misc[0] >= TTOK) ? 1 : 0;
    if (!(misc[1] && misc[2])) return;
    int K = misc[0]; if (K > CAPC) K = CAPC;
    int i = blockIdx.x * 256 + threadIdx.x;
    if (i >= K) return;
    float w = __uint_as_float((unsigned)(cand[i] >> 32));
    atomicAdd(&hist[bucketof(w)], 1);
}

__global__ __launch_bounds__(1024) void k_scanhist(const int* __restrict__ hist, int* __restrict__ offsB) {
    __shared__ int part[1024];
    int tid = threadIdx.x;
    int base = tid * 64;
    int s = 0;
    for (int i = 0; i < 64; i++) s += hist[base + i];
    part[tid] = s;
    __syncthreads();
    for (int off = 1; off < 1024; off <<= 1) {
        int v = (tid >= off) ? part[tid - off] : 0;
        __syncthreads();
        part[tid] += v;
        __syncthreads();
    }
    int pre = (tid == 0) ? 0 : part[tid - 1];
    for (int i = 0; i < 64; i++) { offsB[base + i] = pre; pre += hist[base + i]; }
}

__global__ void k_place(const u64* cand, const int* candJ, const int* misc,
                        const int* offsB, int* cnt2, u64* skey, int* sj) {
    if (!(misc[1] && misc[2])) return;
    int K = misc[0]; if (K > CAPC) K = CAPC;
    int i = blockIdx.x * 256 + threadIdx.x;
    if (i >= K) return;
    u64 key = cand[i];
    float w = __uint_as_float((unsigned)(key >> 32));
    int b = bucketof(w);
    int pos = offsB[b] + atomicAdd(&cnt2[b], 1);
    skey[pos] = key; sj[pos] = candJ[i];
}

__global__ void k_rank2(const u64* __restrict__ skey, const int* __restrict__ sj, const int* misc,
                        const int* __restrict__ offsB, const int* __restrict__ hist,
                        int* slot_seq, int* rankis, int* cnt) {
    if (!(misc[1] && misc[2])) return;
    int K = misc[0]; if (K > CAPC) K = CAPC;
    int i = blockIdx.x * 256 + threadIdx.x;
    if (i >= K) return;
    u64 my = skey[i];
    float w = __uint_as_float((unsigned)(my >> 32));
    int b = bucketof(w);
    int base = offsB[b], n = hist[b];
    int r = base;
    for (int q = 0; q < n; q++) r += (skey[base + q] < my) ? 1 : 0;
    if (r < TTOK) {
        int slot = (int)(my & 0xffffffffu);
        slot_seq[r] = slot;
        rankis[r] = sj[i];
        atomicAdd(&cnt[slot], 1);
    }
}

// ------------------------------------------------- act final + log(act) (fast path)
__global__ void k_actfinal(const float* act0, const int* cnt, float* act_f, float* la, const int* misc) {
    if (!misc[3]) return;
    int i = blockIdx.x * 256 + threadIdx.x;
    if (i >= NSLOT) return;
    float a = act0[i];
    int m = cnt[i];
    for (int r = 0; r < m; r++) a = fminf(1.0f, a + 0.1f);
    act_f[i] = a;
    la[i] = (a < 0.01f) ? -INFINITY : logf(fmaxf(a, 1e-8f));
}

// ------------------------------------------------- serial fallback (cold path)
__global__ __launch_bounds__(64) void k_serial(
    const int* novel, const int* best, const unsigned char* maskraw,
    const float* act0, const int* misc,
    int* slot_seq, int* rankis, int* cnt, float* act_f, float* la)
{
    if (misc[3]) return;
    __shared__ float act[NSLOT];
    __shared__ int cntL[NSLOT];
    const int lane = threadIdx.x;
    const int u8 = (maskraw[1] == 1);
    for (int i = lane; i < NSLOT; i += 64) { act[i] = act0[i]; cntL[i] = 0; }
    __syncthreads();
    float cv; int ci;
    {
        cv = act[lane * 64]; ci = lane * 64;
        for (int u = 1; u < 64; u++) {
            float v = act[lane * 64 + u];
            if (v < cv) { cv = v; ci = lane * 64 + u; }
        }
    }
    for (int t = 0; t < TTOK; t++) {
        int nv = novel[t];
        int mk = (u8 ? (int)maskraw[t] : ((const int*)maskraw)[t]) != 0;
        int slot;
        if (nv) {
            float v = cv; int ix = ci;
            for (int off = 32; off >= 1; off >>= 1) {
                float ov = __shfl_xor(v, off);
                int oi = __shfl_xor(ix, off);
                if (ov < v || (ov == v && oi < ix)) { v = ov; ix = oi; }
            }
            slot = ix;
        } else {
            slot = best[t];
        }
        if (mk) {
            float a = act[slot];
            float a2 = fminf(1.0f, a + 0.1f);
            __syncthreads();
            if (lane == 0) {
                act[slot] = a2;
                slot_seq[t] = slot;
                int r = cntL[slot]; rankis[t] = r; cntL[slot] = r + 1;
            }
            __syncthreads();
            int c = slot >> 6;
            float v = act[c * 64 + lane]; int ix = c * 64 + lane;
            for (int off = 32; off >= 1; off >>= 1) {
                float ov = __shfl_xor(v, off);
                int oi = __shfl_xor(ix, off);
                if (ov < v || (ov == v && oi < ix)) { v = ov; ix = oi; }
            }
            if (lane == c) { cv = v; ci = ix; }
        } else {
            if (lane == 0) rankis[t] = -1;
        }
        __syncthreads();
    }
    for (int i = lane; i < NSLOT; i += 64) {
        cnt[i] = cntL[i];
        float a = act[i];
        act_f[i] = a;
        la[i] = (a < 0.01f) ? -INFINITY : logf(fmaxf(a, 1e-8f));
    }
}

// ------------------------------------------------- offsets + scatter (one block)
__global__ __launch_bounds__(256) void k_offscatter(const int* cnt, int* offs,
                                                    const int* slot_seq, const int* rankis,
                                                    int* listTok) {
    __shared__ int soffs[NSLOT];
    __shared__ int part[256];
    int tid = threadIdx.x;
    int base = tid * 16;
    int loc[16];
    int s = 0;
    #pragma unroll
    for (int i = 0; i < 16; i++) { loc[i] = s; s += cnt[base + i]; }
    part[tid] = s;
    __syncthreads();
    for (int off = 1; off < 256; off <<= 1) {
        int v = (tid >= off) ? part[tid - off] : 0;
        __syncthreads();
        part[tid] += v;
        __syncthreads();
    }
    int pre = (tid == 0) ? 0 : part[tid - 1];
    #pragma unroll
    for (int i = 0; i < 16; i++) { soffs[base + i] = pre + loc[i]; offs[base + i] = pre + loc[i]; }
    __syncthreads();
    for (int t = tid; t < TTOK; t += 256) {
        int r = rankis[t];
        if (r >= 0) listTok[soffs[slot_seq[t]] + r] = t;
    }
}

// ------------------------------------------------- apply buffer writes per slot
__global__ __launch_bounds__(256) void k_apply(
    const float* __restrict__ keys0, const float* __restrict__ values0,
    const float* __restrict__ ka, const float* __restrict__ va,
    const int* __restrict__ novel, const int* __restrict__ cnt,
    const int* __restrict__ offs, const int* __restrict__ listTok,
    ushort_t* __restrict__ kb_bf, float* __restrict__ vb)
{
    int s = blockIdx.x;
    int d = threadIdx.x;
    float kv = keys0[(size_t)s * DIM + d];
    float vv = values0[(size_t)s * DIM + d];
    int m = cnt[s], off = offs[s];
    for (int r = 0; r < m; r++) {
        int t = listTok[off + r];
        float al = novel[t] ? 0.9f : 0.3f;
        kv = (1.0f - al) * kv + al * ka[(size_t)t * DIM + d];
        vv = (1.0f - al) * vv + al * va[(size_t)t * DIM + d];
    }
    kb_bf[(size_t)s * DIM + d] = f2bf(kv);
    vb[(size_t)s * DIM + d] = vv;
}

// ================================================= fused flash attention (no-max)
__global__ __launch_bounds__(256, 2) void k_flash(
    const ushort_t* __restrict__ qa_bf,   // [8192][256]
    const ushort_t* __restrict__ kb_bf,   // [4096][256]
    const ushort_t* __restrict__ vbT,     // [256][4096]
    const float* __restrict__ la,         // [4096]
    float* __restrict__ opart,            // [SPLIT][8192][256] unnormalized
    float* __restrict__ lpart)            // [SPLIT][8192]
{
    __shared__ ushort_t sK[4 * 64 * 64];   // 32KB swizzled
    __shared__ ushort_t sV[256 * 64];      // 32KB swizzled
    __shared__ ushort_t sP[4][16 * 64];    // 8KB per-wave private P tiles

    const int tid = threadIdx.x;
    const int w = tid >> 6;
    const int lane = tid & 63;
    const int lr = lane & 15, lg = lane >> 4;
    const int qw = blockIdx.x * QBLK + w * 16;
    const int z = blockIdx.y;
    const int sbase = z * (NSLOT / SPLIT);

    bf16x8 qreg[4][2];
    #pragma unroll
    for (int kc = 0; kc < 4; kc++)
        #pragma unroll
        for (int h = 0; h < 2; h++)
            qreg[kc][h] = *(const bf16x8*)&qa_bf[(size_t)(qw + lr) * DIM + kc*64 + h*32 + lg*8];

    f32x4 o_acc[16] = {};
    float lsum[4] = {0.f, 0.f, 0.f, 0.f};

    const int krow = tid >> 2, kseg = tid & 3;
    const int vrow = tid >> 3, vseg = tid & 7;

    for (int it = 0; it < NSLOT / SPLIT / 64; ++it) {
        int s0 = sbase + it * 64;
        __syncthreads();
        #pragma unroll
        for (int p = 0; p < 8; p++) {
            int g = p * 4 + kseg;
            uint4 v = *(const uint4*)&kb_bf[(size_t)(s0 + krow) * DIM + g * 8];
            int kc = g >> 3, c64 = (g & 7) * 8;
            *(uint4*)&sK[kc * 4096 + krow * 64 + (c64 ^ ((krow & 7) << 3))] = v;
        }
        #pragma unroll
        for (int p = 0; p < 8; p++) {
            int d = vrow + p * 32;
            uint4 v = *(const uint4*)&vbT[(size_t)d * NSLOT + s0 + vseg * 8];
            *(uint4*)&sV[d * 64 + ((vseg * 8) ^ ((d & 7) << 3))] = v;
        }
        __syncthreads();

        float la_r[4];
        #pragma unroll
        for (int n = 0; n < 4; n++) la_r[n] = la[s0 + n * 16 + lr];

        f32x4 accs[4] = {};
        #pragma unroll
        for (int n = 0; n < 4; n++) {
            int srow = n * 16 + lr;
            int sw = (srow & 7) << 3;
            #pragma unroll
            for (int kc = 0; kc < 4; kc++)
                #pragma unroll
                for (int h = 0; h < 2; h++) {
                    bf16x8 bF = *(const bf16x8*)&sK[kc * 4096 + srow * 64 + ((h * 32 + lg * 8) ^ sw)];
                    accs[n] = __builtin_amdgcn_mfma_f32_16x16x32_bf16(qreg[kc][h], bF, accs[n], 0, 0, 0);
                }
        }

        #pragma unroll
        for (int n = 0; n < 4; n++)
            #pragma unroll
            for (int r = 0; r < 4; r++) {
                int row = lg * 4 + r;
                float p = __expf(accs[n][r] * SCALE + la_r[n]);
                sP[w][row * 64 + ((n * 16 + lr) ^ ((row & 7) << 3))] = f2bf(p);
                lsum[r] += p;
            }

        #pragma unroll
        for (int h = 0; h < 2; h++) {
            bf16x8 aP = *(const bf16x8*)&sP[w][lr * 64 + ((h * 32 + lg * 8) ^ ((lr & 7) << 3))];
            #pragma unroll
            for (int nd = 0; nd < 16; nd++) {
                int d = nd * 16 + lr;
                bf16x8 bV = *(const bf16x8*)&sV[d * 64 + ((h * 32 + lg * 8) ^ ((d & 7) << 3))];
                o_acc[nd] = __builtin_amdgcn_mfma_f32_16x16x32_bf16(aP, bV, o_acc[nd], 0, 0, 0);
            }
        }
    }

    #pragma unroll
    for (int r = 0; r < 4; r++) {
        #pragma unroll
        for (int off = 1; off < 16; off <<= 1) lsum[r] += __shfl_xor(lsum[r], off);
        if (lr == 0) lpart[(size_t)z * TTOK + qw + lg * 4 + r] = lsum[r];
    }
    #pragma unroll
    for (int nd = 0; nd < 16; nd++)
        #pragma unroll
        for (int r = 0; r < 4; r++)
            opart[((size_t)z * TTOK + qw + lg * 4 + r) * DIM + nd * 16 + lr] = o_acc[nd][r];
}

// ------------------------------------------------- combine split partials
__global__ void k_comb(const float* __restrict__ opart, const float* __restrict__ lpart,
                       float* __restrict__ out) {
    int idx = blockIdx.x * 256 + threadIdx.x;
    int t = idx >> 8;
    float den = lpart[t] + lpart[TTOK + t] + lpart[2 * TTOK + t] + lpart[3 * TTOK + t];
    float num = opart[idx] + opart[(size_t)TTOK * DIM + idx]
              + opart[2 * (size_t)TTOK * DIM + idx] + opart[3 * (size_t)TTOK * DIM + idx];
    out[idx] = num / den;
}

// ================================================================ launch
extern "C" void kernel_launch(void* const* d_in, const int* in_sizes, int n_in,
                              void* d_out, int out_size, void* d_ws, size_t ws_size,
                              hipStream_t stream)
{
    (void)in_sizes; (void)n_in; (void)out_size; (void)ws_size;
    const float* x       = (const float*)d_in[0];
    const unsigned char* mask = (const unsigned char*)d_in[1];
    const float* keys0   = (const float*)d_in[2];
    const float* values0 = (const float*)d_in[3];
    const float* act0    = (const float*)d_in[4];
    const float* Wk = (const float*)d_in[5];
    const float* bk = (const float*)d_in[6];
    const float* Wv = (const float*)d_in[7];
    const float* bv = (const float*)d_in[8];
    const float* Wq = (const float*)d_in[9];
    const float* bq = (const float*)d_in[10];
    float* out = (float*)d_out;

    uint8_t* w = (uint8_t*)d_ws;
    size_t off = 0;
    auto alloc = [&](size_t bytes) -> void* {
        void* p = w + off;
        off = (off + bytes + 255) & ~(size_t)255;
        return p;
    };
    float*    ka     = (float*)   alloc((size_t)TTOK * DIM * 4);
    float*    va_    = (float*)   alloc((size_t)TTOK * DIM * 4);
    float*    vb     = (float*)   alloc((size_t)NSLOT * DIM * 4);
    ushort_t* x_bf   = (ushort_t*)alloc((size_t)TTOK * DIM * 2);
    ushort_t* wk_bf  = (ushort_t*)alloc((size_t)DIM * DIM * 2);
    ushort_t* wv_bf  = (ushort_t*)alloc((size_t)DIM * DIM * 2);
    ushort_t* wq_bf  = (ushort_t*)alloc((size_t)DIM * DIM * 2);
    ushort_t* ka_bf  = (ushort_t*)alloc((size_t)TTOK * DIM * 2);
    ushort_t* qa_bf  = (ushort_t*)alloc((size_t)TTOK * DIM * 2);
    ushort_t* k0_bf  = (ushort_t*)alloc((size_t)NSLOT * DIM * 2);
    ushort_t* kb_bf  = (ushort_t*)alloc((size_t)NSLOT * DIM * 2);
    ushort_t* vbT    = (ushort_t*)alloc((size_t)DIM * NSLOT * 2);
    float*    opart  = (float*)   alloc((size_t)SPLIT * TTOK * DIM * 4);
    float*    lpart  = (float*)   alloc((size_t)SPLIT * TTOK * 4);
    float*    partV  = (float*)   alloc((size_t)32 * TTOK * 4);
    int*      partI  = (int*)     alloc((size_t)32 * TTOK * 4);
    float*    act_f  = (float*)   alloc((size_t)NSLOT * 4);
    float*    la     = (float*)   alloc((size_t)NSLOT * 4);
    int*      best   = (int*)     alloc((size_t)TTOK * 4);
    int*      novel  = (int*)     alloc((size_t)TTOK * 4);
    int*      slot_seq = (int*)   alloc((size_t)TTOK * 4);
    int*      rankis = (int*)     alloc((size_t)TTOK * 4);
    int*      cnt    = (int*)     alloc((size_t)NSLOT * 4);
    int*      offs   = (int*)     alloc((size_t)NSLOT * 4);
    int*      listTok= (int*)     alloc((size_t)TTOK * 4);
    u64*      cand   = (u64*)     alloc((size_t)CAPC * 8);
    int*      candJ  = (int*)     alloc((size_t)CAPC * 4);
    u64*      skey   = (u64*)     alloc((size_t)CAPC * 8);
    int*      sj     = (int*)     alloc((size_t)CAPC * 4);
    int*      hist   = (int*)     alloc((size_t)NBUCK * 4);
    int*      cnt2   = (int*)     alloc((size_t)NBUCK * 4);
    int*      offsB  = (int*)     alloc((size_t)NBUCK * 4);
    int*      misc   = (int*)     alloc(64);

    k_zero<<<NBUCK/256, 256, 0, stream>>>(hist, cnt2, cnt, misc);
    k_prep<<<3264, 256, 0, stream>>>(x, Wk, Wv, Wq, keys0, x_bf, wk_bf, wv_bf, wq_bf, k0_bf);
    k_proj3<<<dim3(TTOK/128, 2, 3), 256, 0, stream>>>(
        x_bf, wk_bf, wv_bf, wq_bf, bk, bv, bq, ka, ka_bf, va_, qa_bf);
    k_sim<<<2048, 256, 0, stream>>>(ka_bf, k0_bf, partV, partI);
    k_bmflags<<<32, 256, 0, stream>>>(partV, partI, mask, act0, best, novel, misc);
    k_ladder<<<NSLOT/256, 256, 0, stream>>>(act0, cand, candJ, misc);
    k_hist<<<CAPC/256, 256, 0, stream>>>(cand, misc, hist);
    k_scanhist<<<1, 1024, 0, stream>>>(hist, offsB);
    k_place<<<CAPC/256, 256, 0, stream>>>(cand, candJ, misc, offsB, cnt2, skey, sj);
    k_rank2<<<CAPC/256, 256, 0, stream>>>(skey, sj, misc, offsB, hist, slot_seq, rankis, cnt);
    k_actfinal<<<NSLOT/256, 256, 0, stream>>>(act0, cnt, act_f, la, misc);
    k_serial<<<1, 64, 0, stream>>>(novel, best, mask, act0, misc, slot_seq, rankis, cnt, act_f, la);
    k_offscatter<<<1, 256, 0, stream>>>(cnt, offs, slot_seq, rankis, listTok);
    k_apply<<<NSLOT, 256, 0, stream>>>(keys0, values0, ka, va_, novel, cnt, offs, listTok, kb_bf, vb);
    k_transV<<<dim3(NSLOT/32, DIM/32), 256, 0, stream>>>(vb, vbT);
    k_flash<<<dim3(TTOK/QBLK, SPLIT), 256, 0, stream>>>(qa_bf, kb_bf, vbT, la, opart, lpart);
    k_comb<<<TTOK*DIM/256, 256, 0, stream>>>(opart, lpart, out);
}

// Round 8
// 300.625 us; speedup vs baseline: 4.6204x; 1.2226x over previous
//
#include <hip/hip_runtime.h>
#include <hip/hip_bf16.h>
#include <math.h>
#include <stdint.h>

// Problem constants (B=8,S=1024,D=256,N=4096)
#define TTOK 8192
#define DIM 256
#define NSLOT 4096
#define CAPC 65536
#define NBUCK 65536
#define SCALE 0.0625f     // 1/sqrt(256), exact
#define QBLK 64
#define SPLIT 4

typedef unsigned long long u64;
typedef unsigned short ushort_t;
typedef __attribute__((ext_vector_type(8))) __bf16 bf16x8;
typedef __attribute__((ext_vector_type(4))) float f32x4;

__device__ inline ushort_t f2bf(float f) {
    unsigned u = __float_as_uint(f);
    unsigned r = (u + 0x7fffu + ((u >> 16) & 1u)) >> 16;   // RNE
    return (ushort_t)r;
}
__device__ inline int bucketof(float w) {
    int b = (int)(w * 65536.0f);
    return b > 65535 ? 65535 : b;
}

// misc[0]=cand count, misc[1]=flagA, misc[2]=flagB, misc[3]=fast-path valid

// ---------------------------------------------------------------- zero/init
__global__ void k_zero(int* hist, int* cnt2, int* cnt, int* misc) {
    int i = blockIdx.x * 256 + threadIdx.x;   // grid 256 -> 65536
    hist[i] = 0; cnt2[i] = 0;
    if (i < NSLOT) cnt[i] = 0;
    if (i == 0) { misc[0] = 0; misc[1] = 1; misc[2] = 1; misc[3] = 0; }
}

// ---------------------------------------------------------------- all casts fused
__global__ void k_prep(const float* __restrict__ x, const float* __restrict__ Wk,
                       const float* __restrict__ Wv, const float* __restrict__ Wq,
                       const float* __restrict__ keys0,
                       ushort_t* __restrict__ x_bf, ushort_t* __restrict__ wk_bf,
                       ushort_t* __restrict__ wv_bf, ushort_t* __restrict__ wq_bf,
                       ushort_t* __restrict__ k0_bf)
{
    int b = blockIdx.x;
    const float* src; ushort_t* dst; int i;
    if (b < 2048)      { src = x;     dst = x_bf;  i = (b * 256 + threadIdx.x) * 4; }
    else if (b < 2112) { src = Wk;    dst = wk_bf; i = ((b - 2048) * 256 + threadIdx.x) * 4; }
    else if (b < 2176) { src = Wv;    dst = wv_bf; i = ((b - 2112) * 256 + threadIdx.x) * 4; }
    else if (b < 2240) { src = Wq;    dst = wq_bf; i = ((b - 2176) * 256 + threadIdx.x) * 4; }
    else               { src = keys0; dst = k0_bf; i = ((b - 2240) * 256 + threadIdx.x) * 4; }
    float4 v = *(const float4*)&src[i];
    ushort4 o;
    o.x = f2bf(v.x); o.y = f2bf(v.y); o.z = f2bf(v.z); o.w = f2bf(v.w);
    *(ushort4*)&dst[i] = o;
}

// ---------------------------------------------------------------- vb -> vbT (bf16)
__global__ __launch_bounds__(256) void k_transV(const float* __restrict__ vb, ushort_t* __restrict__ vbT) {
    __shared__ float ts[32][33];
    int tx = threadIdx.x & 31, ty = threadIdx.x >> 5;
    int s0 = blockIdx.x * 32, d0 = blockIdx.y * 32;
    #pragma unroll
    for (int j = 0; j < 4; j++)
        ts[ty + j*8][tx] = vb[(size_t)(s0 + ty + j*8) * DIM + d0 + tx];
    __syncthreads();
    #pragma unroll
    for (int j = 0; j < 4; j++)
        vbT[(size_t)(d0 + ty + j*8) * NSLOT + s0 + tx] = f2bf(ts[tx][ty + j*8]);
}

// =============================================================== GEMM core
// 128x128 tile, K = KSTEPS*64. Wave w owns rows w*32..w*32+31 x ALL 128 cols.
// NAMED-SCALAR registers (no arrays/lambdas -> no scratch spill, rule #20).
// Single-depth prefetch + LDS double-buffer; ONE barrier per K-step.
template<int KSTEPS>
__device__ __forceinline__ void gemm_core(
    const ushort_t* __restrict__ A, const ushort_t* __restrict__ B,
    int lda, int ldb, int rA0, int rB0,
    ushort_t* sA, ushort_t* sB, f32x4 (&acc)[2][8])
{
    const int tid = threadIdx.x;
    const int lane = tid & 63;
    const int w = tid >> 6;
    const int lr = lane & 15, lg = lane >> 4;
    const int ex = (tid & 7) * 8;
    const int rsub = tid >> 3;   // 0..31  (rows rsub, rsub+32, +64, +96)
    const int xi = ex ^ ((rsub & 7) << 3);
    const ushort_t* pA = A + (size_t)(rA0 + rsub) * lda + ex;
    const ushort_t* pB = B + (size_t)(rB0 + rsub) * ldb + ex;
    const size_t strA = (size_t)32 * lda;
    const size_t strB = (size_t)32 * ldb;

    uint4 a0, a1, a2, a3, b0, b1, b2, b3;

#define LOADSET(s) do { \
    a0 = *(const uint4*)(pA + (s) * 64);             b0 = *(const uint4*)(pB + (s) * 64); \
    a1 = *(const uint4*)(pA + strA + (s) * 64);      b1 = *(const uint4*)(pB + strB + (s) * 64); \
    a2 = *(const uint4*)(pA + 2 * strA + (s) * 64);  b2 = *(const uint4*)(pB + 2 * strB + (s) * 64); \
    a3 = *(const uint4*)(pA + 3 * strA + (s) * 64);  b3 = *(const uint4*)(pB + 3 * strB + (s) * 64); } while (0)

#define STAGESET(buf) do { \
    ushort_t* dA = sA + (buf) * 8192 + rsub * 64 + xi; \
    ushort_t* dB = sB + (buf) * 8192 + rsub * 64 + xi; \
    *(uint4*)(dA)            = a0;  *(uint4*)(dB)            = b0; \
    *(uint4*)(dA + 32 * 64)  = a1;  *(uint4*)(dB + 32 * 64)  = b1; \
    *(uint4*)(dA + 64 * 64)  = a2;  *(uint4*)(dB + 64 * 64)  = b2; \
    *(uint4*)(dA + 96 * 64)  = a3;  *(uint4*)(dB + 96 * 64)  = b3; } while (0)

    LOADSET(0);
    STAGESET(0);
    #pragma unroll
    for (int s = 0; s < KSTEPS; ++s) {
        if (s + 1 < KSTEPS) LOADSET(s + 1);       // issue next-step loads early
        __syncthreads();                           // buf[s&1] staged by all waves
        const ushort_t* cA = sA + (s & 1) * 8192;
        const ushort_t* cB = sB + (s & 1) * 8192;
        #pragma unroll
        for (int h = 0; h < 2; h++) {
            int xs0 = (h * 32 + lg * 8) ^ ((lr & 7) << 3);
            bf16x8 aF0 = *(const bf16x8*)&cA[(w * 32 + lr) * 64 + xs0];
            bf16x8 aF1 = *(const bf16x8*)&cA[(w * 32 + 16 + lr) * 64 + xs0];
            #pragma unroll
            for (int n = 0; n < 8; n++) {
                bf16x8 bF = *(const bf16x8*)&cB[(n * 16 + lr) * 64 + xs0];
                acc[0][n] = __builtin_amdgcn_mfma_f32_16x16x32_bf16(aF0, bF, acc[0][n], 0, 0, 0);
                acc[1][n] = __builtin_amdgcn_mfma_f32_16x16x32_bf16(aF1, bF, acc[1][n], 0, 0, 0);
            }
        }
        if (s + 1 < KSTEPS) STAGESET((s + 1) & 1); // other buffer: no race with readers of buf[s&1]
    }
#undef LOADSET
#undef STAGESET
}

// ---------------- 3 projections in one dispatch: grid (64, 2, 3)
__global__ __launch_bounds__(256) void k_proj3(
    const ushort_t* __restrict__ x_bf,
    const ushort_t* __restrict__ wk_bf, const ushort_t* __restrict__ wv_bf,
    const ushort_t* __restrict__ wq_bf,
    const float* __restrict__ bk, const float* __restrict__ bv, const float* __restrict__ bq,
    float* __restrict__ ka, ushort_t* __restrict__ ka_bf,
    float* __restrict__ va, ushort_t* __restrict__ qa_bf)
{
    __shared__ ushort_t sA[2 * 8192];
    __shared__ ushort_t sB[2 * 8192];
    const ushort_t* B; const float* bias; float* oF; ushort_t* oB;
    int z = blockIdx.z;
    if (z == 0)      { B = wk_bf; bias = bk; oF = ka;      oB = ka_bf;   }
    else if (z == 1) { B = wv_bf; bias = bv; oF = va;      oB = nullptr; }
    else             { B = wq_bf; bias = bq; oF = nullptr; oB = qa_bf;  }
    int rA0 = blockIdx.x * 128, rB0 = blockIdx.y * 128;
    f32x4 acc[2][8] = {};
    gemm_core<4>(x_bf, B, DIM, DIM, rA0, rB0, sA, sB, acc);

    const int tid = threadIdx.x, lane = tid & 63, w = tid >> 6;
    const int lr = lane & 15, lg = lane >> 4;
    #pragma unroll
    for (int n = 0; n < 8; n++) {
        int gcol = rB0 + n * 16 + lr;
        float bj = bias[gcol];
        #pragma unroll
        for (int m = 0; m < 2; m++)
            #pragma unroll
            for (int r = 0; r < 4; r++) {
                int grow = rA0 + w * 32 + m * 16 + lg * 4 + r;
                float v = acc[m][n][r] + bj;
                if (oF) oF[(size_t)grow * DIM + gcol] = v;
                if (oB) oB[(size_t)grow * DIM + gcol] = f2bf(v);
            }
    }
}

// ---------------- simmax: grid 2048 1-D, XCD-swizzled; per-wave argmax epilogue
__global__ __launch_bounds__(256) void k_sim(
    const ushort_t* __restrict__ ka_bf, const ushort_t* __restrict__ k0_bf,
    float* __restrict__ partV, int* __restrict__ partI)
{
    __shared__ ushort_t sA[2 * 8192];
    __shared__ ushort_t sB[2 * 8192];
    int lin = blockIdx.x;
    int xcd = lin & 7, pos = lin >> 3;
    int bx = pos >> 2, by = (xcd << 2) | (pos & 3);
    int rA0 = bx * 128, rB0 = by * 128;
    f32x4 acc[2][8] = {};
    gemm_core<4>(ka_bf, k0_bf, DIM, DIM, rA0, rB0, sA, sB, acc);

    const int tid = threadIdx.x, lane = tid & 63, w = tid >> 6;
    const int lr = lane & 15, lg = lane >> 4;
    #pragma unroll
    for (int m = 0; m < 2; m++)
        #pragma unroll
        for (int r = 0; r < 4; r++) {
            float bvv = acc[m][0][r]; int bi = rB0 + lr;
            #pragma unroll
            for (int n = 1; n < 8; n++) {
                float v = acc[m][n][r]; int c = rB0 + n * 16 + lr;
                if (v > bvv) { bvv = v; bi = c; }
            }
            #pragma unroll
            for (int off = 1; off < 16; off <<= 1) {   // reduce within lr group
                float ov = __shfl_xor(bvv, off);
                int oi = __shfl_xor(bi, off);
                if (ov > bvv || (ov == bvv && oi < bi)) { bvv = ov; bi = oi; }
            }
            if (lr == 0) {
                int row = rA0 + w * 32 + m * 16 + lg * 4 + r;
                partV[(size_t)by * TTOK + row] = bvv;
                partI[(size_t)by * TTOK + row] = bi;
            }
        }
}

// ---------------------------------------------------------------- bestmerge + flags
__global__ void k_bmflags(const float* __restrict__ partV, const int* __restrict__ partI,
                          const unsigned char* __restrict__ maskraw, const float* __restrict__ act0,
                          int* best, int* novel, int* misc) {
    int t = blockIdx.x * 256 + threadIdx.x;   // grid 32
    int u8 = (maskraw[1] == 1);
    if (t < TTOK) {
        float bv = partV[t]; int bi = partI[t];
        #pragma unroll
        for (int q = 1; q < 32; q++) {
            float v = partV[(size_t)q * TTOK + t];
            int i = partI[(size_t)q * TTOK + t];
            if (v > bv || (v == bv && i < bi)) { bv = v; bi = i; }
        }
        best[t] = bi;
        int nv = (bv * SCALE < 0.5f) ? 1 : 0;
        novel[t] = nv;
        int mv = u8 ? (int)maskraw[t] : ((const int*)maskraw)[t];
        if (!nv || mv == 0) atomicAnd(&misc[1], 0);
    }
    if (t < NSLOT) {
        float a = act0[t];
        if (!(a >= 0.0f)) atomicAnd(&misc[1], 0);
    }
}

// ------------------------------------------------- ladder candidate generation
__global__ void k_ladder(const float* act0, u64* cand, int* candJ, int* misc) {
    if (misc[1] == 0) return;
    int i = blockIdx.x * 256 + threadIdx.x;
    if (i >= NSLOT) return;
    float w = act0[i];
    int j = 0;
    while (w < 1.0f) {
        if (j >= 48) { atomicAnd(&misc[2], 0); break; }
        int pos = atomicAdd(&misc[0], 1);
        if (pos >= CAPC) { atomicAnd(&misc[2], 0); break; }
        cand[pos] = ((u64)__float_as_uint(w) << 32) | (unsigned)i;
        candJ[pos] = j;
        j++;
        w = fminf(1.0f, w + 0.1f);
    }
}

// ------------------------------------------------- histogram (+ finalize fold)
__global__ void k_hist(const u64* cand, int* misc, int* hist) {
    if (blockIdx.x == 0 && threadIdx.x == 0)
        misc[3] = (misc[1] && misc[2] && misc[0] >= TTOK) ? 1 : 0;
    if (!(misc[1] && misc[2])) return;
    int K = misc[0]; if (K > CAPC) K = CAPC;
    int i = blockIdx.x * 256 + threadIdx.x;
    if (i >= K) return;
    float w = __uint_as_float((unsigned)(cand[i] >> 32));
    atomicAdd(&hist[bucketof(w)], 1);
}

__global__ __launch_bounds__(1024) void k_scanhist(const int* __restrict__ hist, int* __restrict__ offsB) {
    __shared__ int part[1024];
    int tid = threadIdx.x;
    int base = tid * 64;
    int s = 0;
    for (int i = 0; i < 64; i++) s += hist[base + i];
    part[tid] = s;
    __syncthreads();
    for (int off = 1; off < 1024; off <<= 1) {
        int v = (tid >= off) ? part[tid - off] : 0;
        __syncthreads();
        part[tid] += v;
        __syncthreads();
    }
    int pre = (tid == 0) ? 0 : part[tid - 1];
    for (int i = 0; i < 64; i++) { offsB[base + i] = pre; pre += hist[base + i]; }
}

__global__ void k_place(const u64* cand, const int* candJ, const int* misc,
                        const int* offsB, int* cnt2, u64* skey, int* sj) {
    if (!(misc[1] && misc[2])) return;
    int K = misc[0]; if (K > CAPC) K = CAPC;
    int i = blockIdx.x * 256 + threadIdx.x;
    if (i >= K) return;
    u64 key = cand[i];
    float w = __uint_as_float((unsigned)(key >> 32));
    int b = bucketof(w);
    int pos = offsB[b] + atomicAdd(&cnt2[b], 1);
    skey[pos] = key; sj[pos] = candJ[i];
}

__global__ void k_rank2(const u64* __restrict__ skey, const int* __restrict__ sj, const int* misc,
                        const int* __restrict__ offsB, const int* __restrict__ hist,
                        int* slot_seq, int* rankis, int* cnt) {
    if (!(misc[1] && misc[2])) return;
    int K = misc[0]; if (K > CAPC) K = CAPC;
    int i = blockIdx.x * 256 + threadIdx.x;
    if (i >= K) return;
    u64 my = skey[i];
    float w = __uint_as_float((unsigned)(my >> 32));
    int b = bucketof(w);
    int base = offsB[b], n = hist[b];
    int r = base;
    for (int q = 0; q < n; q++) r += (skey[base + q] < my) ? 1 : 0;
    if (r < TTOK) {
        int slot = (int)(my & 0xffffffffu);
        slot_seq[r] = slot;
        rankis[r] = sj[i];
        atomicAdd(&cnt[slot], 1);
    }
}

// ------------------------------------------------- act final + log(act) (fast path)
__global__ void k_actfinal(const float* act0, const int* cnt, float* act_f, float* la, const int* misc) {
    if (!misc[3]) return;
    int i = blockIdx.x * 256 + threadIdx.x;
    if (i >= NSLOT) return;
    float a = act0[i];
    int m = cnt[i];
    for (int r = 0; r < m; r++) a = fminf(1.0f, a + 0.1f);
    act_f[i] = a;
    la[i] = (a < 0.01f) ? -INFINITY : logf(fmaxf(a, 1e-8f));
}

// ------------------------------------------------- serial fallback (cold path)
__global__ __launch_bounds__(64) void k_serial(
    const int* novel, const int* best, const unsigned char* maskraw,
    const float* act0, const int* misc,
    int* slot_seq, int* rankis, int* cnt, float* act_f, float* la)
{
    if (misc[3]) return;
    __shared__ float act[NSLOT];
    __shared__ int cntL[NSLOT];
    const int lane = threadIdx.x;
    const int u8 = (maskraw[1] == 1);
    for (int i = lane; i < NSLOT; i += 64) { act[i] = act0[i]; cntL[i] = 0; }
    __syncthreads();
    float cv; int ci;
    {
        cv = act[lane * 64]; ci = lane * 64;
        for (int u = 1; u < 64; u++) {
            float v = act[lane * 64 + u];
            if (v < cv) { cv = v; ci = lane * 64 + u; }
        }
    }
    for (int t = 0; t < TTOK; t++) {
        int nv = novel[t];
        int mk = (u8 ? (int)maskraw[t] : ((const int*)maskraw)[t]) != 0;
        int slot;
        if (nv) {
            float v = cv; int ix = ci;
            for (int off = 32; off >= 1; off >>= 1) {
                float ov = __shfl_xor(v, off);
                int oi = __shfl_xor(ix, off);
                if (ov < v || (ov == v && oi < ix)) { v = ov; ix = oi; }
            }
            slot = ix;
        } else {
            slot = best[t];
        }
        if (mk) {
            float a = act[slot];
            float a2 = fminf(1.0f, a + 0.1f);
            __syncthreads();
            if (lane == 0) {
                act[slot] = a2;
                slot_seq[t] = slot;
                int r = cntL[slot]; rankis[t] = r; cntL[slot] = r + 1;
            }
            __syncthreads();
            int c = slot >> 6;
            float v = act[c * 64 + lane]; int ix = c * 64 + lane;
            for (int off = 32; off >= 1; off >>= 1) {
                float ov = __shfl_xor(v, off);
                int oi = __shfl_xor(ix, off);
                if (ov < v || (ov == v && oi < ix)) { v = ov; ix = oi; }
            }
            if (lane == c) { cv = v; ci = ix; }
        } else {
            if (lane == 0) rankis[t] = -1;
        }
        __syncthreads();
    }
    for (int i = lane; i < NSLOT; i += 64) {
        cnt[i] = cntL[i];
        float a = act[i];
        act_f[i] = a;
        la[i] = (a < 0.01f) ? -INFINITY : logf(fmaxf(a, 1e-8f));
    }
}

// ------------------------------------------------- offsets + scatter (one block)
__global__ __launch_bounds__(256) void k_offscatter(const int* cnt, int* offs,
                                                    const int* slot_seq, const int* rankis,
                                                    int* listTok) {
    __shared__ int soffs[NSLOT];
    __shared__ int part[256];
    int tid = threadIdx.x;
    int base = tid * 16;
    int loc[16];
    int s = 0;
    #pragma unroll
    for (int i = 0; i < 16; i++) { loc[i] = s; s += cnt[base + i]; }
    part[tid] = s;
    __syncthreads();
    for (int off = 1; off < 256; off <<= 1) {
        int v = (tid >= off) ? part[tid - off] : 0;
        __syncthreads();
        part[tid] += v;
        __syncthreads();
    }
    int pre = (tid == 0) ? 0 : part[tid - 1];
    #pragma unroll
    for (int i = 0; i < 16; i++) { soffs[base + i] = pre + loc[i]; offs[base + i] = pre + loc[i]; }
    __syncthreads();
    for (int t = tid; t < TTOK; t += 256) {
        int r = rankis[t];
        if (r >= 0) listTok[soffs[slot_seq[t]] + r] = t;
    }
}

// ------------------------------------------------- apply buffer writes per slot
__global__ __launch_bounds__(256) void k_apply(
    const float* __restrict__ keys0, const float* __restrict__ values0,
    const float* __restrict__ ka, const float* __restrict__ va,
    const int* __restrict__ novel, const int* __restrict__ cnt,
    const int* __restrict__ offs, const int* __restrict__ listTok,
    ushort_t* __restrict__ kb_bf, float* __restrict__ vb)
{
    int s = blockIdx.x;
    int d = threadIdx.x;
    float kv = keys0[(size_t)s * DIM + d];
    float vv = values0[(size_t)s * DIM + d];
    int m = cnt[s], off = offs[s];
    for (int r = 0; r < m; r++) {
        int t = listTok[off + r];
        float al = novel[t] ? 0.9f : 0.3f;
        kv = (1.0f - al) * kv + al * ka[(size_t)t * DIM + d];
        vv = (1.0f - al) * vv + al * va[(size_t)t * DIM + d];
    }
    kb_bf[(size_t)s * DIM + d] = f2bf(kv);
    vb[(size_t)s * DIM + d] = vv;
}

// ================================================= fused flash attention (no-max)
__global__ __launch_bounds__(256, 2) void k_flash(
    const ushort_t* __restrict__ qa_bf,   // [8192][256]
    const ushort_t* __restrict__ kb_bf,   // [4096][256]
    const ushort_t* __restrict__ vbT,     // [256][4096]
    const float* __restrict__ la,         // [4096]
    float* __restrict__ opart,            // [SPLIT][8192][256] unnormalized
    float* __restrict__ lpart)            // [SPLIT][8192]
{
    __shared__ ushort_t sK[4 * 64 * 64];   // 32KB swizzled
    __shared__ ushort_t sV[256 * 64];      // 32KB swizzled
    __shared__ ushort_t sP[4][16 * 64];    // 8KB per-wave private P tiles

    const int tid = threadIdx.x;
    const int w = tid >> 6;
    const int lane = tid & 63;
    const int lr = lane & 15, lg = lane >> 4;
    const int qw = blockIdx.x * QBLK + w * 16;
    const int z = blockIdx.y;
    const int sbase = z * (NSLOT / SPLIT);

    bf16x8 qreg[4][2];
    #pragma unroll
    for (int kc = 0; kc < 4; kc++)
        #pragma unroll
        for (int h = 0; h < 2; h++)
            qreg[kc][h] = *(const bf16x8*)&qa_bf[(size_t)(qw + lr) * DIM + kc*64 + h*32 + lg*8];

    f32x4 o_acc[16] = {};
    float lsum[4] = {0.f, 0.f, 0.f, 0.f};

    const int krow = tid >> 2, kseg = tid & 3;
    const int vrow = tid >> 3, vseg = tid & 7;

    for (int it = 0; it < NSLOT / SPLIT / 64; ++it) {
        int s0 = sbase + it * 64;
        __syncthreads();
        #pragma unroll
        for (int p = 0; p < 8; p++) {
            int g = p * 4 + kseg;
            uint4 v = *(const uint4*)&kb_bf[(size_t)(s0 + krow) * DIM + g * 8];
            int kc = g >> 3, c64 = (g & 7) * 8;
            *(uint4*)&sK[kc * 4096 + krow * 64 + (c64 ^ ((krow & 7) << 3))] = v;
        }
        #pragma unroll
        for (int p = 0; p < 8; p++) {
            int d = vrow + p * 32;
            uint4 v = *(const uint4*)&vbT[(size_t)d * NSLOT + s0 + vseg * 8];
            *(uint4*)&sV[d * 64 + ((vseg * 8) ^ ((d & 7) << 3))] = v;
        }
        __syncthreads();

        float la_r[4];
        #pragma unroll
        for (int n = 0; n < 4; n++) la_r[n] = la[s0 + n * 16 + lr];

        f32x4 accs[4] = {};
        #pragma unroll
        for (int n = 0; n < 4; n++) {
            int srow = n * 16 + lr;
            int sw = (srow & 7) << 3;
            #pragma unroll
            for (int kc = 0; kc < 4; kc++)
                #pragma unroll
                for (int h = 0; h < 2; h++) {
                    bf16x8 bF = *(const bf16x8*)&sK[kc * 4096 + srow * 64 + ((h * 32 + lg * 8) ^ sw)];
                    accs[n] = __builtin_amdgcn_mfma_f32_16x16x32_bf16(qreg[kc][h], bF, accs[n], 0, 0, 0);
                }
        }

        #pragma unroll
        for (int n = 0; n < 4; n++)
            #pragma unroll
            for (int r = 0; r < 4; r++) {
                int row = lg * 4 + r;
                float p = __expf(accs[n][r] * SCALE + la_r[n]);
                sP[w][row * 64 + ((n * 16 + lr) ^ ((row & 7) << 3))] = f2bf(p);
                lsum[r] += p;
            }

        #pragma unroll
        for (int h = 0; h < 2; h++) {
            bf16x8 aP = *(const bf16x8*)&sP[w][lr * 64 + ((h * 32 + lg * 8) ^ ((lr & 7) << 3))];
            #pragma unroll
            for (int nd = 0; nd < 16; nd++) {
                int d = nd * 16 + lr;
                bf16x8 bV = *(const bf16x8*)&sV[d * 64 + ((h * 32 + lg * 8) ^ ((d & 7) << 3))];
                o_acc[nd] = __builtin_amdgcn_mfma_f32_16x16x32_bf16(aP, bV, o_acc[nd], 0, 0, 0);
            }
        }
    }

    #pragma unroll
    for (int r = 0; r < 4; r++) {
        #pragma unroll
        for (int off = 1; off < 16; off <<= 1) lsum[r] += __shfl_xor(lsum[r], off);
        if (lr == 0) lpart[(size_t)z * TTOK + qw + lg * 4 + r] = lsum[r];
    }
    #pragma unroll
    for (int nd = 0; nd < 16; nd++)
        #pragma unroll
        for (int r = 0; r < 4; r++)
            opart[((size_t)z * TTOK + qw + lg * 4 + r) * DIM + nd * 16 + lr] = o_acc[nd][r];
}

// ------------------------------------------------- combine split partials
__global__ void k_comb(const float* __restrict__ opart, const float* __restrict__ lpart,
                       float* __restrict__ out) {
    int idx = blockIdx.x * 256 + threadIdx.x;
    int t = idx >> 8;
    float den = lpart[t] + lpart[TTOK + t] + lpart[2 * TTOK + t] + lpart[3 * TTOK + t];
    float num = opart[idx] + opart[(size_t)TTOK * DIM + idx]
              + opart[2 * (size_t)TTOK * DIM + idx] + opart[3 * (size_t)TTOK * DIM + idx];
    out[idx] = num / den;
}

// ================================================================ launch
extern "C" void kernel_launch(void* const* d_in, const int* in_sizes, int n_in,
                              void* d_out, int out_size, void* d_ws, size_t ws_size,
                              hipStream_t stream)
{
    (void)in_sizes; (void)n_in; (void)out_size; (void)ws_size;
    const float* x       = (const float*)d_in[0];
    const unsigned char* mask = (const unsigned char*)d_in[1];
    const float* keys0   = (const float*)d_in[2];
    const float* values0 = (const float*)d_in[3];
    const float* act0    = (const float*)d_in[4];
    const float* Wk = (const float*)d_in[5];
    const float* bk = (const float*)d_in[6];
    const float* Wv = (const float*)d_in[7];
    const float* bv = (const float*)d_in[8];
    const float* Wq = (const float*)d_in[9];
    const float* bq = (const float*)d_in[10];
    float* out = (float*)d_out;

    uint8_t* w = (uint8_t*)d_ws;
    size_t off = 0;
    auto alloc = [&](size_t bytes) -> void* {
        void* p = w + off;
        off = (off + bytes + 255) & ~(size_t)255;
        return p;
    };
    float*    ka     = (float*)   alloc((size_t)TTOK * DIM * 4);
    float*    va_    = (float*)   alloc((size_t)TTOK * DIM * 4);
    float*    vb     = (float*)   alloc((size_t)NSLOT * DIM * 4);
    ushort_t* x_bf   = (ushort_t*)alloc((size_t)TTOK * DIM * 2);
    ushort_t* wk_bf  = (ushort_t*)alloc((size_t)DIM * DIM * 2);
    ushort_t* wv_bf  = (ushort_t*)alloc((size_t)DIM * DIM * 2);
    ushort_t* wq_bf  = (ushort_t*)alloc((size_t)DIM * DIM * 2);
    ushort_t* ka_bf  = (ushort_t*)alloc((size_t)TTOK * DIM * 2);
    ushort_t* qa_bf  = (ushort_t*)alloc((size_t)TTOK * DIM * 2);
    ushort_t* k0_bf  = (ushort_t*)alloc((size_t)NSLOT * DIM * 2);
    ushort_t* kb_bf  = (ushort_t*)alloc((size_t)NSLOT * DIM * 2);
    ushort_t* vbT    = (ushort_t*)alloc((size_t)DIM * NSLOT * 2);
    float*    opart  = (float*)   alloc((size_t)SPLIT * TTOK * DIM * 4);
    float*    lpart  = (float*)   alloc((size_t)SPLIT * TTOK * 4);
    float*    partV  = (float*)   alloc((size_t)32 * TTOK * 4);
    int*      partI  = (int*)     alloc((size_t)32 * TTOK * 4);
    float*    act_f  = (float*)   alloc((size_t)NSLOT * 4);
    float*    la     = (float*)   alloc((size_t)NSLOT * 4);
    int*      best   = (int*)     alloc((size_t)TTOK * 4);
    int*      novel  = (int*)     alloc((size_t)TTOK * 4);
    int*      slot_seq = (int*)   alloc((size_t)TTOK * 4);
    int*      rankis = (int*)     alloc((size_t)TTOK * 4);
    int*      cnt    = (int*)     alloc((size_t)NSLOT * 4);
    int*      offs   = (int*)     alloc((size_t)NSLOT * 4);
    int*      listTok= (int*)     alloc((size_t)TTOK * 4);
    u64*      cand   = (u64*)     alloc((size_t)CAPC * 8);
    int*      candJ  = (int*)     alloc((size_t)CAPC * 4);
    u64*      skey   = (u64*)     alloc((size_t)CAPC * 8);
    int*      sj     = (int*)     alloc((size_t)CAPC * 4);
    int*      hist   = (int*)     alloc((size_t)NBUCK * 4);
    int*      cnt2   = (int*)     alloc((size_t)NBUCK * 4);
    int*      offsB  = (int*)     alloc((size_t)NBUCK * 4);
    int*      misc   = (int*)     alloc(64);

    k_zero<<<NBUCK/256, 256, 0, stream>>>(hist, cnt2, cnt, misc);
    k_prep<<<3264, 256, 0, stream>>>(x, Wk, Wv, Wq, keys0, x_bf, wk_bf, wv_bf, wq_bf, k0_bf);
    k_proj3<<<dim3(TTOK/128, 2, 3), 256, 0, stream>>>(
        x_bf, wk_bf, wv_bf, wq_bf, bk, bv, bq, ka, ka_bf, va_, qa_bf);
    k_sim<<<2048, 256, 0, stream>>>(ka_bf, k0_bf, partV, partI);
    k_bmflags<<<32, 256, 0, stream>>>(partV, partI, mask, act0, best, novel, misc);
    k_ladder<<<NSLOT/256, 256, 0, stream>>>(act0, cand, candJ, misc);
    k_hist<<<CAPC/256, 256, 0, stream>>>(cand, misc, hist);
    k_scanhist<<<1, 1024, 0, stream>>>(hist, offsB);
    k_place<<<CAPC/256, 256, 0, stream>>>(cand, candJ, misc, offsB, cnt2, skey, sj);
    k_rank2<<<CAPC/256, 256, 0, stream>>>(skey, sj, misc, offsB, hist, slot_seq, rankis, cnt);
    k_actfinal<<<NSLOT/256, 256, 0, stream>>>(act0, cnt, act_f, la, misc);
    k_serial<<<1, 64, 0, stream>>>(novel, best, mask, act0, misc, slot_seq, rankis, cnt, act_f, la);
    k_offscatter<<<1, 256, 0, stream>>>(cnt, offs, slot_seq, rankis, listTok);
    k_apply<<<NSLOT, 256, 0, stream>>>(keys0, values0, ka, va_, novel, cnt, offs, listTok, kb_bf, vb);
    k_transV<<<dim3(NSLOT/32, DIM/32), 256, 0, stream>>>(vb, vbT);
    k_flash<<<dim3(TTOK/QBLK, SPLIT), 256, 0, stream>>>(qa_bf, kb_bf, vbT, la, opart, lpart);
    k_comb<<<TTOK*DIM/256, 256, 0, stream>>>(opart, lpart, out);
}

// Round 10
// 291.461 us; speedup vs baseline: 4.7657x; 1.0314x over previous
//
#include <hip/hip_runtime.h>
#include <hip/hip_bf16.h>
#include <math.h>
#include <stdint.h>

// Problem constants (B=8,S=1024,D=256,N=4096)
#define TTOK 8192
#define DIM 256
#define NSLOT 4096
#define CAPC 65536
#define NBUCK 65536
#define SCALE 0.0625f     // 1/sqrt(256), exact
#define QBLK 128
#define SPLIT 4

typedef unsigned long long u64;
typedef unsigned short ushort_t;
typedef __attribute__((ext_vector_type(8))) __bf16 bf16x8;
typedef __attribute__((ext_vector_type(4))) float f32x4;

__device__ inline ushort_t f2bf(float f) {
    unsigned u = __float_as_uint(f);
    unsigned r = (u + 0x7fffu + ((u >> 16) & 1u)) >> 16;   // RNE
    return (ushort_t)r;
}
__device__ inline int bucketof(float w) {
    int b = (int)(w * 65536.0f);
    return b > 65535 ? 65535 : b;
}

// misc[0]=cand count, misc[1]=flagA, misc[2]=flagB, misc[3]=fast-path valid

// ---------------------------------------------------------------- zero/init
__global__ void k_zero(int* hist, int* cnt2, int* cnt, int* misc) {
    int i = blockIdx.x * 256 + threadIdx.x;   // grid 256 -> 65536
    hist[i] = 0; cnt2[i] = 0;
    if (i < NSLOT) cnt[i] = 0;
    if (i == 0) { misc[0] = 0; misc[1] = 1; misc[2] = 1; misc[3] = 0; }
}

// ---------------------------------------------------------------- all casts fused
__global__ void k_prep(const float* __restrict__ x, const float* __restrict__ Wk,
                       const float* __restrict__ Wv, const float* __restrict__ Wq,
                       const float* __restrict__ keys0,
                       ushort_t* __restrict__ x_bf, ushort_t* __restrict__ wk_bf,
                       ushort_t* __restrict__ wv_bf, ushort_t* __restrict__ wq_bf,
                       ushort_t* __restrict__ k0_bf)
{
    int b = blockIdx.x;
    const float* src; ushort_t* dst; int i;
    if (b < 2048)      { src = x;     dst = x_bf;  i = (b * 256 + threadIdx.x) * 4; }
    else if (b < 2112) { src = Wk;    dst = wk_bf; i = ((b - 2048) * 256 + threadIdx.x) * 4; }
    else if (b < 2176) { src = Wv;    dst = wv_bf; i = ((b - 2112) * 256 + threadIdx.x) * 4; }
    else if (b < 2240) { src = Wq;    dst = wq_bf; i = ((b - 2176) * 256 + threadIdx.x) * 4; }
    else               { src = keys0; dst = k0_bf; i = ((b - 2240) * 256 + threadIdx.x) * 4; }
    float4 v = *(const float4*)&src[i];
    ushort4 o;
    o.x = f2bf(v.x); o.y = f2bf(v.y); o.z = f2bf(v.z); o.w = f2bf(v.w);
    *(ushort4*)&dst[i] = o;
}

// ---------------------------------------------------------------- vb -> vbT (bf16)
__global__ __launch_bounds__(256) void k_transV(const float* __restrict__ vb, ushort_t* __restrict__ vbT) {
    __shared__ float ts[32][33];
    int tx = threadIdx.x & 31, ty = threadIdx.x >> 5;
    int s0 = blockIdx.x * 32, d0 = blockIdx.y * 32;
    #pragma unroll
    for (int j = 0; j < 4; j++)
        ts[ty + j*8][tx] = vb[(size_t)(s0 + ty + j*8) * DIM + d0 + tx];
    __syncthreads();
    #pragma unroll
    for (int j = 0; j < 4; j++)
        vbT[(size_t)(d0 + ty + j*8) * NSLOT + s0 + tx] = f2bf(ts[tx][ty + j*8]);
}

// =============================================================== GEMM core
// 128x128 tile, K = KSTEPS*64. Wave w owns rows w*32..w*32+31 x ALL 128 cols.
// NAMED-SCALAR registers (no arrays/lambdas -> no scratch spill, rule #20).
// Single-depth prefetch + LDS double-buffer; ONE barrier per K-step.
template<int KSTEPS>
__device__ __forceinline__ void gemm_core(
    const ushort_t* __restrict__ A, const ushort_t* __restrict__ B,
    int lda, int ldb, int rA0, int rB0,
    ushort_t* sA, ushort_t* sB, f32x4 (&acc)[2][8])
{
    const int tid = threadIdx.x;
    const int lane = tid & 63;
    const int w = tid >> 6;
    const int lr = lane & 15, lg = lane >> 4;
    const int ex = (tid & 7) * 8;
    const int rsub = tid >> 3;   // 0..31  (rows rsub, rsub+32, +64, +96)
    const int xi = ex ^ ((rsub & 7) << 3);
    const ushort_t* pA = A + (size_t)(rA0 + rsub) * lda + ex;
    const ushort_t* pB = B + (size_t)(rB0 + rsub) * ldb + ex;
    const size_t strA = (size_t)32 * lda;
    const size_t strB = (size_t)32 * ldb;

    uint4 a0, a1, a2, a3, b0, b1, b2, b3;

#define LOADSET(s) do { \
    a0 = *(const uint4*)(pA + (s) * 64);             b0 = *(const uint4*)(pB + (s) * 64); \
    a1 = *(const uint4*)(pA + strA + (s) * 64);      b1 = *(const uint4*)(pB + strB + (s) * 64); \
    a2 = *(const uint4*)(pA + 2 * strA + (s) * 64);  b2 = *(const uint4*)(pB + 2 * strB + (s) * 64); \
    a3 = *(const uint4*)(pA + 3 * strA + (s) * 64);  b3 = *(const uint4*)(pB + 3 * strB + (s) * 64); } while (0)

#define STAGESET(buf) do { \
    ushort_t* dA = sA + (buf) * 8192 + rsub * 64 + xi; \
    ushort_t* dB = sB + (buf) * 8192 + rsub * 64 + xi; \
    *(uint4*)(dA)            = a0;  *(uint4*)(dB)            = b0; \
    *(uint4*)(dA + 32 * 64)  = a1;  *(uint4*)(dB + 32 * 64)  = b1; \
    *(uint4*)(dA + 64 * 64)  = a2;  *(uint4*)(dB + 64 * 64)  = b2; \
    *(uint4*)(dA + 96 * 64)  = a3;  *(uint4*)(dB + 96 * 64)  = b3; } while (0)

    LOADSET(0);
    STAGESET(0);
    #pragma unroll
    for (int s = 0; s < KSTEPS; ++s) {
        if (s + 1 < KSTEPS) LOADSET(s + 1);       // issue next-step loads early
        __syncthreads();                           // buf[s&1] staged by all waves
        const ushort_t* cA = sA + (s & 1) * 8192;
        const ushort_t* cB = sB + (s & 1) * 8192;
        #pragma unroll
        for (int h = 0; h < 2; h++) {
            int xs0 = (h * 32 + lg * 8) ^ ((lr & 7) << 3);
            bf16x8 aF0 = *(const bf16x8*)&cA[(w * 32 + lr) * 64 + xs0];
            bf16x8 aF1 = *(const bf16x8*)&cA[(w * 32 + 16 + lr) * 64 + xs0];
            #pragma unroll
            for (int n = 0; n < 8; n++) {
                bf16x8 bF = *(const bf16x8*)&cB[(n * 16 + lr) * 64 + xs0];
                acc[0][n] = __builtin_amdgcn_mfma_f32_16x16x32_bf16(aF0, bF, acc[0][n], 0, 0, 0);
                acc[1][n] = __builtin_amdgcn_mfma_f32_16x16x32_bf16(aF1, bF, acc[1][n], 0, 0, 0);
            }
        }
        if (s + 1 < KSTEPS) STAGESET((s + 1) & 1); // other buffer: no race with readers of buf[s&1]
    }
#undef LOADSET
#undef STAGESET
}

// ---------------- 3 projections in one dispatch: grid (64, 2, 3)
__global__ __launch_bounds__(256) void k_proj3(
    const ushort_t* __restrict__ x_bf,
    const ushort_t* __restrict__ wk_bf, const ushort_t* __restrict__ wv_bf,
    const ushort_t* __restrict__ wq_bf,
    const float* __restrict__ bk, const float* __restrict__ bv, const float* __restrict__ bq,
    float* __restrict__ ka, ushort_t* __restrict__ ka_bf,
    float* __restrict__ va, ushort_t* __restrict__ qa_bf)
{
    __shared__ ushort_t sA[2 * 8192];
    __shared__ ushort_t sB[2 * 8192];
    const ushort_t* B; const float* bias; float* oF; ushort_t* oB;
    int z = blockIdx.z;
    if (z == 0)      { B = wk_bf; bias = bk; oF = ka;      oB = ka_bf;   }
    else if (z == 1) { B = wv_bf; bias = bv; oF = va;      oB = nullptr; }
    else             { B = wq_bf; bias = bq; oF = nullptr; oB = qa_bf;  }
    int rA0 = blockIdx.x * 128, rB0 = blockIdx.y * 128;
    f32x4 acc[2][8] = {};
    gemm_core<4>(x_bf, B, DIM, DIM, rA0, rB0, sA, sB, acc);

    const int tid = threadIdx.x, lane = tid & 63, w = tid >> 6;
    const int lr = lane & 15, lg = lane >> 4;
    #pragma unroll
    for (int n = 0; n < 8; n++) {
        int gcol = rB0 + n * 16 + lr;
        float bj = bias[gcol];
        #pragma unroll
        for (int m = 0; m < 2; m++)
            #pragma unroll
            for (int r = 0; r < 4; r++) {
                int grow = rA0 + w * 32 + m * 16 + lg * 4 + r;
                float v = acc[m][n][r] + bj;
                if (oF) oF[(size_t)grow * DIM + gcol] = v;
                if (oB) oB[(size_t)grow * DIM + gcol] = f2bf(v);
            }
    }
}

// ---------------- simmax: grid 2048 1-D, XCD-swizzled; per-wave argmax epilogue
__global__ __launch_bounds__(256) void k_sim(
    const ushort_t* __restrict__ ka_bf, const ushort_t* __restrict__ k0_bf,
    float* __restrict__ partV, int* __restrict__ partI)
{
    __shared__ ushort_t sA[2 * 8192];
    __shared__ ushort_t sB[2 * 8192];
    int lin = blockIdx.x;
    int xcd = lin & 7, pos = lin >> 3;
    int bx = pos >> 2, by = (xcd << 2) | (pos & 3);
    int rA0 = bx * 128, rB0 = by * 128;
    f32x4 acc[2][8] = {};
    gemm_core<4>(ka_bf, k0_bf, DIM, DIM, rA0, rB0, sA, sB, acc);

    const int tid = threadIdx.x, lane = tid & 63, w = tid >> 6;
    const int lr = lane & 15, lg = lane >> 4;
    #pragma unroll
    for (int m = 0; m < 2; m++)
        #pragma unroll
        for (int r = 0; r < 4; r++) {
            float bvv = acc[m][0][r]; int bi = rB0 + lr;
            #pragma unroll
            for (int n = 1; n < 8; n++) {
                float v = acc[m][n][r]; int c = rB0 + n * 16 + lr;
                if (v > bvv) { bvv = v; bi = c; }
            }
            #pragma unroll
            for (int off = 1; off < 16; off <<= 1) {   // reduce within lr group
                float ov = __shfl_xor(bvv, off);
                int oi = __shfl_xor(bi, off);
                if (ov > bvv || (ov == bvv && oi < bi)) { bvv = ov; bi = oi; }
            }
            if (lr == 0) {
                int row = rA0 + w * 32 + m * 16 + lg * 4 + r;
                partV[(size_t)by * TTOK + row] = bvv;
                partI[(size_t)by * TTOK + row] = bi;
            }
        }
}

// ---------------------------------------------------------------- bestmerge + flags
__global__ void k_bmflags(const float* __restrict__ partV, const int* __restrict__ partI,
                          const unsigned char* __restrict__ maskraw, const float* __restrict__ act0,
                          int* best, int* novel, int* misc) {
    int t = blockIdx.x * 256 + threadIdx.x;   // grid 32
    int u8 = (maskraw[1] == 1);
    if (t < TTOK) {
        float bv = partV[t]; int bi = partI[t];
        #pragma unroll
        for (int q = 1; q < 32; q++) {
            float v = partV[(size_t)q * TTOK + t];
            int i = partI[(size_t)q * TTOK + t];
            if (v > bv || (v == bv && i < bi)) { bv = v; bi = i; }
        }
        best[t] = bi;
        int nv = (bv * SCALE < 0.5f) ? 1 : 0;
        novel[t] = nv;
        int mv = u8 ? (int)maskraw[t] : ((const int*)maskraw)[t];
        if (!nv || mv == 0) atomicAnd(&misc[1], 0);
    }
    if (t < NSLOT) {
        float a = act0[t];
        if (!(a >= 0.0f)) atomicAnd(&misc[1], 0);
    }
}

// ------------------------------------------------- ladder candidate generation
__global__ void k_ladder(const float* act0, u64* cand, int* candJ, int* misc) {
    if (misc[1] == 0) return;
    int i = blockIdx.x * 256 + threadIdx.x;
    if (i >= NSLOT) return;
    float w = act0[i];
    int j = 0;
    while (w < 1.0f) {
        if (j >= 48) { atomicAnd(&misc[2], 0); break; }
        int pos = atomicAdd(&misc[0], 1);
        if (pos >= CAPC) { atomicAnd(&misc[2], 0); break; }
        cand[pos] = ((u64)__float_as_uint(w) << 32) | (unsigned)i;
        candJ[pos] = j;
        j++;
        w = fminf(1.0f, w + 0.1f);
    }
}

// ------------------------------------------------- histogram (+ finalize fold)
__global__ void k_hist(const u64* cand, int* misc, int* hist) {
    if (blockIdx.x == 0 && threadIdx.x == 0)
        misc[3] = (misc[1] && misc[2] && misc[0] >= TTOK) ? 1 : 0;
    if (!(misc[1] && misc[2])) return;
    int K = misc[0]; if (K > CAPC) K = CAPC;
    int i = blockIdx.x * 256 + threadIdx.x;
    if (i >= K) return;
    float w = __uint_as_float((unsigned)(cand[i] >> 32));
    atomicAdd(&hist[bucketof(w)], 1);
}

__global__ __launch_bounds__(1024) void k_scanhist(const int* __restrict__ hist, int* __restrict__ offsB) {
    __shared__ int part[1024];
    int tid = threadIdx.x;
    int base = tid * 64;
    int s = 0;
    for (int i = 0; i < 64; i++) s += hist[base + i];
    part[tid] = s;
    __syncthreads();
    for (int off = 1; off < 1024; off <<= 1) {
        int v = (tid >= off) ? part[tid - off] : 0;
        __syncthreads();
        part[tid] += v;
        __syncthreads();
    }
    int pre = (tid == 0) ? 0 : part[tid - 1];
    for (int i = 0; i < 64; i++) { offsB[base + i] = pre; pre += hist[base + i]; }
}

__global__ void k_place(const u64* cand, const int* candJ, const int* misc,
                        const int* offsB, int* cnt2, u64* skey, int* sj) {
    if (!(misc[1] && misc[2])) return;
    int K = misc[0]; if (K > CAPC) K = CAPC;
    int i = blockIdx.x * 256 + threadIdx.x;
    if (i >= K) return;
    u64 key = cand[i];
    float w = __uint_as_float((unsigned)(key >> 32));
    int b = bucketof(w);
    int pos = offsB[b] + atomicAdd(&cnt2[b], 1);
    skey[pos] = key; sj[pos] = candJ[i];
}

__global__ void k_rank2(const u64* __restrict__ skey, const int* __restrict__ sj, const int* misc,
                        const int* __restrict__ offsB, const int* __restrict__ hist,
                        int* slot_seq, int* rankis, int* cnt) {
    if (!(misc[1] && misc[2])) return;
    int K = misc[0]; if (K > CAPC) K = CAPC;
    int i = blockIdx.x * 256 + threadIdx.x;
    if (i >= K) return;
    u64 my = skey[i];
    float w = __uint_as_float((unsigned)(my >> 32));
    int b = bucketof(w);
    int base = offsB[b], n = hist[b];
    int r = base;
    for (int q = 0; q < n; q++) r += (skey[base + q] < my) ? 1 : 0;
    if (r < TTOK) {
        int slot = (int)(my & 0xffffffffu);
        slot_seq[r] = slot;
        rankis[r] = sj[i];
        atomicAdd(&cnt[slot], 1);
    }
}

// ------------------------------------------------- act final + log(act) (fast path)
__global__ void k_actfinal(const float* act0, const int* cnt, float* act_f, float* la, const int* misc) {
    if (!misc[3]) return;
    int i = blockIdx.x * 256 + threadIdx.x;
    if (i >= NSLOT) return;
    float a = act0[i];
    int m = cnt[i];
    for (int r = 0; r < m; r++) a = fminf(1.0f, a + 0.1f);
    act_f[i] = a;
    la[i] = (a < 0.01f) ? -INFINITY : logf(fmaxf(a, 1e-8f));
}

// ------------------------------------------------- serial fallback (cold path)
__global__ __launch_bounds__(64) void k_serial(
    const int* novel, const int* best, const unsigned char* maskraw,
    const float* act0, const int* misc,
    int* slot_seq, int* rankis, int* cnt, float* act_f, float* la)
{
    if (misc[3]) return;
    __shared__ float act[NSLOT];
    __shared__ int cntL[NSLOT];
    const int lane = threadIdx.x;
    const int u8 = (maskraw[1] == 1);
    for (int i = lane; i < NSLOT; i += 64) { act[i] = act0[i]; cntL[i] = 0; }
    __syncthreads();
    float cv; int ci;
    {
        cv = act[lane * 64]; ci = lane * 64;
        for (int u = 1; u < 64; u++) {
            float v = act[lane * 64 + u];
            if (v < cv) { cv = v; ci = lane * 64 + u; }
        }
    }
    for (int t = 0; t < TTOK; t++) {
        int nv = novel[t];
        int mk = (u8 ? (int)maskraw[t] : ((const int*)maskraw)[t]) != 0;
        int slot;
        if (nv) {
            float v = cv; int ix = ci;
            for (int off = 32; off >= 1; off >>= 1) {
                float ov = __shfl_xor(v, off);
                int oi = __shfl_xor(ix, off);
                if (ov < v || (ov == v && oi < ix)) { v = ov; ix = oi; }
            }
            slot = ix;
        } else {
            slot = best[t];
        }
        if (mk) {
            float a = act[slot];
            float a2 = fminf(1.0f, a + 0.1f);
            __syncthreads();
            if (lane == 0) {
                act[slot] = a2;
                slot_seq[t] = slot;
                int r = cntL[slot]; rankis[t] = r; cntL[slot] = r + 1;
            }
            __syncthreads();
            int c = slot >> 6;
            float v = act[c * 64 + lane]; int ix = c * 64 + lane;
            for (int off = 32; off >= 1; off >>= 1) {
                float ov = __shfl_xor(v, off);
                int oi = __shfl_xor(ix, off);
                if (ov < v || (ov == v && oi < ix)) { v = ov; ix = oi; }
            }
            if (lane == c) { cv = v; ci = ix; }
        } else {
            if (lane == 0) rankis[t] = -1;
        }
        __syncthreads();
    }
    for (int i = lane; i < NSLOT; i += 64) {
        cnt[i] = cntL[i];
        float a = act[i];
        act_f[i] = a;
        la[i] = (a < 0.01f) ? -INFINITY : logf(fmaxf(a, 1e-8f));
    }
}

// ------------------------------------------------- offsets + scatter (one block)
__global__ __launch_bounds__(256) void k_offscatter(const int* cnt, int* offs,
                                                    const int* slot_seq, const int* rankis,
                                                    int* listTok) {
    __shared__ int soffs[NSLOT];
    __shared__ int part[256];
    int tid = threadIdx.x;
    int base = tid * 16;
    int loc[16];
    int s = 0;
    #pragma unroll
    for (int i = 0; i < 16; i++) { loc[i] = s; s += cnt[base + i]; }
    part[tid] = s;
    __syncthreads();
    for (int off = 1; off < 256; off <<= 1) {
        int v = (tid >= off) ? part[tid - off] : 0;
        __syncthreads();
        part[tid] += v;
        __syncthreads();
    }
    int pre = (tid == 0) ? 0 : part[tid - 1];
    #pragma unroll
    for (int i = 0; i < 16; i++) { soffs[base + i] = pre + loc[i]; offs[base + i] = pre + loc[i]; }
    __syncthreads();
    for (int t = tid; t < TTOK; t += 256) {
        int r = rankis[t];
        if (r >= 0) listTok[soffs[slot_seq[t]] + r] = t;
    }
}

// ------------------------------------------------- apply buffer writes per slot
__global__ __launch_bounds__(256) void k_apply(
    const float* __restrict__ keys0, const float* __restrict__ values0,
    const float* __restrict__ ka, const float* __restrict__ va,
    const int* __restrict__ novel, const int* __restrict__ cnt,
    const int* __restrict__ offs, const int* __restrict__ listTok,
    ushort_t* __restrict__ kb_bf, float* __restrict__ vb)
{
    int s = blockIdx.x;
    int d = threadIdx.x;
    float kv = keys0[(size_t)s * DIM + d];
    float vv = values0[(size_t)s * DIM + d];
    int m = cnt[s], off = offs[s];
    for (int r = 0; r < m; r++) {
        int t = listTok[off + r];
        float al = novel[t] ? 0.9f : 0.3f;
        kv = (1.0f - al) * kv + al * ka[(size_t)t * DIM + d];
        vv = (1.0f - al) * vv + al * va[(size_t)t * DIM + d];
    }
    kb_bf[(size_t)s * DIM + d] = f2bf(kv);
    vb[(size_t)s * DIM + d] = vv;
}

// ================================================= fused flash attention (no-max)
// 8 waves x 16 q-rows = QBLK 128; reg-prefetch staging overlaps L2 latency with
// compute; one 64KB K/V stage now serves 2x the q-rows vs R8.
__global__ __launch_bounds__(512, 2) void k_flash(
    const ushort_t* __restrict__ qa_bf,   // [8192][256]
    const ushort_t* __restrict__ kb_bf,   // [4096][256]
    const ushort_t* __restrict__ vbT,     // [256][4096]
    const float* __restrict__ la,         // [4096]
    float* __restrict__ opart,            // [SPLIT][8192][256] unnormalized
    float* __restrict__ lpart)            // [SPLIT][8192]
{
    __shared__ ushort_t sK[4 * 64 * 64];   // 32KB [kc][slot][64] swizzled
    __shared__ ushort_t sV[256 * 64];      // 32KB [d][slot] swizzled
    __shared__ ushort_t sP[8][16 * 64];    // 16KB per-wave private P tiles

    const int tid = threadIdx.x;
    const int w = tid >> 6;               // 0..7
    const int lane = tid & 63;
    const int lr = lane & 15, lg = lane >> 4;
    const int qw = blockIdx.x * QBLK + w * 16;
    const int z = blockIdx.y;
    const int sbase = z * (NSLOT / SPLIT);
    const int NT = NSLOT / SPLIT / 64;    // 16 tiles

    bf16x8 qreg[4][2];
    #pragma unroll
    for (int kc = 0; kc < 4; kc++)
        #pragma unroll
        for (int h = 0; h < 2; h++)
            qreg[kc][h] = *(const bf16x8*)&qa_bf[(size_t)(qw + lr) * DIM + kc*64 + h*32 + lg*8];

    f32x4 o_acc[16] = {};
    float lsum[4] = {0.f, 0.f, 0.f, 0.f};

    // staging decomposition for 512 threads
    const int krow = tid >> 3, kseg = tid & 7;   // K: 8 thr/row, 64 rows; 4 granules/thr
    const int dvb  = tid >> 3, vseg = tid & 7;   // V: d = p*64 + dvb, granule vseg
    const ushort_t* gK = kb_bf + (size_t)(sbase + krow) * DIM + kseg * 8;
    const ushort_t* gV = vbT + (size_t)dvb * NSLOT + sbase + vseg * 8;
    const int kx = (kseg * 8) ^ ((krow & 7) << 3);
    const int vx = (vseg * 8) ^ ((dvb & 7) << 3);

    uint4 kr0, kr1, kr2, kr3, vr0, vr1, vr2, vr3;   // named: no scratch (rule #20)

#define LOADKV(it) do { \
    const ushort_t* pk = gK + (size_t)(it) * 64 * DIM; \
    const ushort_t* pv = gV + (it) * 64; \
    kr0 = *(const uint4*)(pk);        kr1 = *(const uint4*)(pk + 64); \
    kr2 = *(const uint4*)(pk + 128);  kr3 = *(const uint4*)(pk + 192); \
    vr0 = *(const uint4*)(pv);                         vr1 = *(const uint4*)(pv + (size_t)64 * NSLOT); \
    vr2 = *(const uint4*)(pv + (size_t)128 * NSLOT);   vr3 = *(const uint4*)(pv + (size_t)192 * NSLOT); } while (0)

#define STOREKV() do { \
    *(uint4*)&sK[0 * 4096 + krow * 64 + kx] = kr0; \
    *(uint4*)&sK[1 * 4096 + krow * 64 + kx] = kr1; \
    *(uint4*)&sK[2 * 4096 + krow * 64 + kx] = kr2; \
    *(uint4*)&sK[3 * 4096 + krow * 64 + kx] = kr3; \
    *(uint4*)&sV[(0 * 64 + dvb) * 64 + vx] = vr0; \
    *(uint4*)&sV[(1 * 64 + dvb) * 64 + vx] = vr1; \
    *(uint4*)&sV[(2 * 64 + dvb) * 64 + vx] = vr2; \
    *(uint4*)&sV[(3 * 64 + dvb) * 64 + vx] = vr3; } while (0)

    LOADKV(0);
    for (int it = 0; it < NT; ++it) {
        __syncthreads();                  // previous tile fully consumed
        STOREKV();
        if (it + 1 < NT) LOADKV(it + 1);  // prefetch overlaps this tile's compute
        __syncthreads();                  // staged data visible

        int s0c = sbase + it * 64;
        float la_r[4];
        #pragma unroll
        for (int n = 0; n < 4; n++) la_r[n] = la[s0c + n * 16 + lr];

        // S = Q K^T for this wave's 16 rows x 64 slots
        f32x4 accs[4] = {};
        #pragma unroll
        for (int n = 0; n < 4; n++) {
            int srow = n * 16 + lr;
            int sw = (srow & 7) << 3;
            #pragma unroll
            for (int kc = 0; kc < 4; kc++)
                #pragma unroll
                for (int h = 0; h < 2; h++) {
                    bf16x8 bF = *(const bf16x8*)&sK[kc * 4096 + srow * 64 + ((h * 32 + lg * 8) ^ sw)];
                    accs[n] = __builtin_amdgcn_mfma_f32_16x16x32_bf16(qreg[kc][h], bF, accs[n], 0, 0, 0);
                }
        }

        // P = exp(S*scale + la) (no max shift; bounded logits)
        #pragma unroll
        for (int n = 0; n < 4; n++)
            #pragma unroll
            for (int r = 0; r < 4; r++) {
                int row = lg * 4 + r;
                float p = __expf(accs[n][r] * SCALE + la_r[n]);
                sP[w][row * 64 + ((n * 16 + lr) ^ ((row & 7) << 3))] = f2bf(p);
                lsum[r] += p;
            }

        // PV: O += P * V
        #pragma unroll
        for (int h = 0; h < 2; h++) {
            bf16x8 aP = *(const bf16x8*)&sP[w][lr * 64 + ((h * 32 + lg * 8) ^ ((lr & 7) << 3))];
            #pragma unroll
            for (int nd = 0; nd < 16; nd++) {
                int d = nd * 16 + lr;
                bf16x8 bV = *(const bf16x8*)&sV[d * 64 + ((h * 32 + lg * 8) ^ ((d & 7) << 3))];
                o_acc[nd] = __builtin_amdgcn_mfma_f32_16x16x32_bf16(aP, bV, o_acc[nd], 0, 0, 0);
            }
        }
    }
#undef LOADKV
#undef STOREKV

    #pragma unroll
    for (int r = 0; r < 4; r++) {
        #pragma unroll
        for (int off = 1; off < 16; off <<= 1) lsum[r] += __shfl_xor(lsum[r], off);
        if (lr == 0) lpart[(size_t)z * TTOK + qw + lg * 4 + r] = lsum[r];
    }
    #pragma unroll
    for (int nd = 0; nd < 16; nd++)
        #pragma unroll
        for (int r = 0; r < 4; r++)
            opart[((size_t)z * TTOK + qw + lg * 4 + r) * DIM + nd * 16 + lr] = o_acc[nd][r];
}

// ------------------------------------------------- combine split partials
__global__ void k_comb(const float* __restrict__ opart, const float* __restrict__ lpart,
                       float* __restrict__ out) {
    int idx = blockIdx.x * 256 + threadIdx.x;
    int t = idx >> 8;
    float den = lpart[t] + lpart[TTOK + t] + lpart[2 * TTOK + t] + lpart[3 * TTOK + t];
    float num = opart[idx] + opart[(size_t)TTOK * DIM + idx]
              + opart[2 * (size_t)TTOK * DIM + idx] + opart[3 * (size_t)TTOK * DIM + idx];
    out[idx] = num / den;
}

// ================================================================ launch
extern "C" void kernel_launch(void* const* d_in, const int* in_sizes, int n_in,
                              void* d_out, int out_size, void* d_ws, size_t ws_size,
                              hipStream_t stream)
{
    (void)in_sizes; (void)n_in; (void)out_size; (void)ws_size;
    const float* x       = (const float*)d_in[0];
    const unsigned char* mask = (const unsigned char*)d_in[1];
    const float* keys0   = (const float*)d_in[2];
    const float* values0 = (const float*)d_in[3];
    const float* act0    = (const float*)d_in[4];
    const float* Wk = (const float*)d_in[5];
    const float* bk = (const float*)d_in[6];
    const float* Wv = (const float*)d_in[7];
    const float* bv = (const float*)d_in[8];
    const float* Wq = (const float*)d_in[9];
    const float* bq = (const float*)d_in[10];
    float* out = (float*)d_out;

    uint8_t* w = (uint8_t*)d_ws;
    size_t off = 0;
    auto alloc = [&](size_t bytes) -> void* {
        void* p = w + off;
        off = (off + bytes + 255) & ~(size_t)255;
        return p;
    };
    float*    ka     = (float*)   alloc((size_t)TTOK * DIM * 4);
    float*    va_    = (float*)   alloc((size_t)TTOK * DIM * 4);
    float*    vb     = (float*)   alloc((size_t)NSLOT * DIM * 4);
    ushort_t* x_bf   = (ushort_t*)alloc((size_t)TTOK * DIM * 2);
    ushort_t* wk_bf  = (ushort_t*)alloc((size_t)DIM * DIM * 2);
    ushort_t* wv_bf  = (ushort_t*)alloc((size_t)DIM * DIM * 2);
    ushort_t* wq_bf  = (ushort_t*)alloc((size_t)DIM * DIM * 2);
    ushort_t* ka_bf  = (ushort_t*)alloc((size_t)TTOK * DIM * 2);
    ushort_t* qa_bf  = (ushort_t*)alloc((size_t)TTOK * DIM * 2);
    ushort_t* k0_bf  = (ushort_t*)alloc((size_t)NSLOT * DIM * 2);
    ushort_t* kb_bf  = (ushort_t*)alloc((size_t)NSLOT * DIM * 2);
    ushort_t* vbT    = (ushort_t*)alloc((size_t)DIM * NSLOT * 2);
    float*    opart  = (float*)   alloc((size_t)SPLIT * TTOK * DIM * 4);
    float*    lpart  = (float*)   alloc((size_t)SPLIT * TTOK * 4);
    float*    partV  = (float*)   alloc((size_t)32 * TTOK * 4);
    int*      partI  = (int*)     alloc((size_t)32 * TTOK * 4);
    float*    act_f  = (float*)   alloc((size_t)NSLOT * 4);
    float*    la     = (float*)   alloc((size_t)NSLOT * 4);
    int*      best   = (int*)     alloc((size_t)TTOK * 4);
    int*      novel  = (int*)     alloc((size_t)TTOK * 4);
    int*      slot_seq = (int*)   alloc((size_t)TTOK * 4);
    int*      rankis = (int*)     alloc((size_t)TTOK * 4);
    int*      cnt    = (int*)     alloc((size_t)NSLOT * 4);
    int*      offs   = (int*)     alloc((size_t)NSLOT * 4);
    int*      listTok= (int*)     alloc((size_t)TTOK * 4);
    u64*      cand   = (u64*)     alloc((size_t)CAPC * 8);
    int*      candJ  = (int*)     alloc((size_t)CAPC * 4);
    u64*      skey   = (u64*)     alloc((size_t)CAPC * 8);
    int*      sj     = (int*)     alloc((size_t)CAPC * 4);
    int*      hist   = (int*)     alloc((size_t)NBUCK * 4);
    int*      cnt2   = (int*)     alloc((size_t)NBUCK * 4);
    int*      offsB  = (int*)     alloc((size_t)NBUCK * 4);
    int*      misc   = (int*)     alloc(64);

    k_zero<<<NBUCK/256, 256, 0, stream>>>(hist, cnt2, cnt, misc);
    k_prep<<<3264, 256, 0, stream>>>(x, Wk, Wv, Wq, keys0, x_bf, wk_bf, wv_bf, wq_bf, k0_bf);
    k_proj3<<<dim3(TTOK/128, 2, 3), 256, 0, stream>>>(
        x_bf, wk_bf, wv_bf, wq_bf, bk, bv, bq, ka, ka_bf, va_, qa_bf);
    k_sim<<<2048, 256, 0, stream>>>(ka_bf, k0_bf, partV, partI);
    k_bmflags<<<32, 256, 0, stream>>>(partV, partI, mask, act0, best, novel, misc);
    k_ladder<<<NSLOT/256, 256, 0, stream>>>(act0, cand, candJ, misc);
    k_hist<<<CAPC/256, 256, 0, stream>>>(cand, misc, hist);
    k_scanhist<<<1, 1024, 0, stream>>>(hist, offsB);
    k_place<<<CAPC/256, 256, 0, stream>>>(cand, candJ, misc, offsB, cnt2, skey, sj);
    k_rank2<<<CAPC/256, 256, 0, stream>>>(skey, sj, misc, offsB, hist, slot_seq, rankis, cnt);
    k_actfinal<<<NSLOT/256, 256, 0, stream>>>(act0, cnt, act_f, la, misc);
    k_serial<<<1, 64, 0, stream>>>(novel, best, mask, act0, misc, slot_seq, rankis, cnt, act_f, la);
    k_offscatter<<<1, 256, 0, stream>>>(cnt, offs, slot_seq, rankis, listTok);
    k_apply<<<NSLOT, 256, 0, stream>>>(keys0, values0, ka, va_, novel, cnt, offs, listTok, kb_bf, vb);
    k_transV<<<dim3(NSLOT/32, DIM/32), 256, 0, stream>>>(vb, vbT);
    k_flash<<<dim3(TTOK/QBLK, SPLIT), 512, 0, stream>>>(qa_bf, kb_bf, vbT, la, opart, lpart);
    k_comb<<<TTOK*DIM/256, 256, 0, stream>>>(opart, lpart, out);
}